// Round 10
// baseline (1663.006 us; speedup 1.0000x reference)
//
#include <hip/hip_runtime.h>

#define NN 50000
#define NE 800000
#define CLAMPV 5.0f
#define BNS 0.9999950000374997f
#define EPKS 132   // int stride of packed Ep rows
#define NBLK 49    // ceil(NN/1024)

typedef __attribute__((ext_vector_type(8))) short s16x8;
typedef __attribute__((ext_vector_type(8))) __bf16 bf16x8;
typedef __attribute__((ext_vector_type(4))) float f32x4;

__device__ inline f32x4 mfma16(s16x8 a, s16x8 b, f32x4 c) {
    return __builtin_amdgcn_mfma_f32_16x16x32_bf16(
        __builtin_bit_cast(bf16x8, a), __builtin_bit_cast(bf16x8, b), c, 0, 0, 0);
}

__device__ inline unsigned short bf16r(float f) {
    return __builtin_bit_cast(unsigned short, (__bf16)f);
}

__device__ inline int pk2(float a, float b) {
    return (int)(unsigned)bf16r(a) | ((int)(unsigned)bf16r(b) << 16);
}

__device__ inline float b2f(unsigned short u) {
    return __builtin_bit_cast(float, (unsigned)u << 16);
}

// ---------------- degree / CSR build ----------------

__global__ __launch_bounds__(256) void k_deg(const int* __restrict__ ei, int* __restrict__ deg) {
    int e = blockIdx.x * 256 + threadIdx.x;
    if (e < NE) atomicAdd(&deg[ei[NE + e]], 1);
}

// hierarchical scan: local inclusive scans + block sums (+ logdeg folded in)
__global__ __launch_bounds__(1024) void k_scan1(const int* __restrict__ deg, int* __restrict__ offs,
                                                int* __restrict__ bsum, float* __restrict__ logdeg) {
    __shared__ int sm[1024];
    int i = blockIdx.x * 1024 + threadIdx.x;
    int v = (i < NN) ? deg[i] : 0;
    if (i < NN) logdeg[i] = logf((float)v + 1.0f);
    sm[threadIdx.x] = v;
    __syncthreads();
    for (int s = 1; s < 1024; s <<= 1) {
        int t = (threadIdx.x >= s) ? sm[threadIdx.x - s] : 0;
        __syncthreads();
        sm[threadIdx.x] += t;
        __syncthreads();
    }
    if (i < NN) offs[i + 1] = sm[threadIdx.x];
    if (threadIdx.x == 1023) bsum[blockIdx.x] = sm[1023];
    if (blockIdx.x == 0 && threadIdx.x == 0) offs[0] = 0;
}

__global__ void k_scan2(int* __restrict__ bsum) {
    if (threadIdx.x == 0) {
        int acc = 0;
        for (int i = 0; i < NBLK; ++i) { int v = bsum[i]; bsum[i] = acc; acc += v; }
    }
}

__global__ __launch_bounds__(1024) void k_scan3(int* __restrict__ offs, const int* __restrict__ bsum) {
    int i = blockIdx.x * 1024 + threadIdx.x;
    if (i < NN) offs[i + 1] += bsum[blockIdx.x];
}

__global__ __launch_bounds__(256) void k_fill(const int* __restrict__ ei, const int* __restrict__ offs,
                                              int* __restrict__ cursor, int* __restrict__ csr_src,
                                              int* __restrict__ epos) {
    int e = blockIdx.x * 256 + threadIdx.x;
    if (e < NE) {
        int d = ei[NE + e];
        int pos = offs[d] + atomicAdd(&cursor[d], 1);
        csr_src[pos] = ei[e];
        epos[e] = pos;
    }
}

// One launch packs ALL weights (both layers) into MFMA B-fragment order.
#define PL_A (128*256)
#define PL_B (128*128)
__global__ __launch_bounds__(256) void k_packAll(
    const float* __restrict__ We,  const float* __restrict__ Woe, const float* __restrict__ Wq,
    const float* __restrict__ Wk,  const float* __restrict__ Wv,  const float* __restrict__ Woh,
    const float* __restrict__ W1,  const float* __restrict__ W2,  const float* __restrict__ VR,
    short* __restrict__ Wep,  short* __restrict__ Woep, short* __restrict__ Wqp,
    short* __restrict__ Wkp,  short* __restrict__ Wvp,  short* __restrict__ Wohp,
    short* __restrict__ W1p,  short* __restrict__ W2p,  short* __restrict__ VRp) {
    int s = blockIdx.x * 256 + threadIdx.x;
    const float* W; short* out; int ncol, perL; bool vr = false;
    if (s < 2 * PL_A) { W = We; out = Wep; ncol = 256; perL = PL_A; }
    else if ((s -= 2 * PL_A) < 2 * PL_B) { W = Woe; out = Woep; ncol = 128; perL = PL_B; }
    else if ((s -= 2 * PL_B) < 2 * PL_B) { W = Wq;  out = Wqp;  ncol = 128; perL = PL_B; }
    else if ((s -= 2 * PL_B) < 2 * PL_B) { W = Wk;  out = Wkp;  ncol = 128; perL = PL_B; }
    else if ((s -= 2 * PL_B) < 2 * PL_B) { W = Wv;  out = Wvp;  ncol = 128; perL = PL_B; }
    else if ((s -= 2 * PL_B) < 2 * PL_B) { W = Woh; out = Wohp; ncol = 128; perL = PL_B; }
    else if ((s -= 2 * PL_B) < 2 * PL_A) { W = W1;  out = W1p;  ncol = 256; perL = PL_A; }
    else if ((s -= 2 * PL_A) < 2 * PL_A) { W = W2;  out = W2p;  ncol = 128; perL = PL_A; }
    else if ((s -= 2 * PL_A) < 2 * PL_B) { W = VR;  out = VRp;  ncol = 128; perL = PL_B; vr = true; }
    else return;
    int l = s / perL, q = s % perL;
    int j = q & 7; int t2 = q >> 3; int kg = t2 & 3; t2 >>= 2;
    int col = t2 % ncol; int kt = t2 / ncol;
    int k = kt * 32 + kg * 8 + j;
    float v;
    if (vr) v = ((k >> 4) == (col >> 4)) ? VR[l * 2048 + (k & 15) * 128 + col] : 0.f;
    else    v = W[(size_t)l * perL + k * ncol + col];
    out[(size_t)l * perL + q] = (short)bf16r(v);
}

// ---------------- per-layer kernels ----------------

// Q/K/V via MFMA: 64 nodes/block, 512 threads (8 waves). Only launched for layer 0.
__global__ __launch_bounds__(512) void k_qkv(const float* __restrict__ x,
                                             const short* __restrict__ Wqp, const float* __restrict__ bq,
                                             const short* __restrict__ Wkp, const short* __restrict__ Wvp,
                                             unsigned short* __restrict__ Qh, unsigned short* __restrict__ Kh,
                                             unsigned short* __restrict__ Vh) {
    __shared__ short xsw[64 * 128];
    int t = threadIdx.x;
    int ci = t & 15, r0 = t >> 4;
    int n0 = blockIdx.x * 64;
    for (int rr = r0; rr < 64; rr += 32) {
        int n = n0 + rr;
        int4 pkv = make_int4(0, 0, 0, 0);
        if (n < NN) {
            const float4* src = (const float4*)(x + (size_t)n * 128 + ci * 8);
            float4 v0 = src[0], v1 = src[1];
            pkv.x = pk2(v0.x, v0.y); pkv.y = pk2(v0.z, v0.w);
            pkv.z = pk2(v1.x, v1.y); pkv.w = pk2(v1.z, v1.w);
        }
        int byte = (rr * 256 + ci * 16) ^ ((rr & 7) << 4);
        *(int4*)((char*)xsw + byte) = pkv;
    }
    __syncthreads();
    int lane = t & 63, w = t >> 6;
    int l15 = lane & 15, kg = lane >> 4;
    f32x4 acc[4][3];
#pragma unroll
    for (int m = 0; m < 4; ++m)
#pragma unroll
        for (int q = 0; q < 3; ++q) { acc[m][q][0] = 0.f; acc[m][q][1] = 0.f; acc[m][q][2] = 0.f; acc[m][q][3] = 0.f; }
    int col = w * 16 + l15;
#pragma unroll
    for (int kt = 0; kt < 4; ++kt) {
        s16x8 a[4];
#pragma unroll
        for (int m = 0; m < 4; ++m) {
            int row = m * 16 + l15;
            int abyte = (row * 256 + kt * 64 + kg * 16) ^ ((l15 & 7) << 4);
            a[m] = *(const s16x8*)((const char*)xsw + abyte);
        }
        size_t bo = ((size_t)((kt * 128 + col) * 4 + kg)) * 8;
        s16x8 bqf = *(const s16x8*)(Wqp + bo);
        s16x8 bkf = *(const s16x8*)(Wkp + bo);
        s16x8 bvf = *(const s16x8*)(Wvp + bo);
#pragma unroll
        for (int m = 0; m < 4; ++m) {
            acc[m][0] = mfma16(a[m], bqf, acc[m][0]);
            acc[m][1] = mfma16(a[m], bkf, acc[m][1]);
            acc[m][2] = mfma16(a[m], bvf, acc[m][2]);
        }
    }
    float bqv = bq[col];
#pragma unroll
    for (int m = 0; m < 4; ++m)
#pragma unroll
        for (int i = 0; i < 4; ++i) {
            int n = n0 + m * 16 + kg * 4 + i;
            if (n < NN) {
                Qh[(size_t)n * 128 + col] = bf16r(acc[m][0][i] + bqv);
                Kh[(size_t)n * 128 + col] = bf16r(acc[m][1][i]);
                Vh[(size_t)n * 128 + col] = bf16r(acc[m][2][i]);
            }
        }
}

// Fused edge kernel: 64 edges/block, 512 threads (8 waves). epk/ets share LDS.
template<bool IN_F32>
__global__ __launch_bounds__(512) void k_edgeA(const void* __restrict__ ea_, const int* __restrict__ ei,
                                               const int* __restrict__ epos,
                                               const short* __restrict__ Wep, const float* __restrict__ be,
                                               const float* __restrict__ Aw,
                                               const unsigned short* __restrict__ Qh,
                                               const unsigned short* __restrict__ Kh,
                                               unsigned short* __restrict__ e_t, float* __restrict__ sc,
                                               const short* __restrict__ Woep, const float* __restrict__ boe,
                                               void* __restrict__ eout_) {
    __shared__ short eas[64 * 128];
    __shared__ int epts[64 * EPKS];
    const float* eaf = (const float*)ea_;
    const unsigned short* eab = (const unsigned short*)ea_;
    unsigned short* eout_b = (unsigned short*)eout_;
    float* eout_f = (float*)eout_;

    int e0 = blockIdx.x * 64;
    int t = threadIdx.x;
    int ci = t & 15, r0 = t >> 4;
    int eA = e0 + r0, eB = eA + 32;
    int siA = ei[eA], diA = ei[NE + eA], posA = epos[eA];
    int siB = ei[eB], diB = ei[NE + eB], posB = epos[eB];

    {   // phase 1: stage ea -> bf16 swizzled
#pragma unroll
        for (int h = 0; h < 2; ++h) {
            int rr = r0 + h * 32;
            int4 pkv;
            if (IN_F32) {
                const float4* src = (const float4*)(eaf + (size_t)(e0 + rr) * 128 + ci * 8);
                float4 v0 = src[0], v1 = src[1];
                pkv.x = pk2(v0.x, v0.y); pkv.y = pk2(v0.z, v0.w);
                pkv.z = pk2(v1.x, v1.y); pkv.w = pk2(v1.z, v1.w);
            } else {
                pkv = *(const int4*)(eab + (size_t)(e0 + rr) * 128 + ci * 8);
            }
            int byte = (rr * 256 + ci * 16) ^ ((rr & 7) << 4);
            *(int4*)((char*)eas + byte) = pkv;
        }
    }
    __syncthreads();
    union { int4 v; unsigned short us[8]; } kuA, quA, kuB, quB;
    kuA.v = *(const int4*)(Kh + (size_t)siA * 128 + ci * 8);
    quA.v = *(const int4*)(Qh + (size_t)diA * 128 + ci * 8);
    kuB.v = *(const int4*)(Kh + (size_t)siB * 128 + ci * 8);
    quB.v = *(const int4*)(Qh + (size_t)diB * 128 + ci * 8);

    int lane = t & 63, w = t >> 6;
    int l15 = lane & 15, kg = lane >> 4;
    {   // phase 2: Ep = eas @ We + be
        f32x4 acc[4][2];
#pragma unroll
        for (int m = 0; m < 4; ++m)
#pragma unroll
            for (int q = 0; q < 2; ++q) { acc[m][q][0] = 0.f; acc[m][q][1] = 0.f; acc[m][q][2] = 0.f; acc[m][q][3] = 0.f; }
#pragma unroll
        for (int kt = 0; kt < 4; ++kt) {
            s16x8 a[4];
#pragma unroll
            for (int m = 0; m < 4; ++m) {
                int row = m * 16 + l15;
                int abyte = (row * 256 + kt * 64 + kg * 16) ^ ((l15 & 7) << 4);
                a[m] = *(const s16x8*)((const char*)eas + abyte);
            }
#pragma unroll
            for (int q = 0; q < 2; ++q) {
                int col = w * 32 + q * 16 + l15;
                s16x8 b = *(const s16x8*)(Wep + ((size_t)((kt * 256 + col) * 4 + kg)) * 8);
#pragma unroll
                for (int m = 0; m < 4; ++m) acc[m][q] = mfma16(a[m], b, acc[m][q]);
            }
        }
        float bw = be[w * 32 + l15], bb = be[w * 32 + 16 + l15];
#pragma unroll
        for (int m = 0; m < 4; ++m)
#pragma unroll
            for (int i = 0; i < 4; ++i) {
                int row = m * 16 + kg * 4 + i;
                epts[row * EPKS + w * 16 + l15] = pk2(acc[m][0][i] + bw, acc[m][1][i] + bb);
            }
    }
    __syncthreads();
    int4 wA0, wA1, wB0, wB1;
    {
        const int4* pA = (const int4*)(epts + r0 * EPKS + ci * 8);
        wA0 = pA[0]; wA1 = pA[1];
        const int4* pB = (const int4*)(epts + (r0 + 32) * EPKS + ci * 8);
        wB0 = pB[0]; wB1 = pB[1];
    }
    __syncthreads();
    {   // phase 3: elementwise
        int hh = ci >> 1, dbase = (ci & 1) * 8;
        float aw[8];
#pragma unroll
        for (int j = 0; j < 8; ++j) aw[j] = Aw[(dbase + j) * 8 + hh];
#pragma unroll
        for (int h = 0; h < 2; ++h) {
            int r = r0 + h * 32;
            int pos = h ? posB : posA;
            const unsigned short* kus = h ? kuB.us : kuA.us;
            const unsigned short* qus = h ? quB.us : quA.us;
            const int4 w0 = h ? wB0 : wA0;
            const int4 w1 = h ? wB1 : wA1;
            int prs[8] = {w0.x, w0.y, w0.z, w0.w, w1.x, w1.y, w1.z, w1.w};
            float p = 0.f;
            float etv[8];
#pragma unroll
            for (int j = 0; j < 8; ++j) {
                int pr = prs[j];
                float ew = b2f((unsigned short)pr);
                float ebv = b2f((unsigned short)((unsigned)pr >> 16));
                float kq = b2f(kus[j]) + b2f(qus[j]);
                float sv = kq * ew;
                float ss = copysignf(sqrtf(fabsf(sv)), sv);
                float et = fmaxf(ss + ebv, 0.f);
                etv[j] = et;
                p += et * aw[j];
            }
            int4 pkv;
            pkv.x = pk2(etv[0], etv[1]); pkv.y = pk2(etv[2], etv[3]);
            pkv.z = pk2(etv[4], etv[5]); pkv.w = pk2(etv[6], etv[7]);
            *(int4*)(e_t + (size_t)pos * 128 + ci * 8) = pkv;
            int byte = (r * 256 + ci * 16) ^ ((r & 7) << 4);
            *(int4*)((char*)epts + byte) = pkv;
            p += __shfl_xor(p, 1);
            if ((ci & 1) == 0) {
                float s = fminf(fmaxf(p, -CLAMPV), CLAMPV);
                sc[(size_t)pos * 8 + hh] = s;
            }
        }
    }
    __syncthreads();
    {   // phase 4: e_out = (ea + ets @ Woe + boe) * BNS
        f32x4 acc[4];
#pragma unroll
        for (int m = 0; m < 4; ++m) { acc[m][0] = 0.f; acc[m][1] = 0.f; acc[m][2] = 0.f; acc[m][3] = 0.f; }
        int col = w * 16 + l15;
#pragma unroll
        for (int kt = 0; kt < 4; ++kt) {
            s16x8 a[4];
#pragma unroll
            for (int m = 0; m < 4; ++m) {
                int row = m * 16 + l15;
                int abyte = (row * 256 + kt * 64 + kg * 16) ^ ((l15 & 7) << 4);
                a[m] = *(const s16x8*)((const char*)epts + abyte);
            }
            s16x8 b = *(const s16x8*)(Woep + ((size_t)((kt * 128 + col) * 4 + kg)) * 8);
#pragma unroll
            for (int m = 0; m < 4; ++m) acc[m] = mfma16(a[m], b, acc[m]);
        }
        float bb = boe[col];
#pragma unroll
        for (int m = 0; m < 4; ++m)
#pragma unroll
            for (int i = 0; i < 4; ++i) {
                int rr = m * 16 + kg * 4 + i;
                int rbyte = (rr * 256 + col * 2) ^ ((rr & 7) << 4);
                float res = b2f(*(const unsigned short*)((const char*)eas + rbyte));
                size_t idx = (size_t)(e0 + rr) * 128 + col;
                float v = (res + acc[m][i] + bb) * BNS;
                if (IN_F32) eout_b[idx] = bf16r(v);
                else        eout_f[idx] = v;
            }
    }
}

// Fused node kernel: 64 nodes/block, 512 threads (8 waves).
// phase 0: CSR attention gather (wave w -> 8 nodes) => wV f32 in bufU, rowV bf16 in bufA
// p1: hs = (wV + rowV@VeRowBD) * degscale -> bufU; p2: h1 = (x + hs@Woh + boh)*BNS -> bufA + regs
// p3: us = relu(h1@W1+b1) -> bufU; p4: out = (h1 + us@W2 + b2)*BNS
// EMIT: additionally compute next-layer Q/K/V from out (double-buffered outputs).
template<bool EMIT>
__global__ __launch_bounds__(512) void k_nodeB(
    const int* __restrict__ offs, const int* __restrict__ csr_src, const float* __restrict__ sc,
    const unsigned short* __restrict__ e_t, const unsigned short* __restrict__ Vh,
    const short* __restrict__ VRp, const float* __restrict__ dc,
    const float* __restrict__ logdeg, const float* __restrict__ x,
    const short* __restrict__ Wohp, const float* __restrict__ boh,
    const short* __restrict__ W1p, const float* __restrict__ b1,
    const short* __restrict__ W2p, const float* __restrict__ b2,
    float* __restrict__ xout,
    const short* __restrict__ Wqp2, const float* __restrict__ bq2,
    const short* __restrict__ Wkp2, const short* __restrict__ Wvp2,
    unsigned short* __restrict__ Qh2, unsigned short* __restrict__ Kh2,
    unsigned short* __restrict__ Vh2) {
    __shared__ short bufA[64 * 128];   // rowV bf16 / h1 / out (16 KB)
    __shared__ short bufU[64 * 256];   // wV f32 / hs / us (32 KB)
    int n0 = blockIdx.x * 64;
    int t = threadIdx.x;
    int lane = t & 63, w = t >> 6;
    {   // phase 0: attention gather, wave w handles nodes n0+w*8 .. +7
        for (int j = 0; j < 8; ++j) {
            int n = n0 + w * 8 + j;
            float av0 = 0.f, av1 = 0.f, ar0 = 0.f, ar1 = 0.f;
            if (n < NN) {
                int beg = offs[n], end = offs[n + 1];
                int h = lane & 7, es = lane >> 3;
                float mx = -1e30f;
                for (int i = beg + es; i < end; i += 8)
                    mx = fmaxf(mx, sc[(size_t)i * 8 + h]);
#pragma unroll
                for (int o = 8; o < 64; o <<= 1) mx = fmaxf(mx, __shfl_xor(mx, o));
                float ds = 0.f;
                for (int i = beg + es; i < end; i += 8)
                    ds += expf(sc[(size_t)i * 8 + h] - mx);
#pragma unroll
                for (int o = 8; o < 64; o <<= 1) ds += __shfl_xor(ds, o);
                float inv = 1.f / (ds + 1e-16f);
                int hv = lane >> 3;
                float mv = __shfl(mx, hv), idv = __shfl(inv, hv);
                for (int i = beg; i < end; ++i) {
                    float a = expf(sc[(size_t)i * 8 + hv] - mv) * idv;
                    int s = csr_src[i];
                    int v = ((const int*)Vh)[(size_t)s * 64 + lane];
                    int u = ((const int*)e_t)[(size_t)i * 64 + lane];
                    av0 += b2f((unsigned short)v) * a;
                    av1 += b2f((unsigned short)((unsigned)v >> 16)) * a;
                    ar0 += b2f((unsigned short)u) * a;
                    ar1 += b2f((unsigned short)((unsigned)u >> 16)) * a;
                }
            }
            int rr = w * 8 + j;
            *(float2*)((char*)bufU + rr * 512 + lane * 8) = make_float2(av0, av1);  // wV f32 linear
            int byte = (rr * 256 + lane * 4) ^ ((rr & 7) << 4);
            *(int*)((char*)bufA + byte) = pk2(ar0, ar1);                            // rowV bf16 swz
        }
    }
    __syncthreads();
    int l15 = lane & 15, kg = lane >> 4;
    int col = w * 16 + l15;
    {   // p1: hs = (wV + rowV@VeRowBD) * degscale
        f32x4 acc[4];
#pragma unroll
        for (int m = 0; m < 4; ++m)
#pragma unroll
            for (int i = 0; i < 4; ++i) {
                int rr = m * 16 + kg * 4 + i;
                acc[m][i] = *(const float*)((const char*)bufU + rr * 512 + col * 4);
            }
#pragma unroll
        for (int kt = 0; kt < 4; ++kt) {
            s16x8 a[4];
#pragma unroll
            for (int m = 0; m < 4; ++m) {
                int row = m * 16 + l15;
                int abyte = (row * 256 + kt * 64 + kg * 16) ^ ((l15 & 7) << 4);
                a[m] = *(const s16x8*)((const char*)bufA + abyte);
            }
            s16x8 b = *(const s16x8*)(VRp + ((size_t)((kt * 128 + col) * 4 + kg)) * 8);
#pragma unroll
            for (int m = 0; m < 4; ++m) acc[m] = mfma16(a[m], b, acc[m]);
        }
        __syncthreads();   // all wV reads complete before hs overwrites bufU
        float d0 = dc[col * 2], d1 = dc[col * 2 + 1];
#pragma unroll
        for (int m = 0; m < 4; ++m)
#pragma unroll
            for (int i = 0; i < 4; ++i) {
                int rr = m * 16 + kg * 4 + i, n = n0 + rr;
                float ld = (n < NN) ? logdeg[n] : 0.f;
                float hs = acc[m][i] * (d0 + ld * d1);
                int byte = (rr * 256 + col * 2) ^ ((rr & 7) << 4);
                *(unsigned short*)((char*)bufU + byte) = bf16r(hs);
            }
    }
    __syncthreads();
    float h1r[4][4];
    {   // p2: h1 = (x + hs@Woh + boh)*BNS
        f32x4 acc[4];
#pragma unroll
        for (int m = 0; m < 4; ++m) { acc[m][0] = 0.f; acc[m][1] = 0.f; acc[m][2] = 0.f; acc[m][3] = 0.f; }
#pragma unroll
        for (int kt = 0; kt < 4; ++kt) {
            s16x8 a[4];
#pragma unroll
            for (int m = 0; m < 4; ++m) {
                int row = m * 16 + l15;
                int abyte = (row * 256 + kt * 64 + kg * 16) ^ ((l15 & 7) << 4);
                a[m] = *(const s16x8*)((const char*)bufU + abyte);
            }
            s16x8 b = *(const s16x8*)(Wohp + ((size_t)((kt * 128 + col) * 4 + kg)) * 8);
#pragma unroll
            for (int m = 0; m < 4; ++m) acc[m] = mfma16(a[m], b, acc[m]);
        }
        float bb = boh[col];
#pragma unroll
        for (int m = 0; m < 4; ++m)
#pragma unroll
            for (int i = 0; i < 4; ++i) {
                int rr = m * 16 + kg * 4 + i, n = n0 + rr;
                float xv = (n < NN) ? x[(size_t)n * 128 + col] : 0.f;
                float h1 = (xv + acc[m][i] + bb) * BNS;
                h1r[m][i] = h1;
                int byte = (rr * 256 + col * 2) ^ ((rr & 7) << 4);
                *(unsigned short*)((char*)bufA + byte) = bf16r(h1);
            }
    }
    __syncthreads();
    {   // p3: us = relu(h1@W1 + b1)
        f32x4 acc[4][2];
#pragma unroll
        for (int m = 0; m < 4; ++m)
#pragma unroll
            for (int q = 0; q < 2; ++q) { acc[m][q][0] = 0.f; acc[m][q][1] = 0.f; acc[m][q][2] = 0.f; acc[m][q][3] = 0.f; }
#pragma unroll
        for (int kt = 0; kt < 4; ++kt) {
            s16x8 a[4];
#pragma unroll
            for (int m = 0; m < 4; ++m) {
                int row = m * 16 + l15;
                int abyte = (row * 256 + kt * 64 + kg * 16) ^ ((l15 & 7) << 4);
                a[m] = *(const s16x8*)((const char*)bufA + abyte);
            }
#pragma unroll
            for (int q = 0; q < 2; ++q) {
                int colq = w * 32 + q * 16 + l15;
                s16x8 b = *(const s16x8*)(W1p + ((size_t)((kt * 256 + colq) * 4 + kg)) * 8);
#pragma unroll
                for (int m = 0; m < 4; ++m) acc[m][q] = mfma16(a[m], b, acc[m][q]);
            }
        }
        __syncthreads();   // hs reads (p2) complete before us overwrites bufU
#pragma unroll
        for (int q = 0; q < 2; ++q) {
            int colq = w * 32 + q * 16 + l15;
            float bb = b1[colq];
#pragma unroll
            for (int m = 0; m < 4; ++m)
#pragma unroll
                for (int i = 0; i < 4; ++i) {
                    int rr = m * 16 + kg * 4 + i;
                    float us = fmaxf(acc[m][q][i] + bb, 0.f);
                    int byte = (rr * 512 + colq * 2) ^ ((rr & 7) << 4);
                    *(unsigned short*)((char*)bufU + byte) = bf16r(us);
                }
        }
    }
    __syncthreads();
    {   // p4: out = (h1 + us@W2 + b2)*BNS; EMIT: stage out bf16 into bufA
        f32x4 acc[4];
#pragma unroll
        for (int m = 0; m < 4; ++m) { acc[m][0] = 0.f; acc[m][1] = 0.f; acc[m][2] = 0.f; acc[m][3] = 0.f; }
#pragma unroll
        for (int kt = 0; kt < 8; ++kt) {
            s16x8 a[4];
#pragma unroll
            for (int m = 0; m < 4; ++m) {
                int row = m * 16 + l15;
                int abyte = (row * 512 + kt * 64 + kg * 16) ^ ((l15 & 7) << 4);
                a[m] = *(const s16x8*)((const char*)bufU + abyte);
            }
            s16x8 b = *(const s16x8*)(W2p + ((size_t)((kt * 128 + col) * 4 + kg)) * 8);
#pragma unroll
            for (int m = 0; m < 4; ++m) acc[m] = mfma16(a[m], b, acc[m]);
        }
        float bb = b2[col];
#pragma unroll
        for (int m = 0; m < 4; ++m)
#pragma unroll
            for (int i = 0; i < 4; ++i) {
                int rr = m * 16 + kg * 4 + i, n = n0 + rr;
                float outv = (h1r[m][i] + acc[m][i] + bb) * BNS;
                if (n < NN) xout[(size_t)n * 128 + col] = outv;
                if (EMIT) {
                    int byte = (rr * 256 + col * 2) ^ ((rr & 7) << 4);
                    *(unsigned short*)((char*)bufA + byte) = bf16r(outv);
                }
            }
    }
    if (EMIT) {   // next-layer Q/K/V from staged out
        __syncthreads();
        f32x4 acc[4][3];
#pragma unroll
        for (int m = 0; m < 4; ++m)
#pragma unroll
            for (int q = 0; q < 3; ++q) { acc[m][q][0] = 0.f; acc[m][q][1] = 0.f; acc[m][q][2] = 0.f; acc[m][q][3] = 0.f; }
#pragma unroll
        for (int kt = 0; kt < 4; ++kt) {
            s16x8 a[4];
#pragma unroll
            for (int m = 0; m < 4; ++m) {
                int row = m * 16 + l15;
                int abyte = (row * 256 + kt * 64 + kg * 16) ^ ((l15 & 7) << 4);
                a[m] = *(const s16x8*)((const char*)bufA + abyte);
            }
            size_t bo = ((size_t)((kt * 128 + col) * 4 + kg)) * 8;
            s16x8 bqf = *(const s16x8*)(Wqp2 + bo);
            s16x8 bkf = *(const s16x8*)(Wkp2 + bo);
            s16x8 bvf = *(const s16x8*)(Wvp2 + bo);
#pragma unroll
            for (int m = 0; m < 4; ++m) {
                acc[m][0] = mfma16(a[m], bqf, acc[m][0]);
                acc[m][1] = mfma16(a[m], bkf, acc[m][1]);
                acc[m][2] = mfma16(a[m], bvf, acc[m][2]);
            }
        }
        float bqv = bq2[col];
#pragma unroll
        for (int m = 0; m < 4; ++m)
#pragma unroll
            for (int i = 0; i < 4; ++i) {
                int n = n0 + m * 16 + kg * 4 + i;
                if (n < NN) {
                    Qh2[(size_t)n * 128 + col] = bf16r(acc[m][0][i] + bqv);
                    Kh2[(size_t)n * 128 + col] = bf16r(acc[m][1][i]);
                    Vh2[(size_t)n * 128 + col] = bf16r(acc[m][2][i]);
                }
            }
    }
}

// ---------------- host launch ----------------

extern "C" void kernel_launch(void* const* d_in, const int* in_sizes, int n_in,
                              void* d_out, int out_size, void* d_ws, size_t ws_size,
                              hipStream_t stream) {
    (void)in_sizes; (void)n_in; (void)out_size; (void)ws_size;
    const float* x_in0  = (const float*)d_in[0];
    const int*   ei     = (const int*)d_in[1];
    const float* ea_in0 = (const float*)d_in[2];
    const float* Wq = (const float*)d_in[3];
    const float* bq = (const float*)d_in[4];
    const float* Wk = (const float*)d_in[5];
    const float* Wv = (const float*)d_in[6];
    const float* We = (const float*)d_in[7];
    const float* be = (const float*)d_in[8];
    const float* Aw = (const float*)d_in[9];
    const float* VeRow = (const float*)d_in[10];
    const float* Woh = (const float*)d_in[11];
    const float* boh = (const float*)d_in[12];
    const float* Woe = (const float*)d_in[13];
    const float* boe = (const float*)d_in[14];
    const float* dc  = (const float*)d_in[15];
    const float* W1 = (const float*)d_in[16];
    const float* b1 = (const float*)d_in[17];
    const float* W2 = (const float*)d_in[18];
    const float* b2 = (const float*)d_in[19];

    char* ws = (char*)d_ws;
    size_t off = 0;
    auto alloc = [&](size_t bytes) { void* p = ws + off; off = (off + bytes + 255) & ~(size_t)255; return p; };
    int*   deg    = (int*)alloc((size_t)NN * 4);
    int*   cursor = (int*)alloc((size_t)NN * 4);
    int*   offs   = (int*)alloc((size_t)(NN + 1) * 4);
    int*   bsum   = (int*)alloc((size_t)64 * 4);
    int*   csr_src= (int*)alloc((size_t)NE * 4);
    int*   epos   = (int*)alloc((size_t)NE * 4);
    float* logdeg = (float*)alloc((size_t)NN * 4);
    unsigned short* Qh  = (unsigned short*)alloc((size_t)NN * 128 * 2);
    unsigned short* Kh  = (unsigned short*)alloc((size_t)NN * 128 * 2);
    unsigned short* Vh  = (unsigned short*)alloc((size_t)NN * 128 * 2);
    unsigned short* Qh2 = (unsigned short*)alloc((size_t)NN * 128 * 2);
    unsigned short* Kh2 = (unsigned short*)alloc((size_t)NN * 128 * 2);
    unsigned short* Vh2 = (unsigned short*)alloc((size_t)NN * 128 * 2);
    unsigned short* e_t = (unsigned short*)alloc((size_t)NE * 128 * 2);
    unsigned short* ea_bf = (unsigned short*)alloc((size_t)NE * 128 * 2);
    float* sc     = (float*)alloc((size_t)NE * 8 * 4);
    short* Wep    = (short*)alloc((size_t)2 * 128 * 256 * 2);
    short* Woep   = (short*)alloc((size_t)2 * 128 * 128 * 2);
    short* Wqp    = (short*)alloc((size_t)2 * 128 * 128 * 2);
    short* Wkp    = (short*)alloc((size_t)2 * 128 * 128 * 2);
    short* Wvp    = (short*)alloc((size_t)2 * 128 * 128 * 2);
    short* Wohp   = (short*)alloc((size_t)2 * 128 * 128 * 2);
    short* W1p    = (short*)alloc((size_t)2 * 128 * 256 * 2);
    short* W2p    = (short*)alloc((size_t)2 * 256 * 128 * 2);
    short* VRp    = (short*)alloc((size_t)2 * 128 * 128 * 2);

    float* out_x = (float*)d_out;
    float* out_e = out_x + (size_t)NN * 128;

    hipError_t err;
    err = hipMemsetAsync(deg, 0, (size_t)NN * 4, stream); (void)err;
    err = hipMemsetAsync(cursor, 0, (size_t)NN * 4, stream); (void)err;

    k_deg<<<(NE + 255) / 256, 256, 0, stream>>>(ei, deg);
    k_scan1<<<NBLK, 1024, 0, stream>>>(deg, offs, bsum, logdeg);
    k_scan2<<<1, 64, 0, stream>>>(bsum);
    k_scan3<<<NBLK, 1024, 0, stream>>>(offs, bsum);
    k_fill<<<(NE + 255) / 256, 256, 0, stream>>>(ei, offs, cursor, csr_src, epos);
    k_packAll<<<1536, 256, 0, stream>>>(We, Woe, Wq, Wk, Wv, Woh, W1, W2, VeRow,
                                        Wep, Woep, Wqp, Wkp, Wvp, Wohp, W1p, W2p, VRp);

    // ---- layer 0 ----
    k_qkv<<<(NN + 63) / 64, 512, 0, stream>>>(x_in0, Wqp, bq, Wkp, Wvp, Qh, Kh, Vh);
    k_edgeA<true><<<NE / 64, 512, 0, stream>>>(ea_in0, ei, epos, Wep, be, Aw, Qh, Kh,
                                               e_t, sc, Woep, boe, ea_bf);
    k_nodeB<true><<<(NN + 63) / 64, 512, 0, stream>>>(
        offs, csr_src, sc, e_t, Vh, VRp, dc, logdeg, x_in0,
        Wohp, boh, W1p, b1, W2p, b2, out_x,
        Wqp + 128 * 128, bq + 128, Wkp + 128 * 128, Wvp + 128 * 128, Qh2, Kh2, Vh2);

    // ---- layer 1 ----
    k_edgeA<false><<<NE / 64, 512, 0, stream>>>(ea_bf, ei, epos, Wep + 128 * 256, be + 256,
                                                Aw + 128, Qh2, Kh2, e_t, sc,
                                                Woep + 128 * 128, boe + 128, out_e);
    k_nodeB<false><<<(NN + 63) / 64, 512, 0, stream>>>(
        offs, csr_src, sc, e_t, Vh2, VRp + 128 * 128, dc + 256, logdeg, out_x,
        Wohp + 128 * 128, boh + 128, W1p + 128 * 256, b1 + 256, W2p + 256 * 128, b2 + 128, out_x,
        nullptr, nullptr, nullptr, nullptr, nullptr, nullptr, nullptr);
}

// Round 11
// 1051.923 us; speedup vs baseline: 1.5809x; 1.5809x over previous
//
#include <hip/hip_runtime.h>

#define NN 50000
#define NE 800000
#define CLAMPV 5.0f
#define BNS 0.9999950000374997f
#define EPKS 132   // int stride of packed Ep rows
#define NBLK 49    // ceil(NN/1024)

typedef __attribute__((ext_vector_type(8))) short s16x8;
typedef __attribute__((ext_vector_type(8))) __bf16 bf16x8;
typedef __attribute__((ext_vector_type(4))) float f32x4;

__device__ inline f32x4 mfma16(s16x8 a, s16x8 b, f32x4 c) {
    return __builtin_amdgcn_mfma_f32_16x16x32_bf16(
        __builtin_bit_cast(bf16x8, a), __builtin_bit_cast(bf16x8, b), c, 0, 0, 0);
}

__device__ inline unsigned short bf16r(float f) {
    return __builtin_bit_cast(unsigned short, (__bf16)f);
}

__device__ inline int pk2(float a, float b) {
    return (int)(unsigned)bf16r(a) | ((int)(unsigned)bf16r(b) << 16);
}

__device__ inline float b2f(unsigned short u) {
    return __builtin_bit_cast(float, (unsigned)u << 16);
}

// ---------------- degree / CSR build ----------------

__global__ __launch_bounds__(256) void k_deg(const int* __restrict__ ei, int* __restrict__ deg) {
    int e = blockIdx.x * 256 + threadIdx.x;
    if (e < NE) atomicAdd(&deg[ei[NE + e]], 1);
}

__global__ __launch_bounds__(1024) void k_scan1(const int* __restrict__ deg, int* __restrict__ offs,
                                                int* __restrict__ bsum, float* __restrict__ logdeg) {
    __shared__ int sm[1024];
    int i = blockIdx.x * 1024 + threadIdx.x;
    int v = (i < NN) ? deg[i] : 0;
    if (i < NN) logdeg[i] = logf((float)v + 1.0f);
    sm[threadIdx.x] = v;
    __syncthreads();
    for (int s = 1; s < 1024; s <<= 1) {
        int t = (threadIdx.x >= s) ? sm[threadIdx.x - s] : 0;
        __syncthreads();
        sm[threadIdx.x] += t;
        __syncthreads();
    }
    if (i < NN) offs[i + 1] = sm[threadIdx.x];
    if (threadIdx.x == 1023) bsum[blockIdx.x] = sm[1023];
    if (blockIdx.x == 0 && threadIdx.x == 0) offs[0] = 0;
}

__global__ void k_scan2(int* __restrict__ bsum) {
    if (threadIdx.x == 0) {
        int acc = 0;
        for (int i = 0; i < NBLK; ++i) { int v = bsum[i]; bsum[i] = acc; acc += v; }
    }
}

__global__ __launch_bounds__(1024) void k_scan3(int* __restrict__ offs, const int* __restrict__ bsum) {
    int i = blockIdx.x * 1024 + threadIdx.x;
    if (i < NN) offs[i + 1] += bsum[blockIdx.x];
}

__global__ __launch_bounds__(256) void k_fill(const int* __restrict__ ei, const int* __restrict__ offs,
                                              int* __restrict__ cursor, int* __restrict__ csr_src,
                                              int* __restrict__ epos) {
    int e = blockIdx.x * 256 + threadIdx.x;
    if (e < NE) {
        int d = ei[NE + e];
        int pos = offs[d] + atomicAdd(&cursor[d], 1);
        csr_src[pos] = ei[e];
        epos[e] = pos;
    }
}

// One launch packs ALL weights (both layers) into MFMA B-fragment order.
#define PL_A (128*256)
#define PL_B (128*128)
__global__ __launch_bounds__(256) void k_packAll(
    const float* __restrict__ We,  const float* __restrict__ Woe, const float* __restrict__ Wq,
    const float* __restrict__ Wk,  const float* __restrict__ Wv,  const float* __restrict__ Woh,
    const float* __restrict__ W1,  const float* __restrict__ W2,  const float* __restrict__ VR,
    short* __restrict__ Wep,  short* __restrict__ Woep, short* __restrict__ Wqp,
    short* __restrict__ Wkp,  short* __restrict__ Wvp,  short* __restrict__ Wohp,
    short* __restrict__ W1p,  short* __restrict__ W2p,  short* __restrict__ VRp) {
    int s = blockIdx.x * 256 + threadIdx.x;
    const float* W; short* out; int ncol, perL; bool vr = false;
    if (s < 2 * PL_A) { W = We; out = Wep; ncol = 256; perL = PL_A; }
    else if ((s -= 2 * PL_A) < 2 * PL_B) { W = Woe; out = Woep; ncol = 128; perL = PL_B; }
    else if ((s -= 2 * PL_B) < 2 * PL_B) { W = Wq;  out = Wqp;  ncol = 128; perL = PL_B; }
    else if ((s -= 2 * PL_B) < 2 * PL_B) { W = Wk;  out = Wkp;  ncol = 128; perL = PL_B; }
    else if ((s -= 2 * PL_B) < 2 * PL_B) { W = Wv;  out = Wvp;  ncol = 128; perL = PL_B; }
    else if ((s -= 2 * PL_B) < 2 * PL_B) { W = Woh; out = Wohp; ncol = 128; perL = PL_B; }
    else if ((s -= 2 * PL_B) < 2 * PL_A) { W = W1;  out = W1p;  ncol = 256; perL = PL_A; }
    else if ((s -= 2 * PL_A) < 2 * PL_A) { W = W2;  out = W2p;  ncol = 128; perL = PL_A; }
    else if ((s -= 2 * PL_A) < 2 * PL_B) { W = VR;  out = VRp;  ncol = 128; perL = PL_B; vr = true; }
    else return;
    int l = s / perL, q = s % perL;
    int j = q & 7; int t2 = q >> 3; int kg = t2 & 3; t2 >>= 2;
    int col = t2 % ncol; int kt = t2 / ncol;
    int k = kt * 32 + kg * 8 + j;
    float v;
    if (vr) v = ((k >> 4) == (col >> 4)) ? VR[l * 2048 + (k & 15) * 128 + col] : 0.f;
    else    v = W[(size_t)l * perL + k * ncol + col];
    out[(size_t)l * perL + q] = (short)bf16r(v);
}

// ---------------- per-layer kernels ----------------

// Q/K/V via MFMA: 64 nodes/block, 512 threads (8 waves). Layer 0 only.
__global__ __launch_bounds__(512) void k_qkv(const float* __restrict__ x,
                                             const short* __restrict__ Wqp, const float* __restrict__ bq,
                                             const short* __restrict__ Wkp, const short* __restrict__ Wvp,
                                             unsigned short* __restrict__ Qh, unsigned short* __restrict__ Kh,
                                             unsigned short* __restrict__ Vh) {
    __shared__ short xsw[64 * 128];
    int t = threadIdx.x;
    int ci = t & 15, r0 = t >> 4;
    int n0 = blockIdx.x * 64;
    for (int rr = r0; rr < 64; rr += 32) {
        int n = n0 + rr;
        int4 pkv = make_int4(0, 0, 0, 0);
        if (n < NN) {
            const float4* src = (const float4*)(x + (size_t)n * 128 + ci * 8);
            float4 v0 = src[0], v1 = src[1];
            pkv.x = pk2(v0.x, v0.y); pkv.y = pk2(v0.z, v0.w);
            pkv.z = pk2(v1.x, v1.y); pkv.w = pk2(v1.z, v1.w);
        }
        int byte = (rr * 256 + ci * 16) ^ ((rr & 7) << 4);
        *(int4*)((char*)xsw + byte) = pkv;
    }
    __syncthreads();
    int lane = t & 63, w = t >> 6;
    int l15 = lane & 15, kg = lane >> 4;
    f32x4 acc[4][3];
#pragma unroll
    for (int m = 0; m < 4; ++m)
#pragma unroll
        for (int q = 0; q < 3; ++q) { acc[m][q][0] = 0.f; acc[m][q][1] = 0.f; acc[m][q][2] = 0.f; acc[m][q][3] = 0.f; }
    int col = w * 16 + l15;
#pragma unroll
    for (int kt = 0; kt < 4; ++kt) {
        s16x8 a[4];
#pragma unroll
        for (int m = 0; m < 4; ++m) {
            int row = m * 16 + l15;
            int abyte = (row * 256 + kt * 64 + kg * 16) ^ ((l15 & 7) << 4);
            a[m] = *(const s16x8*)((const char*)xsw + abyte);
        }
        size_t bo = ((size_t)((kt * 128 + col) * 4 + kg)) * 8;
        s16x8 bqf = *(const s16x8*)(Wqp + bo);
        s16x8 bkf = *(const s16x8*)(Wkp + bo);
        s16x8 bvf = *(const s16x8*)(Wvp + bo);
#pragma unroll
        for (int m = 0; m < 4; ++m) {
            acc[m][0] = mfma16(a[m], bqf, acc[m][0]);
            acc[m][1] = mfma16(a[m], bkf, acc[m][1]);
            acc[m][2] = mfma16(a[m], bvf, acc[m][2]);
        }
    }
    float bqv = bq[col];
#pragma unroll
    for (int m = 0; m < 4; ++m)
#pragma unroll
        for (int i = 0; i < 4; ++i) {
            int n = n0 + m * 16 + kg * 4 + i;
            if (n < NN) {
                Qh[(size_t)n * 128 + col] = bf16r(acc[m][0][i] + bqv);
                Kh[(size_t)n * 128 + col] = bf16r(acc[m][1][i]);
                Vh[(size_t)n * 128 + col] = bf16r(acc[m][2][i]);
            }
        }
}

// Fused edge kernel: 64 edges/block, 512 threads (8 waves). epk/ets share LDS.
template<bool IN_F32>
__global__ __launch_bounds__(512) void k_edgeA(const void* __restrict__ ea_, const int* __restrict__ ei,
                                               const int* __restrict__ epos,
                                               const short* __restrict__ Wep, const float* __restrict__ be,
                                               const float* __restrict__ Aw,
                                               const unsigned short* __restrict__ Qh,
                                               const unsigned short* __restrict__ Kh,
                                               unsigned short* __restrict__ e_t, float* __restrict__ sc,
                                               const short* __restrict__ Woep, const float* __restrict__ boe,
                                               void* __restrict__ eout_) {
    __shared__ short eas[64 * 128];
    __shared__ int epts[64 * EPKS];
    const float* eaf = (const float*)ea_;
    const unsigned short* eab = (const unsigned short*)ea_;
    unsigned short* eout_b = (unsigned short*)eout_;
    float* eout_f = (float*)eout_;

    int e0 = blockIdx.x * 64;
    int t = threadIdx.x;
    int ci = t & 15, r0 = t >> 4;
    int eA = e0 + r0, eB = eA + 32;
    int siA = ei[eA], diA = ei[NE + eA], posA = epos[eA];
    int siB = ei[eB], diB = ei[NE + eB], posB = epos[eB];

    {   // phase 1: stage ea -> bf16 swizzled
#pragma unroll
        for (int h = 0; h < 2; ++h) {
            int rr = r0 + h * 32;
            int4 pkv;
            if (IN_F32) {
                const float4* src = (const float4*)(eaf + (size_t)(e0 + rr) * 128 + ci * 8);
                float4 v0 = src[0], v1 = src[1];
                pkv.x = pk2(v0.x, v0.y); pkv.y = pk2(v0.z, v0.w);
                pkv.z = pk2(v1.x, v1.y); pkv.w = pk2(v1.z, v1.w);
            } else {
                pkv = *(const int4*)(eab + (size_t)(e0 + rr) * 128 + ci * 8);
            }
            int byte = (rr * 256 + ci * 16) ^ ((rr & 7) << 4);
            *(int4*)((char*)eas + byte) = pkv;
        }
    }
    __syncthreads();
    union { int4 v; unsigned short us[8]; } kuA, quA, kuB, quB;
    kuA.v = *(const int4*)(Kh + (size_t)siA * 128 + ci * 8);
    quA.v = *(const int4*)(Qh + (size_t)diA * 128 + ci * 8);
    kuB.v = *(const int4*)(Kh + (size_t)siB * 128 + ci * 8);
    quB.v = *(const int4*)(Qh + (size_t)diB * 128 + ci * 8);

    int lane = t & 63, w = t >> 6;
    int l15 = lane & 15, kg = lane >> 4;
    {   // phase 2: Ep = eas @ We + be
        f32x4 acc[4][2];
#pragma unroll
        for (int m = 0; m < 4; ++m)
#pragma unroll
            for (int q = 0; q < 2; ++q) { acc[m][q][0] = 0.f; acc[m][q][1] = 0.f; acc[m][q][2] = 0.f; acc[m][q][3] = 0.f; }
        __builtin_amdgcn_s_setprio(1);
#pragma unroll
        for (int kt = 0; kt < 4; ++kt) {
            s16x8 a[4];
#pragma unroll
            for (int m = 0; m < 4; ++m) {
                int row = m * 16 + l15;
                int abyte = (row * 256 + kt * 64 + kg * 16) ^ ((l15 & 7) << 4);
                a[m] = *(const s16x8*)((const char*)eas + abyte);
            }
#pragma unroll
            for (int q = 0; q < 2; ++q) {
                int col = w * 32 + q * 16 + l15;
                s16x8 b = *(const s16x8*)(Wep + ((size_t)((kt * 256 + col) * 4 + kg)) * 8);
#pragma unroll
                for (int m = 0; m < 4; ++m) acc[m][q] = mfma16(a[m], b, acc[m][q]);
            }
        }
        __builtin_amdgcn_s_setprio(0);
        float bw = be[w * 32 + l15], bb = be[w * 32 + 16 + l15];
#pragma unroll
        for (int m = 0; m < 4; ++m)
#pragma unroll
            for (int i = 0; i < 4; ++i) {
                int row = m * 16 + kg * 4 + i;
                epts[row * EPKS + w * 16 + l15] = pk2(acc[m][0][i] + bw, acc[m][1][i] + bb);
            }
    }
    __syncthreads();
    int4 wA0, wA1, wB0, wB1;
    {
        const int4* pA = (const int4*)(epts + r0 * EPKS + ci * 8);
        wA0 = pA[0]; wA1 = pA[1];
        const int4* pB = (const int4*)(epts + (r0 + 32) * EPKS + ci * 8);
        wB0 = pB[0]; wB1 = pB[1];
    }
    __syncthreads();
    {   // phase 3: elementwise
        int hh = ci >> 1, dbase = (ci & 1) * 8;
        float aw[8];
#pragma unroll
        for (int j = 0; j < 8; ++j) aw[j] = Aw[(dbase + j) * 8 + hh];
#pragma unroll
        for (int h = 0; h < 2; ++h) {
            int r = r0 + h * 32;
            int pos = h ? posB : posA;
            const unsigned short* kus = h ? kuB.us : kuA.us;
            const unsigned short* qus = h ? quB.us : quA.us;
            const int4 w0 = h ? wB0 : wA0;
            const int4 w1 = h ? wB1 : wA1;
            int prs[8] = {w0.x, w0.y, w0.z, w0.w, w1.x, w1.y, w1.z, w1.w};
            float p = 0.f;
            float etv[8];
#pragma unroll
            for (int j = 0; j < 8; ++j) {
                int pr = prs[j];
                float ew = b2f((unsigned short)pr);
                float ebv = b2f((unsigned short)((unsigned)pr >> 16));
                float kq = b2f(kus[j]) + b2f(qus[j]);
                float sv = kq * ew;
                float ss = copysignf(sqrtf(fabsf(sv)), sv);
                float et = fmaxf(ss + ebv, 0.f);
                etv[j] = et;
                p += et * aw[j];
            }
            int4 pkv;
            pkv.x = pk2(etv[0], etv[1]); pkv.y = pk2(etv[2], etv[3]);
            pkv.z = pk2(etv[4], etv[5]); pkv.w = pk2(etv[6], etv[7]);
            *(int4*)(e_t + (size_t)pos * 128 + ci * 8) = pkv;
            int byte = (r * 256 + ci * 16) ^ ((r & 7) << 4);
            *(int4*)((char*)epts + byte) = pkv;
            p += __shfl_xor(p, 1);
            if ((ci & 1) == 0) {
                float s = fminf(fmaxf(p, -CLAMPV), CLAMPV);
                sc[(size_t)pos * 8 + hh] = s;
            }
        }
    }
    __syncthreads();
    {   // phase 4: e_out = (ea + ets @ Woe + boe) * BNS
        f32x4 acc[4];
#pragma unroll
        for (int m = 0; m < 4; ++m) { acc[m][0] = 0.f; acc[m][1] = 0.f; acc[m][2] = 0.f; acc[m][3] = 0.f; }
        int col = w * 16 + l15;
        __builtin_amdgcn_s_setprio(1);
#pragma unroll
        for (int kt = 0; kt < 4; ++kt) {
            s16x8 a[4];
#pragma unroll
            for (int m = 0; m < 4; ++m) {
                int row = m * 16 + l15;
                int abyte = (row * 256 + kt * 64 + kg * 16) ^ ((l15 & 7) << 4);
                a[m] = *(const s16x8*)((const char*)epts + abyte);
            }
            s16x8 b = *(const s16x8*)(Woep + ((size_t)((kt * 128 + col) * 4 + kg)) * 8);
#pragma unroll
            for (int m = 0; m < 4; ++m) acc[m] = mfma16(a[m], b, acc[m]);
        }
        __builtin_amdgcn_s_setprio(0);
        float bb = boe[col];
#pragma unroll
        for (int m = 0; m < 4; ++m)
#pragma unroll
            for (int i = 0; i < 4; ++i) {
                int rr = m * 16 + kg * 4 + i;
                int rbyte = (rr * 256 + col * 2) ^ ((rr & 7) << 4);
                float res = b2f(*(const unsigned short*)((const char*)eas + rbyte));
                size_t idx = (size_t)(e0 + rr) * 128 + col;
                float v = (res + acc[m][i] + bb) * BNS;
                if (IN_F32) eout_b[idx] = bf16r(v);
                else        eout_f[idx] = v;
            }
    }
}

// Node attention: one 64-lane wave per node. sc/e_t in CSR order -> coalesced.
__global__ __launch_bounds__(64) void k_nattn(const int* __restrict__ offs, const int* __restrict__ csr_src,
                                              const float* __restrict__ sc,
                                              const unsigned short* __restrict__ e_t,
                                              const unsigned short* __restrict__ Vh,
                                              float* __restrict__ wV, float* __restrict__ rowV) {
    int n = blockIdx.x;
    int lane = threadIdx.x;
    int beg = offs[n], end = offs[n + 1];
    int h = lane & 7, es = lane >> 3;
    float m = -1e30f;
    for (int i = beg + es; i < end; i += 8)
        m = fmaxf(m, sc[(size_t)i * 8 + h]);
#pragma unroll
    for (int off = 8; off < 64; off <<= 1) m = fmaxf(m, __shfl_xor(m, off));
    float dsum = 0.0f;
    for (int i = beg + es; i < end; i += 8)
        dsum += expf(sc[(size_t)i * 8 + h] - m);
#pragma unroll
    for (int off = 8; off < 64; off <<= 1) dsum += __shfl_xor(dsum, off);
    float inv_d = 1.0f / (dsum + 1e-16f);

    int hv = lane >> 3;
    float mv = __shfl(m, hv);
    float idv = __shfl(inv_d, hv);
    float av0 = 0.0f, av1 = 0.0f, ar0 = 0.0f, ar1 = 0.0f;
    for (int i = beg; i < end; ++i) {
        float a = expf(sc[(size_t)i * 8 + hv] - mv) * idv;
        int s = csr_src[i];
        int v = ((const int*)Vh)[(size_t)s * 64 + lane];
        int u = ((const int*)e_t)[(size_t)i * 64 + lane];
        av0 += b2f((unsigned short)v) * a;
        av1 += b2f((unsigned short)((unsigned)v >> 16)) * a;
        ar0 += b2f((unsigned short)u) * a;
        ar1 += b2f((unsigned short)((unsigned)u >> 16)) * a;
    }
    *(float2*)(wV + (size_t)n * 128 + 2 * lane)   = make_float2(av0, av1);
    *(float2*)(rowV + (size_t)n * 128 + 2 * lane) = make_float2(ar0, ar1);
}

// Node post via MFMA: 64 nodes/block, 512 threads. EMIT: also compute next-layer Q/K/V.
template<bool EMIT>
__global__ __launch_bounds__(512) void k_nodeB(
    const float* __restrict__ wV, const float* __restrict__ rowV,
    const short* __restrict__ VRp, const float* __restrict__ dc,
    const float* __restrict__ logdeg, const float* __restrict__ x,
    const short* __restrict__ Wohp, const float* __restrict__ boh,
    const short* __restrict__ W1p, const float* __restrict__ b1,
    const short* __restrict__ W2p, const float* __restrict__ b2,
    float* __restrict__ xout,
    const short* __restrict__ Wqp2, const float* __restrict__ bq2,
    const short* __restrict__ Wkp2, const short* __restrict__ Wvp2,
    unsigned short* __restrict__ Qh2, unsigned short* __restrict__ Kh2,
    unsigned short* __restrict__ Vh2) {
    __shared__ short bufA[64 * 128];   // rowV staging / h1 / out (16 KB)
    __shared__ short bufU[64 * 256];   // hs / us (32 KB)
    int n0 = blockIdx.x * 64;
    int t = threadIdx.x;
    int ci = t & 15, r0 = t >> 4;
    {   // p0: stage rowV -> bufA bf16 swizzled
#pragma unroll
        for (int h = 0; h < 2; ++h) {
            int rr = r0 + h * 32, n = n0 + rr;
            int4 pkv = make_int4(0, 0, 0, 0);
            if (n < NN) {
                const float4* src = (const float4*)(rowV + (size_t)n * 128 + ci * 8);
                float4 v0 = src[0], v1 = src[1];
                pkv.x = pk2(v0.x, v0.y); pkv.y = pk2(v0.z, v0.w);
                pkv.z = pk2(v1.x, v1.y); pkv.w = pk2(v1.z, v1.w);
            }
            int byte = (rr * 256 + ci * 16) ^ ((rr & 7) << 4);
            *(int4*)((char*)bufA + byte) = pkv;
        }
    }
    __syncthreads();
    int lane = t & 63, w = t >> 6;
    int l15 = lane & 15, kg = lane >> 4;
    int col = w * 16 + l15;
    {   // p1: hs = (wV + rowV@VeRowBD) * degscale -> bufU
        f32x4 acc[4];
#pragma unroll
        for (int m = 0; m < 4; ++m)
#pragma unroll
            for (int i = 0; i < 4; ++i) {
                int n = n0 + m * 16 + kg * 4 + i;
                acc[m][i] = (n < NN) ? wV[(size_t)n * 128 + col] : 0.f;
            }
#pragma unroll
        for (int kt = 0; kt < 4; ++kt) {
            s16x8 a[4];
#pragma unroll
            for (int m = 0; m < 4; ++m) {
                int row = m * 16 + l15;
                int abyte = (row * 256 + kt * 64 + kg * 16) ^ ((l15 & 7) << 4);
                a[m] = *(const s16x8*)((const char*)bufA + abyte);
            }
            s16x8 b = *(const s16x8*)(VRp + ((size_t)((kt * 128 + col) * 4 + kg)) * 8);
#pragma unroll
            for (int m = 0; m < 4; ++m) acc[m] = mfma16(a[m], b, acc[m]);
        }
        float d0 = dc[col * 2], d1 = dc[col * 2 + 1];
#pragma unroll
        for (int m = 0; m < 4; ++m)
#pragma unroll
            for (int i = 0; i < 4; ++i) {
                int rr = m * 16 + kg * 4 + i, n = n0 + rr;
                float ld = (n < NN) ? logdeg[n] : 0.f;
                float hs = acc[m][i] * (d0 + ld * d1);
                int byte = (rr * 256 + col * 2) ^ ((rr & 7) << 4);
                *(unsigned short*)((char*)bufU + byte) = bf16r(hs);
            }
    }
    __syncthreads();
    float h1r[4][4];
    {   // p2: h1 = (x + hs@Woh + boh)*BNS
        f32x4 acc[4];
#pragma unroll
        for (int m = 0; m < 4; ++m) { acc[m][0] = 0.f; acc[m][1] = 0.f; acc[m][2] = 0.f; acc[m][3] = 0.f; }
#pragma unroll
        for (int kt = 0; kt < 4; ++kt) {
            s16x8 a[4];
#pragma unroll
            for (int m = 0; m < 4; ++m) {
                int row = m * 16 + l15;
                int abyte = (row * 256 + kt * 64 + kg * 16) ^ ((l15 & 7) << 4);
                a[m] = *(const s16x8*)((const char*)bufU + abyte);
            }
            s16x8 b = *(const s16x8*)(Wohp + ((size_t)((kt * 128 + col) * 4 + kg)) * 8);
#pragma unroll
            for (int m = 0; m < 4; ++m) acc[m] = mfma16(a[m], b, acc[m]);
        }
        float bb = boh[col];
#pragma unroll
        for (int m = 0; m < 4; ++m)
#pragma unroll
            for (int i = 0; i < 4; ++i) {
                int rr = m * 16 + kg * 4 + i, n = n0 + rr;
                float xv = (n < NN) ? x[(size_t)n * 128 + col] : 0.f;
                float h1 = (xv + acc[m][i] + bb) * BNS;
                h1r[m][i] = h1;
                int byte = (rr * 256 + col * 2) ^ ((rr & 7) << 4);
                *(unsigned short*)((char*)bufA + byte) = bf16r(h1);
            }
    }
    __syncthreads();
    {   // p3: us = relu(h1@W1 + b1) -> bufU
        f32x4 acc[4][2];
#pragma unroll
        for (int m = 0; m < 4; ++m)
#pragma unroll
            for (int q = 0; q < 2; ++q) { acc[m][q][0] = 0.f; acc[m][q][1] = 0.f; acc[m][q][2] = 0.f; acc[m][q][3] = 0.f; }
#pragma unroll
        for (int kt = 0; kt < 4; ++kt) {
            s16x8 a[4];
#pragma unroll
            for (int m = 0; m < 4; ++m) {
                int row = m * 16 + l15;
                int abyte = (row * 256 + kt * 64 + kg * 16) ^ ((l15 & 7) << 4);
                a[m] = *(const s16x8*)((const char*)bufA + abyte);
            }
#pragma unroll
            for (int q = 0; q < 2; ++q) {
                int colq = w * 32 + q * 16 + l15;
                s16x8 b = *(const s16x8*)(W1p + ((size_t)((kt * 256 + colq) * 4 + kg)) * 8);
#pragma unroll
                for (int m = 0; m < 4; ++m) acc[m][q] = mfma16(a[m], b, acc[m][q]);
            }
        }
        __syncthreads();   // hs reads (p2) complete before us overwrites bufU
#pragma unroll
        for (int q = 0; q < 2; ++q) {
            int colq = w * 32 + q * 16 + l15;
            float bb = b1[colq];
#pragma unroll
            for (int m = 0; m < 4; ++m)
#pragma unroll
                for (int i = 0; i < 4; ++i) {
                    int rr = m * 16 + kg * 4 + i;
                    float us = fmaxf(acc[m][q][i] + bb, 0.f);
                    int byte = (rr * 512 + colq * 2) ^ ((rr & 7) << 4);
                    *(unsigned short*)((char*)bufU + byte) = bf16r(us);
                }
        }
    }
    __syncthreads();
    {   // p4: out = (h1 + us@W2 + b2)*BNS; EMIT: stage out bf16 into bufA
        f32x4 acc[4];
#pragma unroll
        for (int m = 0; m < 4; ++m) { acc[m][0] = 0.f; acc[m][1] = 0.f; acc[m][2] = 0.f; acc[m][3] = 0.f; }
#pragma unroll
        for (int kt = 0; kt < 8; ++kt) {
            s16x8 a[4];
#pragma unroll
            for (int m = 0; m < 4; ++m) {
                int row = m * 16 + l15;
                int abyte = (row * 512 + kt * 64 + kg * 16) ^ ((l15 & 7) << 4);
                a[m] = *(const s16x8*)((const char*)bufU + abyte);
            }
            s16x8 b = *(const s16x8*)(W2p + ((size_t)((kt * 128 + col) * 4 + kg)) * 8);
#pragma unroll
            for (int m = 0; m < 4; ++m) acc[m] = mfma16(a[m], b, acc[m]);
        }
        float bb = b2[col];
#pragma unroll
        for (int m = 0; m < 4; ++m)
#pragma unroll
            for (int i = 0; i < 4; ++i) {
                int rr = m * 16 + kg * 4 + i, n = n0 + rr;
                float outv = (h1r[m][i] + acc[m][i] + bb) * BNS;
                if (n < NN) xout[(size_t)n * 128 + col] = outv;
                if (EMIT) {
                    int byte = (rr * 256 + col * 2) ^ ((rr & 7) << 4);
                    *(unsigned short*)((char*)bufA + byte) = bf16r(outv);
                }
            }
    }
    if (EMIT) {   // next-layer Q/K/V from staged out
        __syncthreads();
        f32x4 acc[4][3];
#pragma unroll
        for (int m = 0; m < 4; ++m)
#pragma unroll
            for (int q = 0; q < 3; ++q) { acc[m][q][0] = 0.f; acc[m][q][1] = 0.f; acc[m][q][2] = 0.f; acc[m][q][3] = 0.f; }
#pragma unroll
        for (int kt = 0; kt < 4; ++kt) {
            s16x8 a[4];
#pragma unroll
            for (int m = 0; m < 4; ++m) {
                int row = m * 16 + l15;
                int abyte = (row * 256 + kt * 64 + kg * 16) ^ ((l15 & 7) << 4);
                a[m] = *(const s16x8*)((const char*)bufA + abyte);
            }
            size_t bo = ((size_t)((kt * 128 + col) * 4 + kg)) * 8;
            s16x8 bqf = *(const s16x8*)(Wqp2 + bo);
            s16x8 bkf = *(const s16x8*)(Wkp2 + bo);
            s16x8 bvf = *(const s16x8*)(Wvp2 + bo);
#pragma unroll
            for (int m = 0; m < 4; ++m) {
                acc[m][0] = mfma16(a[m], bqf, acc[m][0]);
                acc[m][1] = mfma16(a[m], bkf, acc[m][1]);
                acc[m][2] = mfma16(a[m], bvf, acc[m][2]);
            }
        }
        float bqv = bq2[col];
#pragma unroll
        for (int m = 0; m < 4; ++m)
#pragma unroll
            for (int i = 0; i < 4; ++i) {
                int n = n0 + m * 16 + kg * 4 + i;
                if (n < NN) {
                    Qh2[(size_t)n * 128 + col] = bf16r(acc[m][0][i] + bqv);
                    Kh2[(size_t)n * 128 + col] = bf16r(acc[m][1][i]);
                    Vh2[(size_t)n * 128 + col] = bf16r(acc[m][2][i]);
                }
            }
    }
}

// ---------------- host launch ----------------

extern "C" void kernel_launch(void* const* d_in, const int* in_sizes, int n_in,
                              void* d_out, int out_size, void* d_ws, size_t ws_size,
                              hipStream_t stream) {
    (void)in_sizes; (void)n_in; (void)out_size; (void)ws_size;
    const float* x_in0  = (const float*)d_in[0];
    const int*   ei     = (const int*)d_in[1];
    const float* ea_in0 = (const float*)d_in[2];
    const float* Wq = (const float*)d_in[3];
    const float* bq = (const float*)d_in[4];
    const float* Wk = (const float*)d_in[5];
    const float* Wv = (const float*)d_in[6];
    const float* We = (const float*)d_in[7];
    const float* be = (const float*)d_in[8];
    const float* Aw = (const float*)d_in[9];
    const float* VeRow = (const float*)d_in[10];
    const float* Woh = (const float*)d_in[11];
    const float* boh = (const float*)d_in[12];
    const float* Woe = (const float*)d_in[13];
    const float* boe = (const float*)d_in[14];
    const float* dc  = (const float*)d_in[15];
    const float* W1 = (const float*)d_in[16];
    const float* b1 = (const float*)d_in[17];
    const float* W2 = (const float*)d_in[18];
    const float* b2 = (const float*)d_in[19];

    char* ws = (char*)d_ws;
    size_t off = 0;
    auto alloc = [&](size_t bytes) { void* p = ws + off; off = (off + bytes + 255) & ~(size_t)255; return p; };
    int*   deg    = (int*)alloc((size_t)NN * 4);
    int*   cursor = (int*)alloc((size_t)NN * 4);
    int*   offs   = (int*)alloc((size_t)(NN + 1) * 4);
    int*   bsum   = (int*)alloc((size_t)64 * 4);
    int*   csr_src= (int*)alloc((size_t)NE * 4);
    int*   epos   = (int*)alloc((size_t)NE * 4);
    float* logdeg = (float*)alloc((size_t)NN * 4);
    unsigned short* Qh  = (unsigned short*)alloc((size_t)NN * 128 * 2);
    unsigned short* Kh  = (unsigned short*)alloc((size_t)NN * 128 * 2);
    unsigned short* Vh  = (unsigned short*)alloc((size_t)NN * 128 * 2);
    unsigned short* Qh2 = (unsigned short*)alloc((size_t)NN * 128 * 2);
    unsigned short* Kh2 = (unsigned short*)alloc((size_t)NN * 128 * 2);
    unsigned short* Vh2 = (unsigned short*)alloc((size_t)NN * 128 * 2);
    unsigned short* e_t = (unsigned short*)alloc((size_t)NE * 128 * 2);
    unsigned short* ea_bf = (unsigned short*)alloc((size_t)NE * 128 * 2);
    float* sc     = (float*)alloc((size_t)NE * 8 * 4);
    float* wV     = (float*)alloc((size_t)NN * 128 * 4);
    float* rowV   = (float*)alloc((size_t)NN * 128 * 4);
    short* Wep    = (short*)alloc((size_t)2 * 128 * 256 * 2);
    short* Woep   = (short*)alloc((size_t)2 * 128 * 128 * 2);
    short* Wqp    = (short*)alloc((size_t)2 * 128 * 128 * 2);
    short* Wkp    = (short*)alloc((size_t)2 * 128 * 128 * 2);
    short* Wvp    = (short*)alloc((size_t)2 * 128 * 128 * 2);
    short* Wohp   = (short*)alloc((size_t)2 * 128 * 128 * 2);
    short* W1p    = (short*)alloc((size_t)2 * 128 * 256 * 2);
    short* W2p    = (short*)alloc((size_t)2 * 256 * 128 * 2);
    short* VRp    = (short*)alloc((size_t)2 * 128 * 128 * 2);

    float* out_x = (float*)d_out;
    float* out_e = out_x + (size_t)NN * 128;

    hipError_t err;
    err = hipMemsetAsync(deg, 0, (size_t)NN * 4, stream); (void)err;
    err = hipMemsetAsync(cursor, 0, (size_t)NN * 4, stream); (void)err;

    k_deg<<<(NE + 255) / 256, 256, 0, stream>>>(ei, deg);
    k_scan1<<<NBLK, 1024, 0, stream>>>(deg, offs, bsum, logdeg);
    k_scan2<<<1, 64, 0, stream>>>(bsum);
    k_scan3<<<NBLK, 1024, 0, stream>>>(offs, bsum);
    k_fill<<<(NE + 255) / 256, 256, 0, stream>>>(ei, offs, cursor, csr_src, epos);
    k_packAll<<<1536, 256, 0, stream>>>(We, Woe, Wq, Wk, Wv, Woh, W1, W2, VeRow,
                                        Wep, Woep, Wqp, Wkp, Wvp, Wohp, W1p, W2p, VRp);

    // ---- layer 0 ----
    k_qkv<<<(NN + 63) / 64, 512, 0, stream>>>(x_in0, Wqp, bq, Wkp, Wvp, Qh, Kh, Vh);
    k_edgeA<true><<<NE / 64, 512, 0, stream>>>(ea_in0, ei, epos, Wep, be, Aw, Qh, Kh,
                                               e_t, sc, Woep, boe, ea_bf);
    k_nattn<<<NN, 64, 0, stream>>>(offs, csr_src, sc, e_t, Vh, wV, rowV);
    k_nodeB<true><<<(NN + 63) / 64, 512, 0, stream>>>(
        wV, rowV, VRp, dc, logdeg, x_in0,
        Wohp, boh, W1p, b1, W2p, b2, out_x,
        Wqp + 128 * 128, bq + 128, Wkp + 128 * 128, Wvp + 128 * 128, Qh2, Kh2, Vh2);

    // ---- layer 1 ----
    k_edgeA<false><<<NE / 64, 512, 0, stream>>>(ea_bf, ei, epos, Wep + 128 * 256, be + 256,
                                                Aw + 128, Qh2, Kh2, e_t, sc,
                                                Woep + 128 * 128, boe + 128, out_e);
    k_nattn<<<NN, 64, 0, stream>>>(offs, csr_src, sc, e_t, Vh2, wV, rowV);
    k_nodeB<false><<<(NN + 63) / 64, 512, 0, stream>>>(
        wV, rowV, VRp + 128 * 128, dc + 256, logdeg, out_x,
        Wohp + 128 * 128, boh + 128, W1p + 128 * 256, b1 + 256, W2p + 256 * 128, b2 + 128, out_x,
        nullptr, nullptr, nullptr, nullptr, nullptr, nullptr, nullptr);
}

// Round 12
// 1034.711 us; speedup vs baseline: 1.6072x; 1.0166x over previous
//
#include <hip/hip_runtime.h>

#define NN 50000
#define NE 800000
#define CLAMPV 5.0f
#define BNS 0.9999950000374997f
#define EPKS 132   // int stride of packed Ep rows
#define NBLK 49    // ceil(NN/1024)

typedef __attribute__((ext_vector_type(8))) short s16x8;
typedef __attribute__((ext_vector_type(8))) __bf16 bf16x8;
typedef __attribute__((ext_vector_type(4))) float f32x4;

__device__ inline f32x4 mfma16(s16x8 a, s16x8 b, f32x4 c) {
    return __builtin_amdgcn_mfma_f32_16x16x32_bf16(
        __builtin_bit_cast(bf16x8, a), __builtin_bit_cast(bf16x8, b), c, 0, 0, 0);
}

__device__ inline unsigned short bf16r(float f) {
    return __builtin_bit_cast(unsigned short, (__bf16)f);
}

__device__ inline int pk2(float a, float b) {
    return (int)(unsigned)bf16r(a) | ((int)(unsigned)bf16r(b) << 16);
}

__device__ inline float b2f(unsigned short u) {
    return __builtin_bit_cast(float, (unsigned)u << 16);
}

// ---------------- degree / CSR build ----------------

__global__ __launch_bounds__(256) void k_deg(const int* __restrict__ ei, int* __restrict__ deg) {
    int e = blockIdx.x * 256 + threadIdx.x;
    if (e < NE) atomicAdd(&deg[ei[NE + e]], 1);
}

__global__ __launch_bounds__(1024) void k_scan1(const int* __restrict__ deg, int* __restrict__ offs,
                                                int* __restrict__ bsum, float* __restrict__ logdeg) {
    __shared__ int sm[1024];
    int i = blockIdx.x * 1024 + threadIdx.x;
    int v = (i < NN) ? deg[i] : 0;
    if (i < NN) logdeg[i] = logf((float)v + 1.0f);
    sm[threadIdx.x] = v;
    __syncthreads();
    for (int s = 1; s < 1024; s <<= 1) {
        int t = (threadIdx.x >= s) ? sm[threadIdx.x - s] : 0;
        __syncthreads();
        sm[threadIdx.x] += t;
        __syncthreads();
    }
    if (i < NN) offs[i + 1] = sm[threadIdx.x];
    if (threadIdx.x == 1023) bsum[blockIdx.x] = sm[1023];
    if (blockIdx.x == 0 && threadIdx.x == 0) offs[0] = 0;
}

__global__ void k_scan2(int* __restrict__ bsum) {
    if (threadIdx.x == 0) {
        int acc = 0;
        for (int i = 0; i < NBLK; ++i) { int v = bsum[i]; bsum[i] = acc; acc += v; }
    }
}

__global__ __launch_bounds__(1024) void k_scan3(int* __restrict__ offs, const int* __restrict__ bsum) {
    int i = blockIdx.x * 1024 + threadIdx.x;
    if (i < NN) offs[i + 1] += bsum[blockIdx.x];
}

__global__ __launch_bounds__(256) void k_fill(const int* __restrict__ ei, const int* __restrict__ offs,
                                              int* __restrict__ cursor, int* __restrict__ csr_src,
                                              int* __restrict__ epos) {
    int e = blockIdx.x * 256 + threadIdx.x;
    if (e < NE) {
        int d = ei[NE + e];
        int pos = offs[d] + atomicAdd(&cursor[d], 1);
        csr_src[pos] = ei[e];
        epos[e] = pos;
    }
}

// One launch packs ALL weights (both layers) into MFMA B-fragment order.
#define PL_A (128*256)
#define PL_B (128*128)
__global__ __launch_bounds__(256) void k_packAll(
    const float* __restrict__ We,  const float* __restrict__ Woe, const float* __restrict__ Wq,
    const float* __restrict__ Wk,  const float* __restrict__ Wv,  const float* __restrict__ Woh,
    const float* __restrict__ W1,  const float* __restrict__ W2,  const float* __restrict__ VR,
    short* __restrict__ Wep,  short* __restrict__ Woep, short* __restrict__ Wqp,
    short* __restrict__ Wkp,  short* __restrict__ Wvp,  short* __restrict__ Wohp,
    short* __restrict__ W1p,  short* __restrict__ W2p,  short* __restrict__ VRp) {
    int s = blockIdx.x * 256 + threadIdx.x;
    const float* W; short* out; int ncol, perL; bool vr = false;
    if (s < 2 * PL_A) { W = We; out = Wep; ncol = 256; perL = PL_A; }
    else if ((s -= 2 * PL_A) < 2 * PL_B) { W = Woe; out = Woep; ncol = 128; perL = PL_B; }
    else if ((s -= 2 * PL_B) < 2 * PL_B) { W = Wq;  out = Wqp;  ncol = 128; perL = PL_B; }
    else if ((s -= 2 * PL_B) < 2 * PL_B) { W = Wk;  out = Wkp;  ncol = 128; perL = PL_B; }
    else if ((s -= 2 * PL_B) < 2 * PL_B) { W = Wv;  out = Wvp;  ncol = 128; perL = PL_B; }
    else if ((s -= 2 * PL_B) < 2 * PL_B) { W = Woh; out = Wohp; ncol = 128; perL = PL_B; }
    else if ((s -= 2 * PL_B) < 2 * PL_A) { W = W1;  out = W1p;  ncol = 256; perL = PL_A; }
    else if ((s -= 2 * PL_A) < 2 * PL_A) { W = W2;  out = W2p;  ncol = 128; perL = PL_A; }
    else if ((s -= 2 * PL_A) < 2 * PL_B) { W = VR;  out = VRp;  ncol = 128; perL = PL_B; vr = true; }
    else return;
    int l = s / perL, q = s % perL;
    int j = q & 7; int t2 = q >> 3; int kg = t2 & 3; t2 >>= 2;
    int col = t2 % ncol; int kt = t2 / ncol;
    int k = kt * 32 + kg * 8 + j;
    float v;
    if (vr) v = ((k >> 4) == (col >> 4)) ? VR[l * 2048 + (k & 15) * 128 + col] : 0.f;
    else    v = W[(size_t)l * perL + k * ncol + col];
    out[(size_t)l * perL + q] = (short)bf16r(v);
}

// ---------------- per-layer kernels ----------------

// Q/K/V via MFMA: 64 nodes/block, 512 threads (8 waves). Layer 0 only.
__global__ __launch_bounds__(512) void k_qkv(const float* __restrict__ x,
                                             const short* __restrict__ Wqp, const float* __restrict__ bq,
                                             const short* __restrict__ Wkp, const short* __restrict__ Wvp,
                                             unsigned short* __restrict__ Qh, unsigned short* __restrict__ Kh,
                                             unsigned short* __restrict__ Vh) {
    __shared__ short xsw[64 * 128];
    int t = threadIdx.x;
    int ci = t & 15, r0 = t >> 4;
    int n0 = blockIdx.x * 64;
    for (int rr = r0; rr < 64; rr += 32) {
        int n = n0 + rr;
        int4 pkv = make_int4(0, 0, 0, 0);
        if (n < NN) {
            const float4* src = (const float4*)(x + (size_t)n * 128 + ci * 8);
            float4 v0 = src[0], v1 = src[1];
            pkv.x = pk2(v0.x, v0.y); pkv.y = pk2(v0.z, v0.w);
            pkv.z = pk2(v1.x, v1.y); pkv.w = pk2(v1.z, v1.w);
        }
        int byte = (rr * 256 + ci * 16) ^ ((rr & 7) << 4);
        *(int4*)((char*)xsw + byte) = pkv;
    }
    __syncthreads();
    int lane = t & 63, w = t >> 6;
    int l15 = lane & 15, kg = lane >> 4;
    f32x4 acc[4][3];
#pragma unroll
    for (int m = 0; m < 4; ++m)
#pragma unroll
        for (int q = 0; q < 3; ++q) { acc[m][q][0] = 0.f; acc[m][q][1] = 0.f; acc[m][q][2] = 0.f; acc[m][q][3] = 0.f; }
    int col = w * 16 + l15;
#pragma unroll
    for (int kt = 0; kt < 4; ++kt) {
        s16x8 a[4];
#pragma unroll
        for (int m = 0; m < 4; ++m) {
            int row = m * 16 + l15;
            int abyte = (row * 256 + kt * 64 + kg * 16) ^ ((l15 & 7) << 4);
            a[m] = *(const s16x8*)((const char*)xsw + abyte);
        }
        size_t bo = ((size_t)((kt * 128 + col) * 4 + kg)) * 8;
        s16x8 bqf = *(const s16x8*)(Wqp + bo);
        s16x8 bkf = *(const s16x8*)(Wkp + bo);
        s16x8 bvf = *(const s16x8*)(Wvp + bo);
#pragma unroll
        for (int m = 0; m < 4; ++m) {
            acc[m][0] = mfma16(a[m], bqf, acc[m][0]);
            acc[m][1] = mfma16(a[m], bkf, acc[m][1]);
            acc[m][2] = mfma16(a[m], bvf, acc[m][2]);
        }
    }
    float bqv = bq[col];
#pragma unroll
    for (int m = 0; m < 4; ++m)
#pragma unroll
        for (int i = 0; i < 4; ++i) {
            int n = n0 + m * 16 + kg * 4 + i;
            if (n < NN) {
                Qh[(size_t)n * 128 + col] = bf16r(acc[m][0][i] + bqv);
                Kh[(size_t)n * 128 + col] = bf16r(acc[m][1][i]);
                Vh[(size_t)n * 128 + col] = bf16r(acc[m][2][i]);
            }
        }
}

// Fused edge kernel: 64 edges/block, 512 threads (8 waves). epk/ets share LDS. (no setprio)
template<bool IN_F32>
__global__ __launch_bounds__(512) void k_edgeA(const void* __restrict__ ea_, const int* __restrict__ ei,
                                               const int* __restrict__ epos,
                                               const short* __restrict__ Wep, const float* __restrict__ be,
                                               const float* __restrict__ Aw,
                                               const unsigned short* __restrict__ Qh,
                                               const unsigned short* __restrict__ Kh,
                                               unsigned short* __restrict__ e_t, float* __restrict__ sc,
                                               const short* __restrict__ Woep, const float* __restrict__ boe,
                                               void* __restrict__ eout_) {
    __shared__ short eas[64 * 128];
    __shared__ int epts[64 * EPKS];
    const float* eaf = (const float*)ea_;
    const unsigned short* eab = (const unsigned short*)ea_;
    unsigned short* eout_b = (unsigned short*)eout_;
    float* eout_f = (float*)eout_;

    int e0 = blockIdx.x * 64;
    int t = threadIdx.x;
    int ci = t & 15, r0 = t >> 4;
    int eA = e0 + r0, eB = eA + 32;
    int siA = ei[eA], diA = ei[NE + eA], posA = epos[eA];
    int siB = ei[eB], diB = ei[NE + eB], posB = epos[eB];

    {   // phase 1: stage ea -> bf16 swizzled
#pragma unroll
        for (int h = 0; h < 2; ++h) {
            int rr = r0 + h * 32;
            int4 pkv;
            if (IN_F32) {
                const float4* src = (const float4*)(eaf + (size_t)(e0 + rr) * 128 + ci * 8);
                float4 v0 = src[0], v1 = src[1];
                pkv.x = pk2(v0.x, v0.y); pkv.y = pk2(v0.z, v0.w);
                pkv.z = pk2(v1.x, v1.y); pkv.w = pk2(v1.z, v1.w);
            } else {
                pkv = *(const int4*)(eab + (size_t)(e0 + rr) * 128 + ci * 8);
            }
            int byte = (rr * 256 + ci * 16) ^ ((rr & 7) << 4);
            *(int4*)((char*)eas + byte) = pkv;
        }
    }
    __syncthreads();
    union { int4 v; unsigned short us[8]; } kuA, quA, kuB, quB;
    kuA.v = *(const int4*)(Kh + (size_t)siA * 128 + ci * 8);
    quA.v = *(const int4*)(Qh + (size_t)diA * 128 + ci * 8);
    kuB.v = *(const int4*)(Kh + (size_t)siB * 128 + ci * 8);
    quB.v = *(const int4*)(Qh + (size_t)diB * 128 + ci * 8);

    int lane = t & 63, w = t >> 6;
    int l15 = lane & 15, kg = lane >> 4;
    {   // phase 2: Ep = eas @ We + be
        f32x4 acc[4][2];
#pragma unroll
        for (int m = 0; m < 4; ++m)
#pragma unroll
            for (int q = 0; q < 2; ++q) { acc[m][q][0] = 0.f; acc[m][q][1] = 0.f; acc[m][q][2] = 0.f; acc[m][q][3] = 0.f; }
#pragma unroll
        for (int kt = 0; kt < 4; ++kt) {
            s16x8 a[4];
#pragma unroll
            for (int m = 0; m < 4; ++m) {
                int row = m * 16 + l15;
                int abyte = (row * 256 + kt * 64 + kg * 16) ^ ((l15 & 7) << 4);
                a[m] = *(const s16x8*)((const char*)eas + abyte);
            }
#pragma unroll
            for (int q = 0; q < 2; ++q) {
                int col = w * 32 + q * 16 + l15;
                s16x8 b = *(const s16x8*)(Wep + ((size_t)((kt * 256 + col) * 4 + kg)) * 8);
#pragma unroll
                for (int m = 0; m < 4; ++m) acc[m][q] = mfma16(a[m], b, acc[m][q]);
            }
        }
        float bw = be[w * 32 + l15], bb = be[w * 32 + 16 + l15];
#pragma unroll
        for (int m = 0; m < 4; ++m)
#pragma unroll
            for (int i = 0; i < 4; ++i) {
                int row = m * 16 + kg * 4 + i;
                epts[row * EPKS + w * 16 + l15] = pk2(acc[m][0][i] + bw, acc[m][1][i] + bb);
            }
    }
    __syncthreads();
    int4 wA0, wA1, wB0, wB1;
    {
        const int4* pA = (const int4*)(epts + r0 * EPKS + ci * 8);
        wA0 = pA[0]; wA1 = pA[1];
        const int4* pB = (const int4*)(epts + (r0 + 32) * EPKS + ci * 8);
        wB0 = pB[0]; wB1 = pB[1];
    }
    __syncthreads();
    {   // phase 3: elementwise
        int hh = ci >> 1, dbase = (ci & 1) * 8;
        float aw[8];
#pragma unroll
        for (int j = 0; j < 8; ++j) aw[j] = Aw[(dbase + j) * 8 + hh];
#pragma unroll
        for (int h = 0; h < 2; ++h) {
            int r = r0 + h * 32;
            int pos = h ? posB : posA;
            const unsigned short* kus = h ? kuB.us : kuA.us;
            const unsigned short* qus = h ? quB.us : quA.us;
            const int4 w0 = h ? wB0 : wA0;
            const int4 w1 = h ? wB1 : wA1;
            int prs[8] = {w0.x, w0.y, w0.z, w0.w, w1.x, w1.y, w1.z, w1.w};
            float p = 0.f;
            float etv[8];
#pragma unroll
            for (int j = 0; j < 8; ++j) {
                int pr = prs[j];
                float ew = b2f((unsigned short)pr);
                float ebv = b2f((unsigned short)((unsigned)pr >> 16));
                float kq = b2f(kus[j]) + b2f(qus[j]);
                float sv = kq * ew;
                float ss = copysignf(sqrtf(fabsf(sv)), sv);
                float et = fmaxf(ss + ebv, 0.f);
                etv[j] = et;
                p += et * aw[j];
            }
            int4 pkv;
            pkv.x = pk2(etv[0], etv[1]); pkv.y = pk2(etv[2], etv[3]);
            pkv.z = pk2(etv[4], etv[5]); pkv.w = pk2(etv[6], etv[7]);
            *(int4*)(e_t + (size_t)pos * 128 + ci * 8) = pkv;
            int byte = (r * 256 + ci * 16) ^ ((r & 7) << 4);
            *(int4*)((char*)epts + byte) = pkv;
            p += __shfl_xor(p, 1);
            if ((ci & 1) == 0) {
                float s = fminf(fmaxf(p, -CLAMPV), CLAMPV);
                sc[(size_t)pos * 8 + hh] = s;
            }
        }
    }
    __syncthreads();
    {   // phase 4: e_out = (ea + ets @ Woe + boe) * BNS
        f32x4 acc[4];
#pragma unroll
        for (int m = 0; m < 4; ++m) { acc[m][0] = 0.f; acc[m][1] = 0.f; acc[m][2] = 0.f; acc[m][3] = 0.f; }
        int col = w * 16 + l15;
#pragma unroll
        for (int kt = 0; kt < 4; ++kt) {
            s16x8 a[4];
#pragma unroll
            for (int m = 0; m < 4; ++m) {
                int row = m * 16 + l15;
                int abyte = (row * 256 + kt * 64 + kg * 16) ^ ((l15 & 7) << 4);
                a[m] = *(const s16x8*)((const char*)epts + abyte);
            }
            s16x8 b = *(const s16x8*)(Woep + ((size_t)((kt * 128 + col) * 4 + kg)) * 8);
#pragma unroll
            for (int m = 0; m < 4; ++m) acc[m] = mfma16(a[m], b, acc[m]);
        }
        float bb = boe[col];
#pragma unroll
        for (int m = 0; m < 4; ++m)
#pragma unroll
            for (int i = 0; i < 4; ++i) {
                int rr = m * 16 + kg * 4 + i;
                int rbyte = (rr * 256 + col * 2) ^ ((rr & 7) << 4);
                float res = b2f(*(const unsigned short*)((const char*)eas + rbyte));
                size_t idx = (size_t)(e0 + rr) * 128 + col;
                float v = (res + acc[m][i] + bb) * BNS;
                if (IN_F32) eout_b[idx] = bf16r(v);
                else        eout_f[idx] = v;
            }
    }
}

// Node attention: one 64-lane wave per node. sc/e_t in CSR order -> coalesced.
__global__ __launch_bounds__(64) void k_nattn(const int* __restrict__ offs, const int* __restrict__ csr_src,
                                              const float* __restrict__ sc,
                                              const unsigned short* __restrict__ e_t,
                                              const unsigned short* __restrict__ Vh,
                                              float* __restrict__ wV, float* __restrict__ rowV) {
    int n = blockIdx.x;
    int lane = threadIdx.x;
    int beg = offs[n], end = offs[n + 1];
    int h = lane & 7, es = lane >> 3;
    float m = -1e30f;
    for (int i = beg + es; i < end; i += 8)
        m = fmaxf(m, sc[(size_t)i * 8 + h]);
#pragma unroll
    for (int off = 8; off < 64; off <<= 1) m = fmaxf(m, __shfl_xor(m, off));
    float dsum = 0.0f;
    for (int i = beg + es; i < end; i += 8)
        dsum += expf(sc[(size_t)i * 8 + h] - m);
#pragma unroll
    for (int off = 8; off < 64; off <<= 1) dsum += __shfl_xor(dsum, off);
    float inv_d = 1.0f / (dsum + 1e-16f);

    int hv = lane >> 3;
    float mv = __shfl(m, hv);
    float idv = __shfl(inv_d, hv);
    float av0 = 0.0f, av1 = 0.0f, ar0 = 0.0f, ar1 = 0.0f;
    for (int i = beg; i < end; ++i) {
        float a = expf(sc[(size_t)i * 8 + hv] - mv) * idv;
        int s = csr_src[i];
        int v = ((const int*)Vh)[(size_t)s * 64 + lane];
        int u = ((const int*)e_t)[(size_t)i * 64 + lane];
        av0 += b2f((unsigned short)v) * a;
        av1 += b2f((unsigned short)((unsigned)v >> 16)) * a;
        ar0 += b2f((unsigned short)u) * a;
        ar1 += b2f((unsigned short)((unsigned)u >> 16)) * a;
    }
    *(float2*)(wV + (size_t)n * 128 + 2 * lane)   = make_float2(av0, av1);
    *(float2*)(rowV + (size_t)n * 128 + 2 * lane) = make_float2(ar0, ar1);
}

// Node post via MFMA: 32 nodes/block, 256 threads (4 waves), LDS 24 KB -> ~6 blocks/CU.
// Wave w owns cols w*32..w*32+31 (2 col-tiles) in 128-col phases; w*64..+63 (4 tiles) in p3.
template<bool EMIT>
__global__ __launch_bounds__(256) void k_nodeB(
    const float* __restrict__ wV, const float* __restrict__ rowV,
    const short* __restrict__ VRp, const float* __restrict__ dc,
    const float* __restrict__ logdeg, const float* __restrict__ x,
    const short* __restrict__ Wohp, const float* __restrict__ boh,
    const short* __restrict__ W1p, const float* __restrict__ b1,
    const short* __restrict__ W2p, const float* __restrict__ b2,
    float* __restrict__ xout,
    const short* __restrict__ Wqp2, const float* __restrict__ bq2,
    const short* __restrict__ Wkp2, const short* __restrict__ Wvp2,
    unsigned short* __restrict__ Qh2, unsigned short* __restrict__ Kh2,
    unsigned short* __restrict__ Vh2) {
    __shared__ short bufA[32 * 128];   // rowV staging / h1 / out (8 KB)
    __shared__ short bufU[32 * 256];   // hs / us (16 KB)
    int n0 = blockIdx.x * 32;
    int t = threadIdx.x;
    int ci = t & 15, r0 = t >> 4;      // r0 in 0..15
    {   // p0: stage rowV -> bufA bf16 swizzled (rows r0, r0+16)
#pragma unroll
        for (int h = 0; h < 2; ++h) {
            int rr = r0 + h * 16, n = n0 + rr;
            int4 pkv = make_int4(0, 0, 0, 0);
            if (n < NN) {
                const float4* src = (const float4*)(rowV + (size_t)n * 128 + ci * 8);
                float4 v0 = src[0], v1 = src[1];
                pkv.x = pk2(v0.x, v0.y); pkv.y = pk2(v0.z, v0.w);
                pkv.z = pk2(v1.x, v1.y); pkv.w = pk2(v1.z, v1.w);
            }
            int byte = (rr * 256 + ci * 16) ^ ((rr & 7) << 4);
            *(int4*)((char*)bufA + byte) = pkv;
        }
    }
    __syncthreads();
    int lane = t & 63, w = t >> 6;     // w in 0..3
    int l15 = lane & 15, kg = lane >> 4;
    int cq[2] = {w * 32 + l15, w * 32 + 16 + l15};
    {   // p1: hs = (wV + rowV@VeRowBD) * degscale -> bufU (256B-stride layout)
        f32x4 acc[2][2];
#pragma unroll
        for (int m = 0; m < 2; ++m)
#pragma unroll
            for (int q = 0; q < 2; ++q)
#pragma unroll
                for (int i = 0; i < 4; ++i) {
                    int n = n0 + m * 16 + kg * 4 + i;
                    acc[m][q][i] = (n < NN) ? wV[(size_t)n * 128 + cq[q]] : 0.f;
                }
#pragma unroll
        for (int kt = 0; kt < 4; ++kt) {
            s16x8 a[2];
#pragma unroll
            for (int m = 0; m < 2; ++m) {
                int row = m * 16 + l15;
                int abyte = (row * 256 + kt * 64 + kg * 16) ^ ((l15 & 7) << 4);
                a[m] = *(const s16x8*)((const char*)bufA + abyte);
            }
#pragma unroll
            for (int q = 0; q < 2; ++q) {
                s16x8 b = *(const s16x8*)(VRp + ((size_t)((kt * 128 + cq[q]) * 4 + kg)) * 8);
#pragma unroll
                for (int m = 0; m < 2; ++m) acc[m][q] = mfma16(a[m], b, acc[m][q]);
            }
        }
#pragma unroll
        for (int q = 0; q < 2; ++q) {
            float d0 = dc[cq[q] * 2], d1 = dc[cq[q] * 2 + 1];
#pragma unroll
            for (int m = 0; m < 2; ++m)
#pragma unroll
                for (int i = 0; i < 4; ++i) {
                    int rr = m * 16 + kg * 4 + i, n = n0 + rr;
                    float ld = (n < NN) ? logdeg[n] : 0.f;
                    float hs = acc[m][q][i] * (d0 + ld * d1);
                    int byte = (rr * 256 + cq[q] * 2) ^ ((rr & 7) << 4);
                    *(unsigned short*)((char*)bufU + byte) = bf16r(hs);
                }
        }
    }
    __syncthreads();
    float h1r[2][2][4];
    {   // p2: h1 = (x + hs@Woh + boh)*BNS -> bufA + regs
        f32x4 acc[2][2];
#pragma unroll
        for (int m = 0; m < 2; ++m)
#pragma unroll
            for (int q = 0; q < 2; ++q) { acc[m][q][0] = 0.f; acc[m][q][1] = 0.f; acc[m][q][2] = 0.f; acc[m][q][3] = 0.f; }
#pragma unroll
        for (int kt = 0; kt < 4; ++kt) {
            s16x8 a[2];
#pragma unroll
            for (int m = 0; m < 2; ++m) {
                int row = m * 16 + l15;
                int abyte = (row * 256 + kt * 64 + kg * 16) ^ ((l15 & 7) << 4);
                a[m] = *(const s16x8*)((const char*)bufU + abyte);
            }
#pragma unroll
            for (int q = 0; q < 2; ++q) {
                s16x8 b = *(const s16x8*)(Wohp + ((size_t)((kt * 128 + cq[q]) * 4 + kg)) * 8);
#pragma unroll
                for (int m = 0; m < 2; ++m) acc[m][q] = mfma16(a[m], b, acc[m][q]);
            }
        }
#pragma unroll
        for (int q = 0; q < 2; ++q) {
            float bb = boh[cq[q]];
#pragma unroll
            for (int m = 0; m < 2; ++m)
#pragma unroll
                for (int i = 0; i < 4; ++i) {
                    int rr = m * 16 + kg * 4 + i, n = n0 + rr;
                    float xv = (n < NN) ? x[(size_t)n * 128 + cq[q]] : 0.f;
                    float h1 = (xv + acc[m][q][i] + bb) * BNS;
                    h1r[m][q][i] = h1;
                    int byte = (rr * 256 + cq[q] * 2) ^ ((rr & 7) << 4);
                    *(unsigned short*)((char*)bufA + byte) = bf16r(h1);
                }
        }
    }
    __syncthreads();
    {   // p3: us = relu(h1@W1 + b1) -> bufU (512B-stride layout); wave w owns cols w*64..+63
        f32x4 acc[2][4];
#pragma unroll
        for (int m = 0; m < 2; ++m)
#pragma unroll
            for (int q = 0; q < 4; ++q) { acc[m][q][0] = 0.f; acc[m][q][1] = 0.f; acc[m][q][2] = 0.f; acc[m][q][3] = 0.f; }
#pragma unroll
        for (int kt = 0; kt < 4; ++kt) {
            s16x8 a[2];
#pragma unroll
            for (int m = 0; m < 2; ++m) {
                int row = m * 16 + l15;
                int abyte = (row * 256 + kt * 64 + kg * 16) ^ ((l15 & 7) << 4);
                a[m] = *(const s16x8*)((const char*)bufA + abyte);
            }
#pragma unroll
            for (int q = 0; q < 4; ++q) {
                int colq = w * 64 + q * 16 + l15;
                s16x8 b = *(const s16x8*)(W1p + ((size_t)((kt * 256 + colq) * 4 + kg)) * 8);
#pragma unroll
                for (int m = 0; m < 2; ++m) acc[m][q] = mfma16(a[m], b, acc[m][q]);
            }
        }
        __syncthreads();   // hs reads (p2) complete before us overwrites bufU
#pragma unroll
        for (int q = 0; q < 4; ++q) {
            int colq = w * 64 + q * 16 + l15;
            float bb = b1[colq];
#pragma unroll
            for (int m = 0; m < 2; ++m)
#pragma unroll
                for (int i = 0; i < 4; ++i) {
                    int rr = m * 16 + kg * 4 + i;
                    float us = fmaxf(acc[m][q][i] + bb, 0.f);
                    int byte = (rr * 512 + colq * 2) ^ ((rr & 7) << 4);
                    *(unsigned short*)((char*)bufU + byte) = bf16r(us);
                }
        }
    }
    __syncthreads();
    {   // p4: out = (h1 + us@W2 + b2)*BNS; EMIT: stage out bf16 into bufA
        f32x4 acc[2][2];
#pragma unroll
        for (int m = 0; m < 2; ++m)
#pragma unroll
            for (int q = 0; q < 2; ++q) { acc[m][q][0] = 0.f; acc[m][q][1] = 0.f; acc[m][q][2] = 0.f; acc[m][q][3] = 0.f; }
#pragma unroll
        for (int kt = 0; kt < 8; ++kt) {
            s16x8 a[2];
#pragma unroll
            for (int m = 0; m < 2; ++m) {
                int row = m * 16 + l15;
                int abyte = (row * 512 + kt * 64 + kg * 16) ^ ((l15 & 7) << 4);
                a[m] = *(const s16x8*)((const char*)bufU + abyte);
            }
#pragma unroll
            for (int q = 0; q < 2; ++q) {
                s16x8 b = *(const s16x8*)(W2p + ((size_t)((kt * 128 + cq[q]) * 4 + kg)) * 8);
#pragma unroll
                for (int m = 0; m < 2; ++m) acc[m][q] = mfma16(a[m], b, acc[m][q]);
            }
        }
#pragma unroll
        for (int q = 0; q < 2; ++q) {
            float bb = b2[cq[q]];
#pragma unroll
            for (int m = 0; m < 2; ++m)
#pragma unroll
                for (int i = 0; i < 4; ++i) {
                    int rr = m * 16 + kg * 4 + i, n = n0 + rr;
                    float outv = (h1r[m][q][i] + acc[m][q][i] + bb) * BNS;
                    if (n < NN) xout[(size_t)n * 128 + cq[q]] = outv;
                    if (EMIT) {
                        int byte = (rr * 256 + cq[q] * 2) ^ ((rr & 7) << 4);
                        *(unsigned short*)((char*)bufA + byte) = bf16r(outv);
                    }
                }
        }
    }
    if (EMIT) {   // next-layer Q/K/V from staged out
        __syncthreads();
        f32x4 acc[2][2][3];
#pragma unroll
        for (int m = 0; m < 2; ++m)
#pragma unroll
            for (int q = 0; q < 2; ++q)
#pragma unroll
                for (int o = 0; o < 3; ++o) { acc[m][q][o][0] = 0.f; acc[m][q][o][1] = 0.f; acc[m][q][o][2] = 0.f; acc[m][q][o][3] = 0.f; }
#pragma unroll
        for (int kt = 0; kt < 4; ++kt) {
            s16x8 a[2];
#pragma unroll
            for (int m = 0; m < 2; ++m) {
                int row = m * 16 + l15;
                int abyte = (row * 256 + kt * 64 + kg * 16) ^ ((l15 & 7) << 4);
                a[m] = *(const s16x8*)((const char*)bufA + abyte);
            }
#pragma unroll
            for (int q = 0; q < 2; ++q) {
                size_t bo = ((size_t)((kt * 128 + cq[q]) * 4 + kg)) * 8;
                s16x8 bqf = *(const s16x8*)(Wqp2 + bo);
                s16x8 bkf = *(const s16x8*)(Wkp2 + bo);
                s16x8 bvf = *(const s16x8*)(Wvp2 + bo);
#pragma unroll
                for (int m = 0; m < 2; ++m) {
                    acc[m][q][0] = mfma16(a[m], bqf, acc[m][q][0]);
                    acc[m][q][1] = mfma16(a[m], bkf, acc[m][q][1]);
                    acc[m][q][2] = mfma16(a[m], bvf, acc[m][q][2]);
                }
            }
        }
#pragma unroll
        for (int q = 0; q < 2; ++q) {
            float bqv = bq2[cq[q]];
#pragma unroll
            for (int m = 0; m < 2; ++m)
#pragma unroll
                for (int i = 0; i < 4; ++i) {
                    int n = n0 + m * 16 + kg * 4 + i;
                    if (n < NN) {
                        Qh2[(size_t)n * 128 + cq[q]] = bf16r(acc[m][q][0][i] + bqv);
                        Kh2[(size_t)n * 128 + cq[q]] = bf16r(acc[m][q][1][i]);
                        Vh2[(size_t)n * 128 + cq[q]] = bf16r(acc[m][q][2][i]);
                    }
                }
        }
    }
}

// ---------------- host launch ----------------

extern "C" void kernel_launch(void* const* d_in, const int* in_sizes, int n_in,
                              void* d_out, int out_size, void* d_ws, size_t ws_size,
                              hipStream_t stream) {
    (void)in_sizes; (void)n_in; (void)out_size; (void)ws_size;
    const float* x_in0  = (const float*)d_in[0];
    const int*   ei     = (const int*)d_in[1];
    const float* ea_in0 = (const float*)d_in[2];
    const float* Wq = (const float*)d_in[3];
    const float* bq = (const float*)d_in[4];
    const float* Wk = (const float*)d_in[5];
    const float* Wv = (const float*)d_in[6];
    const float* We = (const float*)d_in[7];
    const float* be = (const float*)d_in[8];
    const float* Aw = (const float*)d_in[9];
    const float* VeRow = (const float*)d_in[10];
    const float* Woh = (const float*)d_in[11];
    const float* boh = (const float*)d_in[12];
    const float* Woe = (const float*)d_in[13];
    const float* boe = (const float*)d_in[14];
    const float* dc  = (const float*)d_in[15];
    const float* W1 = (const float*)d_in[16];
    const float* b1 = (const float*)d_in[17];
    const float* W2 = (const float*)d_in[18];
    const float* b2 = (const float*)d_in[19];

    char* ws = (char*)d_ws;
    size_t off = 0;
    auto alloc = [&](size_t bytes) { void* p = ws + off; off = (off + bytes + 255) & ~(size_t)255; return p; };
    int*   deg    = (int*)alloc((size_t)NN * 4);
    int*   cursor = (int*)alloc((size_t)NN * 4);
    int*   offs   = (int*)alloc((size_t)(NN + 1) * 4);
    int*   bsum   = (int*)alloc((size_t)64 * 4);
    int*   csr_src= (int*)alloc((size_t)NE * 4);
    int*   epos   = (int*)alloc((size_t)NE * 4);
    float* logdeg = (float*)alloc((size_t)NN * 4);
    unsigned short* Qh  = (unsigned short*)alloc((size_t)NN * 128 * 2);
    unsigned short* Kh  = (unsigned short*)alloc((size_t)NN * 128 * 2);
    unsigned short* Vh  = (unsigned short*)alloc((size_t)NN * 128 * 2);
    unsigned short* Qh2 = (unsigned short*)alloc((size_t)NN * 128 * 2);
    unsigned short* Kh2 = (unsigned short*)alloc((size_t)NN * 128 * 2);
    unsigned short* Vh2 = (unsigned short*)alloc((size_t)NN * 128 * 2);
    unsigned short* e_t = (unsigned short*)alloc((size_t)NE * 128 * 2);
    unsigned short* ea_bf = (unsigned short*)alloc((size_t)NE * 128 * 2);
    float* sc     = (float*)alloc((size_t)NE * 8 * 4);
    float* wV     = (float*)alloc((size_t)NN * 128 * 4);
    float* rowV   = (float*)alloc((size_t)NN * 128 * 4);
    short* Wep    = (short*)alloc((size_t)2 * 128 * 256 * 2);
    short* Woep   = (short*)alloc((size_t)2 * 128 * 128 * 2);
    short* Wqp    = (short*)alloc((size_t)2 * 128 * 128 * 2);
    short* Wkp    = (short*)alloc((size_t)2 * 128 * 128 * 2);
    short* Wvp    = (short*)alloc((size_t)2 * 128 * 128 * 2);
    short* Wohp   = (short*)alloc((size_t)2 * 128 * 128 * 2);
    short* W1p    = (short*)alloc((size_t)2 * 128 * 256 * 2);
    short* W2p    = (short*)alloc((size_t)2 * 256 * 128 * 2);
    short* VRp    = (short*)alloc((size_t)2 * 128 * 128 * 2);

    float* out_x = (float*)d_out;
    float* out_e = out_x + (size_t)NN * 128;

    hipError_t err;
    err = hipMemsetAsync(deg, 0, (size_t)NN * 4, stream); (void)err;
    err = hipMemsetAsync(cursor, 0, (size_t)NN * 4, stream); (void)err;

    k_deg<<<(NE + 255) / 256, 256, 0, stream>>>(ei, deg);
    k_scan1<<<NBLK, 1024, 0, stream>>>(deg, offs, bsum, logdeg);
    k_scan2<<<1, 64, 0, stream>>>(bsum);
    k_scan3<<<NBLK, 1024, 0, stream>>>(offs, bsum);
    k_fill<<<(NE + 255) / 256, 256, 0, stream>>>(ei, offs, cursor, csr_src, epos);
    k_packAll<<<1536, 256, 0, stream>>>(We, Woe, Wq, Wk, Wv, Woh, W1, W2, VeRow,
                                        Wep, Woep, Wqp, Wkp, Wvp, Wohp, W1p, W2p, VRp);

    // ---- layer 0 ----
    k_qkv<<<(NN + 63) / 64, 512, 0, stream>>>(x_in0, Wqp, bq, Wkp, Wvp, Qh, Kh, Vh);
    k_edgeA<true><<<NE / 64, 512, 0, stream>>>(ea_in0, ei, epos, Wep, be, Aw, Qh, Kh,
                                               e_t, sc, Woep, boe, ea_bf);
    k_nattn<<<NN, 64, 0, stream>>>(offs, csr_src, sc, e_t, Vh, wV, rowV);
    k_nodeB<true><<<(NN + 31) / 32, 256, 0, stream>>>(
        wV, rowV, VRp, dc, logdeg, x_in0,
        Wohp, boh, W1p, b1, W2p, b2, out_x,
        Wqp + 128 * 128, bq + 128, Wkp + 128 * 128, Wvp + 128 * 128, Qh2, Kh2, Vh2);

    // ---- layer 1 ----
    k_edgeA<false><<<NE / 64, 512, 0, stream>>>(ea_bf, ei, epos, Wep + 128 * 256, be + 256,
                                                Aw + 128, Qh2, Kh2, e_t, sc,
                                                Woep + 128 * 128, boe + 128, out_e);
    k_nattn<<<NN, 64, 0, stream>>>(offs, csr_src, sc, e_t, Vh2, wV, rowV);
    k_nodeB<false><<<(NN + 31) / 32, 256, 0, stream>>>(
        wV, rowV, VRp + 128 * 128, dc + 256, logdeg, out_x,
        Wohp + 128 * 128, boh + 128, W1p + 128 * 256, b1 + 256, W2p + 256 * 128, b2 + 128, out_x,
        nullptr, nullptr, nullptr, nullptr, nullptr, nullptr, nullptr);
}

// Round 13
// 967.053 us; speedup vs baseline: 1.7197x; 1.0700x over previous
//
#include <hip/hip_runtime.h>

#define NN 50000
#define NE 800000
#define CLAMPV 5.0f
#define BNS 0.9999950000374997f
#define EPKS 132   // int stride of packed Ep rows
#define NBLK 49    // ceil(NN/1024)

typedef __attribute__((ext_vector_type(8))) short s16x8;
typedef __attribute__((ext_vector_type(8))) __bf16 bf16x8;
typedef __attribute__((ext_vector_type(4))) float f32x4;

__device__ inline f32x4 mfma16(s16x8 a, s16x8 b, f32x4 c) {
    return __builtin_amdgcn_mfma_f32_16x16x32_bf16(
        __builtin_bit_cast(bf16x8, a), __builtin_bit_cast(bf16x8, b), c, 0, 0, 0);
}

__device__ inline unsigned short bf16r(float f) {
    return __builtin_bit_cast(unsigned short, (__bf16)f);
}

__device__ inline int pk2(float a, float b) {
    return (int)(unsigned)bf16r(a) | ((int)(unsigned)bf16r(b) << 16);
}

__device__ inline float b2f(unsigned short u) {
    return __builtin_bit_cast(float, (unsigned)u << 16);
}

// ---------------- degree / CSR build ----------------

__global__ __launch_bounds__(256) void k_deg(const int* __restrict__ ei, int* __restrict__ deg) {
    int e = blockIdx.x * 256 + threadIdx.x;
    if (e < NE) atomicAdd(&deg[ei[NE + e]], 1);
}

__global__ __launch_bounds__(1024) void k_scan1(const int* __restrict__ deg, int* __restrict__ offs,
                                                int* __restrict__ bsum, float* __restrict__ logdeg) {
    __shared__ int sm[1024];
    int i = blockIdx.x * 1024 + threadIdx.x;
    int v = (i < NN) ? deg[i] : 0;
    if (i < NN) logdeg[i] = logf((float)v + 1.0f);
    sm[threadIdx.x] = v;
    __syncthreads();
    for (int s = 1; s < 1024; s <<= 1) {
        int t = (threadIdx.x >= s) ? sm[threadIdx.x - s] : 0;
        __syncthreads();
        sm[threadIdx.x] += t;
        __syncthreads();
    }
    if (i < NN) offs[i + 1] = sm[threadIdx.x];
    if (threadIdx.x == 1023) bsum[blockIdx.x] = sm[1023];
    if (blockIdx.x == 0 && threadIdx.x == 0) offs[0] = 0;
}

// scan2 folded in: each block serially sums its prefix of bsum (<=48 adds).
__global__ __launch_bounds__(1024) void k_scan3(int* __restrict__ offs, const int* __restrict__ bsum) {
    __shared__ int pre;
    if (threadIdx.x == 0) {
        int acc = 0;
        for (int i = 0; i < (int)blockIdx.x; ++i) acc += bsum[i];
        pre = acc;
    }
    __syncthreads();
    int i = blockIdx.x * 1024 + threadIdx.x;
    if (i < NN) offs[i + 1] += pre;
}

__global__ __launch_bounds__(256) void k_fill(const int* __restrict__ ei, const int* __restrict__ offs,
                                              int* __restrict__ cursor, int* __restrict__ csr_src,
                                              int* __restrict__ epos) {
    int e = blockIdx.x * 256 + threadIdx.x;
    if (e < NE) {
        int d = ei[NE + e];
        int pos = offs[d] + atomicAdd(&cursor[d], 1);
        csr_src[pos] = ei[e];
        epos[e] = pos;
    }
}

// One launch packs ALL weights (both layers) into MFMA B-fragment order.
#define PL_A (128*256)
#define PL_B (128*128)
__global__ __launch_bounds__(256) void k_packAll(
    const float* __restrict__ We,  const float* __restrict__ Woe, const float* __restrict__ Wq,
    const float* __restrict__ Wk,  const float* __restrict__ Wv,  const float* __restrict__ Woh,
    const float* __restrict__ W1,  const float* __restrict__ W2,  const float* __restrict__ VR,
    short* __restrict__ Wep,  short* __restrict__ Woep, short* __restrict__ Wqp,
    short* __restrict__ Wkp,  short* __restrict__ Wvp,  short* __restrict__ Wohp,
    short* __restrict__ W1p,  short* __restrict__ W2p,  short* __restrict__ VRp) {
    int s = blockIdx.x * 256 + threadIdx.x;
    const float* W; short* out; int ncol, perL; bool vr = false;
    if (s < 2 * PL_A) { W = We; out = Wep; ncol = 256; perL = PL_A; }
    else if ((s -= 2 * PL_A) < 2 * PL_B) { W = Woe; out = Woep; ncol = 128; perL = PL_B; }
    else if ((s -= 2 * PL_B) < 2 * PL_B) { W = Wq;  out = Wqp;  ncol = 128; perL = PL_B; }
    else if ((s -= 2 * PL_B) < 2 * PL_B) { W = Wk;  out = Wkp;  ncol = 128; perL = PL_B; }
    else if ((s -= 2 * PL_B) < 2 * PL_B) { W = Wv;  out = Wvp;  ncol = 128; perL = PL_B; }
    else if ((s -= 2 * PL_B) < 2 * PL_B) { W = Woh; out = Wohp; ncol = 128; perL = PL_B; }
    else if ((s -= 2 * PL_B) < 2 * PL_A) { W = W1;  out = W1p;  ncol = 256; perL = PL_A; }
    else if ((s -= 2 * PL_A) < 2 * PL_A) { W = W2;  out = W2p;  ncol = 128; perL = PL_A; }
    else if ((s -= 2 * PL_A) < 2 * PL_B) { W = VR;  out = VRp;  ncol = 128; perL = PL_B; vr = true; }
    else return;
    int l = s / perL, q = s % perL;
    int j = q & 7; int t2 = q >> 3; int kg = t2 & 3; t2 >>= 2;
    int col = t2 % ncol; int kt = t2 / ncol;
    int k = kt * 32 + kg * 8 + j;
    float v;
    if (vr) v = ((k >> 4) == (col >> 4)) ? VR[l * 2048 + (k & 15) * 128 + col] : 0.f;
    else    v = W[(size_t)l * perL + k * ncol + col];
    out[(size_t)l * perL + q] = (short)bf16r(v);
}

// ---------------- per-layer kernels ----------------

// Q/K/V via MFMA: 64 nodes/block, 512 threads (8 waves). Layer 0 only.
__global__ __launch_bounds__(512) void k_qkv(const float* __restrict__ x,
                                             const short* __restrict__ Wqp, const float* __restrict__ bq,
                                             const short* __restrict__ Wkp, const short* __restrict__ Wvp,
                                             unsigned short* __restrict__ Qh, unsigned short* __restrict__ Kh,
                                             unsigned short* __restrict__ Vh) {
    __shared__ short xsw[64 * 128];
    int t = threadIdx.x;
    int ci = t & 15, r0 = t >> 4;
    int n0 = blockIdx.x * 64;
    for (int rr = r0; rr < 64; rr += 32) {
        int n = n0 + rr;
        int4 pkv = make_int4(0, 0, 0, 0);
        if (n < NN) {
            const float4* src = (const float4*)(x + (size_t)n * 128 + ci * 8);
            float4 v0 = src[0], v1 = src[1];
            pkv.x = pk2(v0.x, v0.y); pkv.y = pk2(v0.z, v0.w);
            pkv.z = pk2(v1.x, v1.y); pkv.w = pk2(v1.z, v1.w);
        }
        int byte = (rr * 256 + ci * 16) ^ ((rr & 7) << 4);
        *(int4*)((char*)xsw + byte) = pkv;
    }
    __syncthreads();
    int lane = t & 63, w = t >> 6;
    int l15 = lane & 15, kg = lane >> 4;
    f32x4 acc[4][3];
#pragma unroll
    for (int m = 0; m < 4; ++m)
#pragma unroll
        for (int q = 0; q < 3; ++q) { acc[m][q][0] = 0.f; acc[m][q][1] = 0.f; acc[m][q][2] = 0.f; acc[m][q][3] = 0.f; }
    int col = w * 16 + l15;
#pragma unroll
    for (int kt = 0; kt < 4; ++kt) {
        s16x8 a[4];
#pragma unroll
        for (int m = 0; m < 4; ++m) {
            int row = m * 16 + l15;
            int abyte = (row * 256 + kt * 64 + kg * 16) ^ ((l15 & 7) << 4);
            a[m] = *(const s16x8*)((const char*)xsw + abyte);
        }
        size_t bo = ((size_t)((kt * 128 + col) * 4 + kg)) * 8;
        s16x8 bqf = *(const s16x8*)(Wqp + bo);
        s16x8 bkf = *(const s16x8*)(Wkp + bo);
        s16x8 bvf = *(const s16x8*)(Wvp + bo);
#pragma unroll
        for (int m = 0; m < 4; ++m) {
            acc[m][0] = mfma16(a[m], bqf, acc[m][0]);
            acc[m][1] = mfma16(a[m], bkf, acc[m][1]);
            acc[m][2] = mfma16(a[m], bvf, acc[m][2]);
        }
    }
    float bqv = bq[col];
#pragma unroll
    for (int m = 0; m < 4; ++m)
#pragma unroll
        for (int i = 0; i < 4; ++i) {
            int n = n0 + m * 16 + kg * 4 + i;
            if (n < NN) {
                Qh[(size_t)n * 128 + col] = bf16r(acc[m][0][i] + bqv);
                Kh[(size_t)n * 128 + col] = bf16r(acc[m][1][i]);
                Vh[(size_t)n * 128 + col] = bf16r(acc[m][2][i]);
            }
        }
}

// Fused edge kernel: 64 edges/block, 512 threads (8 waves). epk/ets share LDS.
// e_t for nattn is stored as OCP fp8 e4m3 (HW cvt), CSR-ordered.
template<bool IN_F32>
__global__ __launch_bounds__(512) void k_edgeA(const void* __restrict__ ea_, const int* __restrict__ ei,
                                               const int* __restrict__ epos,
                                               const short* __restrict__ Wep, const float* __restrict__ be,
                                               const float* __restrict__ Aw,
                                               const unsigned short* __restrict__ Qh,
                                               const unsigned short* __restrict__ Kh,
                                               unsigned char* __restrict__ e8, float* __restrict__ sc,
                                               const short* __restrict__ Woep, const float* __restrict__ boe,
                                               void* __restrict__ eout_) {
    __shared__ short eas[64 * 128];
    __shared__ int epts[64 * EPKS];
    const float* eaf = (const float*)ea_;
    const unsigned short* eab = (const unsigned short*)ea_;
    unsigned short* eout_b = (unsigned short*)eout_;
    float* eout_f = (float*)eout_;

    int e0 = blockIdx.x * 64;
    int t = threadIdx.x;
    int ci = t & 15, r0 = t >> 4;
    int eA = e0 + r0, eB = eA + 32;
    int siA = ei[eA], diA = ei[NE + eA], posA = epos[eA];
    int siB = ei[eB], diB = ei[NE + eB], posB = epos[eB];

    {   // phase 1: stage ea -> bf16 swizzled
#pragma unroll
        for (int h = 0; h < 2; ++h) {
            int rr = r0 + h * 32;
            int4 pkv;
            if (IN_F32) {
                const float4* src = (const float4*)(eaf + (size_t)(e0 + rr) * 128 + ci * 8);
                float4 v0 = src[0], v1 = src[1];
                pkv.x = pk2(v0.x, v0.y); pkv.y = pk2(v0.z, v0.w);
                pkv.z = pk2(v1.x, v1.y); pkv.w = pk2(v1.z, v1.w);
            } else {
                pkv = *(const int4*)(eab + (size_t)(e0 + rr) * 128 + ci * 8);
            }
            int byte = (rr * 256 + ci * 16) ^ ((rr & 7) << 4);
            *(int4*)((char*)eas + byte) = pkv;
        }
    }
    __syncthreads();
    union { int4 v; unsigned short us[8]; } kuA, quA, kuB, quB;
    kuA.v = *(const int4*)(Kh + (size_t)siA * 128 + ci * 8);
    quA.v = *(const int4*)(Qh + (size_t)diA * 128 + ci * 8);
    kuB.v = *(const int4*)(Kh + (size_t)siB * 128 + ci * 8);
    quB.v = *(const int4*)(Qh + (size_t)diB * 128 + ci * 8);

    int lane = t & 63, w = t >> 6;
    int l15 = lane & 15, kg = lane >> 4;
    {   // phase 2: Ep = eas @ We + be
        f32x4 acc[4][2];
#pragma unroll
        for (int m = 0; m < 4; ++m)
#pragma unroll
            for (int q = 0; q < 2; ++q) { acc[m][q][0] = 0.f; acc[m][q][1] = 0.f; acc[m][q][2] = 0.f; acc[m][q][3] = 0.f; }
#pragma unroll
        for (int kt = 0; kt < 4; ++kt) {
            s16x8 a[4];
#pragma unroll
            for (int m = 0; m < 4; ++m) {
                int row = m * 16 + l15;
                int abyte = (row * 256 + kt * 64 + kg * 16) ^ ((l15 & 7) << 4);
                a[m] = *(const s16x8*)((const char*)eas + abyte);
            }
#pragma unroll
            for (int q = 0; q < 2; ++q) {
                int col = w * 32 + q * 16 + l15;
                s16x8 b = *(const s16x8*)(Wep + ((size_t)((kt * 256 + col) * 4 + kg)) * 8);
#pragma unroll
                for (int m = 0; m < 4; ++m) acc[m][q] = mfma16(a[m], b, acc[m][q]);
            }
        }
        float bw = be[w * 32 + l15], bb = be[w * 32 + 16 + l15];
#pragma unroll
        for (int m = 0; m < 4; ++m)
#pragma unroll
            for (int i = 0; i < 4; ++i) {
                int row = m * 16 + kg * 4 + i;
                epts[row * EPKS + w * 16 + l15] = pk2(acc[m][0][i] + bw, acc[m][1][i] + bb);
            }
    }
    __syncthreads();
    int4 wA0, wA1, wB0, wB1;
    {
        const int4* pA = (const int4*)(epts + r0 * EPKS + ci * 8);
        wA0 = pA[0]; wA1 = pA[1];
        const int4* pB = (const int4*)(epts + (r0 + 32) * EPKS + ci * 8);
        wB0 = pB[0]; wB1 = pB[1];
    }
    __syncthreads();
    {   // phase 3: elementwise
        int hh = ci >> 1, dbase = (ci & 1) * 8;
        float aw[8];
#pragma unroll
        for (int j = 0; j < 8; ++j) aw[j] = Aw[(dbase + j) * 8 + hh];
#pragma unroll
        for (int h = 0; h < 2; ++h) {
            int r = r0 + h * 32;
            int pos = h ? posB : posA;
            const unsigned short* kus = h ? kuB.us : kuA.us;
            const unsigned short* qus = h ? quB.us : quA.us;
            const int4 w0 = h ? wB0 : wA0;
            const int4 w1 = h ? wB1 : wA1;
            int prs[8] = {w0.x, w0.y, w0.z, w0.w, w1.x, w1.y, w1.z, w1.w};
            float p = 0.f;
            float etv[8];
#pragma unroll
            for (int j = 0; j < 8; ++j) {
                int pr = prs[j];
                float ew = b2f((unsigned short)pr);
                float ebv = b2f((unsigned short)((unsigned)pr >> 16));
                float kq = b2f(kus[j]) + b2f(qus[j]);
                float sv = kq * ew;
                float ss = copysignf(sqrtf(fabsf(sv)), sv);
                float et = fmaxf(ss + ebv, 0.f);
                etv[j] = et;
                p += et * aw[j];
            }
            // fp8 pack (OCP e4m3) for the nattn/rowV path
            int lo = __builtin_amdgcn_cvt_pk_fp8_f32(etv[0], etv[1], 0, 0);
            lo = __builtin_amdgcn_cvt_pk_fp8_f32(etv[2], etv[3], lo, 1);
            int hi = __builtin_amdgcn_cvt_pk_fp8_f32(etv[4], etv[5], 0, 0);
            hi = __builtin_amdgcn_cvt_pk_fp8_f32(etv[6], etv[7], hi, 1);
            *(int2*)(e8 + (size_t)pos * 128 + ci * 8) = make_int2(lo, hi);
            // bf16 into LDS for phase-4 GEMM
            int4 pkv;
            pkv.x = pk2(etv[0], etv[1]); pkv.y = pk2(etv[2], etv[3]);
            pkv.z = pk2(etv[4], etv[5]); pkv.w = pk2(etv[6], etv[7]);
            int byte = (r * 256 + ci * 16) ^ ((r & 7) << 4);
            *(int4*)((char*)epts + byte) = pkv;
            p += __shfl_xor(p, 1);
            if ((ci & 1) == 0) {
                float s = fminf(fmaxf(p, -CLAMPV), CLAMPV);
                sc[(size_t)pos * 8 + hh] = s;
            }
        }
    }
    __syncthreads();
    {   // phase 4: e_out = (ea + ets @ Woe + boe) * BNS
        f32x4 acc[4];
#pragma unroll
        for (int m = 0; m < 4; ++m) { acc[m][0] = 0.f; acc[m][1] = 0.f; acc[m][2] = 0.f; acc[m][3] = 0.f; }
        int col = w * 16 + l15;
#pragma unroll
        for (int kt = 0; kt < 4; ++kt) {
            s16x8 a[4];
#pragma unroll
            for (int m = 0; m < 4; ++m) {
                int row = m * 16 + l15;
                int abyte = (row * 256 + kt * 64 + kg * 16) ^ ((l15 & 7) << 4);
                a[m] = *(const s16x8*)((const char*)epts + abyte);
            }
            s16x8 b = *(const s16x8*)(Woep + ((size_t)((kt * 128 + col) * 4 + kg)) * 8);
#pragma unroll
            for (int m = 0; m < 4; ++m) acc[m] = mfma16(a[m], b, acc[m]);
        }
        float bb = boe[col];
#pragma unroll
        for (int m = 0; m < 4; ++m)
#pragma unroll
            for (int i = 0; i < 4; ++i) {
                int rr = m * 16 + kg * 4 + i;
                int rbyte = (rr * 256 + col * 2) ^ ((rr & 7) << 4);
                float res = b2f(*(const unsigned short*)((const char*)eas + rbyte));
                size_t idx = (size_t)(e0 + rr) * 128 + col;
                float v = (res + acc[m][i] + bb) * BNS;
                if (IN_F32) eout_b[idx] = bf16r(v);
                else        eout_f[idx] = v;
            }
    }
}

// Node attention: one 64-lane wave per node; merged denom+accumulate pass.
// e_t read as fp8; wV/rowV written bf16.
__global__ __launch_bounds__(64) void k_nattn(const int* __restrict__ offs, const int* __restrict__ csr_src,
                                              const float* __restrict__ sc,
                                              const unsigned char* __restrict__ e8,
                                              const unsigned short* __restrict__ Vh,
                                              unsigned short* __restrict__ wVb,
                                              unsigned short* __restrict__ rowVb) {
    int n = blockIdx.x;
    int lane = threadIdx.x;
    int beg = offs[n], end = offs[n + 1];
    int h = lane & 7, es = lane >> 3;
    float m = -1e30f;
    for (int i = beg + es; i < end; i += 8)
        m = fmaxf(m, sc[(size_t)i * 8 + h]);
#pragma unroll
    for (int off = 8; off < 64; off <<= 1) m = fmaxf(m, __shfl_xor(m, off));
    int hv = lane >> 3;                   // head of cols (2*lane, 2*lane+1)
    float mv = __shfl(m, hv);
    float dsum = 0.f, av0 = 0.f, av1 = 0.f, ar0 = 0.f, ar1 = 0.f;
    for (int i = beg; i < end; ++i) {
        float a = expf(sc[(size_t)i * 8 + hv] - mv);
        dsum += a;
        int s = csr_src[i];
        int v = ((const int*)Vh)[(size_t)s * 64 + lane];
        int u8 = ((const unsigned short*)e8)[(size_t)i * 64 + lane];
        av0 += b2f((unsigned short)v) * a;
        av1 += b2f((unsigned short)((unsigned)v >> 16)) * a;
        ar0 += __builtin_amdgcn_cvt_f32_fp8(u8, 0) * a;
        ar1 += __builtin_amdgcn_cvt_f32_fp8(u8, 1) * a;
    }
    float inv = 1.f / (dsum + 1e-16f);
    ((int*)wVb)[(size_t)n * 64 + lane]   = pk2(av0 * inv, av1 * inv);
    ((int*)rowVb)[(size_t)n * 64 + lane] = pk2(ar0 * inv, ar1 * inv);
}

// Node post via MFMA: 32 nodes/block, 256 threads (4 waves), LDS 24 KB.
template<bool EMIT>
__global__ __launch_bounds__(256) void k_nodeB(
    const unsigned short* __restrict__ wVb, const unsigned short* __restrict__ rowVb,
    const short* __restrict__ VRp, const float* __restrict__ dc,
    const float* __restrict__ logdeg, const float* __restrict__ x,
    const short* __restrict__ Wohp, const float* __restrict__ boh,
    const short* __restrict__ W1p, const float* __restrict__ b1,
    const short* __restrict__ W2p, const float* __restrict__ b2,
    float* __restrict__ xout,
    const short* __restrict__ Wqp2, const float* __restrict__ bq2,
    const short* __restrict__ Wkp2, const short* __restrict__ Wvp2,
    unsigned short* __restrict__ Qh2, unsigned short* __restrict__ Kh2,
    unsigned short* __restrict__ Vh2) {
    __shared__ short bufA[32 * 128];   // rowV staging / h1 / out (8 KB)
    __shared__ short bufU[32 * 256];   // hs / us (16 KB)
    int n0 = blockIdx.x * 32;
    int t = threadIdx.x;
    int ci = t & 15, r0 = t >> 4;      // r0 in 0..15
    {   // p0: stage rowV (bf16) -> bufA swizzled (pure copy)
#pragma unroll
        for (int h = 0; h < 2; ++h) {
            int rr = r0 + h * 16, n = n0 + rr;
            int4 pkv = make_int4(0, 0, 0, 0);
            if (n < NN) pkv = *(const int4*)(rowVb + (size_t)n * 128 + ci * 8);
            int byte = (rr * 256 + ci * 16) ^ ((rr & 7) << 4);
            *(int4*)((char*)bufA + byte) = pkv;
        }
    }
    __syncthreads();
    int lane = t & 63, w = t >> 6;     // w in 0..3
    int l15 = lane & 15, kg = lane >> 4;
    int cq[2] = {w * 32 + l15, w * 32 + 16 + l15};
    {   // p1: hs = (wV + rowV@VeRowBD) * degscale -> bufU
        f32x4 acc[2][2];
#pragma unroll
        for (int m = 0; m < 2; ++m)
#pragma unroll
            for (int q = 0; q < 2; ++q)
#pragma unroll
                for (int i = 0; i < 4; ++i) {
                    int n = n0 + m * 16 + kg * 4 + i;
                    acc[m][q][i] = (n < NN) ? b2f(wVb[(size_t)n * 128 + cq[q]]) : 0.f;
                }
#pragma unroll
        for (int kt = 0; kt < 4; ++kt) {
            s16x8 a[2];
#pragma unroll
            for (int m = 0; m < 2; ++m) {
                int row = m * 16 + l15;
                int abyte = (row * 256 + kt * 64 + kg * 16) ^ ((l15 & 7) << 4);
                a[m] = *(const s16x8*)((const char*)bufA + abyte);
            }
#pragma unroll
            for (int q = 0; q < 2; ++q) {
                s16x8 b = *(const s16x8*)(VRp + ((size_t)((kt * 128 + cq[q]) * 4 + kg)) * 8);
#pragma unroll
                for (int m = 0; m < 2; ++m) acc[m][q] = mfma16(a[m], b, acc[m][q]);
            }
        }
#pragma unroll
        for (int q = 0; q < 2; ++q) {
            float d0 = dc[cq[q] * 2], d1 = dc[cq[q] * 2 + 1];
#pragma unroll
            for (int m = 0; m < 2; ++m)
#pragma unroll
                for (int i = 0; i < 4; ++i) {
                    int rr = m * 16 + kg * 4 + i, n = n0 + rr;
                    float ld = (n < NN) ? logdeg[n] : 0.f;
                    float hs = acc[m][q][i] * (d0 + ld * d1);
                    int byte = (rr * 256 + cq[q] * 2) ^ ((rr & 7) << 4);
                    *(unsigned short*)((char*)bufU + byte) = bf16r(hs);
                }
        }
    }
    __syncthreads();
    float h1r[2][2][4];
    {   // p2: h1 = (x + hs@Woh + boh)*BNS -> bufA + regs
        f32x4 acc[2][2];
#pragma unroll
        for (int m = 0; m < 2; ++m)
#pragma unroll
            for (int q = 0; q < 2; ++q) { acc[m][q][0] = 0.f; acc[m][q][1] = 0.f; acc[m][q][2] = 0.f; acc[m][q][3] = 0.f; }
#pragma unroll
        for (int kt = 0; kt < 4; ++kt) {
            s16x8 a[2];
#pragma unroll
            for (int m = 0; m < 2; ++m) {
                int row = m * 16 + l15;
                int abyte = (row * 256 + kt * 64 + kg * 16) ^ ((l15 & 7) << 4);
                a[m] = *(const s16x8*)((const char*)bufU + abyte);
            }
#pragma unroll
            for (int q = 0; q < 2; ++q) {
                s16x8 b = *(const s16x8*)(Wohp + ((size_t)((kt * 128 + cq[q]) * 4 + kg)) * 8);
#pragma unroll
                for (int m = 0; m < 2; ++m) acc[m][q] = mfma16(a[m], b, acc[m][q]);
            }
        }
#pragma unroll
        for (int q = 0; q < 2; ++q) {
            float bb = boh[cq[q]];
#pragma unroll
            for (int m = 0; m < 2; ++m)
#pragma unroll
                for (int i = 0; i < 4; ++i) {
                    int rr = m * 16 + kg * 4 + i, n = n0 + rr;
                    float xv = (n < NN) ? x[(size_t)n * 128 + cq[q]] : 0.f;
                    float h1 = (xv + acc[m][q][i] + bb) * BNS;
                    h1r[m][q][i] = h1;
                    int byte = (rr * 256 + cq[q] * 2) ^ ((rr & 7) << 4);
                    *(unsigned short*)((char*)bufA + byte) = bf16r(h1);
                }
        }
    }
    __syncthreads();
    {   // p3: us = relu(h1@W1 + b1) -> bufU; wave w owns cols w*64..+63
        f32x4 acc[2][4];
#pragma unroll
        for (int m = 0; m < 2; ++m)
#pragma unroll
            for (int q = 0; q < 4; ++q) { acc[m][q][0] = 0.f; acc[m][q][1] = 0.f; acc[m][q][2] = 0.f; acc[m][q][3] = 0.f; }
#pragma unroll
        for (int kt = 0; kt < 4; ++kt) {
            s16x8 a[2];
#pragma unroll
            for (int m = 0; m < 2; ++m) {
                int row = m * 16 + l15;
                int abyte = (row * 256 + kt * 64 + kg * 16) ^ ((l15 & 7) << 4);
                a[m] = *(const s16x8*)((const char*)bufA + abyte);
            }
#pragma unroll
            for (int q = 0; q < 4; ++q) {
                int colq = w * 64 + q * 16 + l15;
                s16x8 b = *(const s16x8*)(W1p + ((size_t)((kt * 256 + colq) * 4 + kg)) * 8);
#pragma unroll
                for (int m = 0; m < 2; ++m) acc[m][q] = mfma16(a[m], b, acc[m][q]);
            }
        }
        __syncthreads();   // hs reads (p2) complete before us overwrites bufU
#pragma unroll
        for (int q = 0; q < 4; ++q) {
            int colq = w * 64 + q * 16 + l15;
            float bb = b1[colq];
#pragma unroll
            for (int m = 0; m < 2; ++m)
#pragma unroll
                for (int i = 0; i < 4; ++i) {
                    int rr = m * 16 + kg * 4 + i;
                    float us = fmaxf(acc[m][q][i] + bb, 0.f);
                    int byte = (rr * 512 + colq * 2) ^ ((rr & 7) << 4);
                    *(unsigned short*)((char*)bufU + byte) = bf16r(us);
                }
        }
    }
    __syncthreads();
    {   // p4: out = (h1 + us@W2 + b2)*BNS; EMIT: stage out bf16 into bufA
        f32x4 acc[2][2];
#pragma unroll
        for (int m = 0; m < 2; ++m)
#pragma unroll
            for (int q = 0; q < 2; ++q) { acc[m][q][0] = 0.f; acc[m][q][1] = 0.f; acc[m][q][2] = 0.f; acc[m][q][3] = 0.f; }
#pragma unroll
        for (int kt = 0; kt < 8; ++kt) {
            s16x8 a[2];
#pragma unroll
            for (int m = 0; m < 2; ++m) {
                int row = m * 16 + l15;
                int abyte = (row * 512 + kt * 64 + kg * 16) ^ ((l15 & 7) << 4);
                a[m] = *(const s16x8*)((const char*)bufU + abyte);
            }
#pragma unroll
            for (int q = 0; q < 2; ++q) {
                s16x8 b = *(const s16x8*)(W2p + ((size_t)((kt * 128 + cq[q]) * 4 + kg)) * 8);
#pragma unroll
                for (int m = 0; m < 2; ++m) acc[m][q] = mfma16(a[m], b, acc[m][q]);
            }
        }
#pragma unroll
        for (int q = 0; q < 2; ++q) {
            float bb = b2[cq[q]];
#pragma unroll
            for (int m = 0; m < 2; ++m)
#pragma unroll
                for (int i = 0; i < 4; ++i) {
                    int rr = m * 16 + kg * 4 + i, n = n0 + rr;
                    float outv = (h1r[m][q][i] + acc[m][q][i] + bb) * BNS;
                    if (n < NN) xout[(size_t)n * 128 + cq[q]] = outv;
                    if (EMIT) {
                        int byte = (rr * 256 + cq[q] * 2) ^ ((rr & 7) << 4);
                        *(unsigned short*)((char*)bufA + byte) = bf16r(outv);
                    }
                }
        }
    }
    if (EMIT) {   // next-layer Q/K/V from staged out
        __syncthreads();
        f32x4 acc[2][2][3];
#pragma unroll
        for (int m = 0; m < 2; ++m)
#pragma unroll
            for (int q = 0; q < 2; ++q)
#pragma unroll
                for (int o = 0; o < 3; ++o) { acc[m][q][o][0] = 0.f; acc[m][q][o][1] = 0.f; acc[m][q][o][2] = 0.f; acc[m][q][o][3] = 0.f; }
#pragma unroll
        for (int kt = 0; kt < 4; ++kt) {
            s16x8 a[2];
#pragma unroll
            for (int m = 0; m < 2; ++m) {
                int row = m * 16 + l15;
                int abyte = (row * 256 + kt * 64 + kg * 16) ^ ((l15 & 7) << 4);
                a[m] = *(const s16x8*)((const char*)bufA + abyte);
            }
#pragma unroll
            for (int q = 0; q < 2; ++q) {
                size_t bo = ((size_t)((kt * 128 + cq[q]) * 4 + kg)) * 8;
                s16x8 bqf = *(const s16x8*)(Wqp2 + bo);
                s16x8 bkf = *(const s16x8*)(Wkp2 + bo);
                s16x8 bvf = *(const s16x8*)(Wvp2 + bo);
#pragma unroll
                for (int m = 0; m < 2; ++m) {
                    acc[m][q][0] = mfma16(a[m], bqf, acc[m][q][0]);
                    acc[m][q][1] = mfma16(a[m], bkf, acc[m][q][1]);
                    acc[m][q][2] = mfma16(a[m], bvf, acc[m][q][2]);
                }
            }
        }
#pragma unroll
        for (int q = 0; q < 2; ++q) {
            float bqv = bq2[cq[q]];
#pragma unroll
            for (int m = 0; m < 2; ++m)
#pragma unroll
                for (int i = 0; i < 4; ++i) {
                    int n = n0 + m * 16 + kg * 4 + i;
                    if (n < NN) {
                        Qh2[(size_t)n * 128 + cq[q]] = bf16r(acc[m][q][0][i] + bqv);
                        Kh2[(size_t)n * 128 + cq[q]] = bf16r(acc[m][q][1][i]);
                        Vh2[(size_t)n * 128 + cq[q]] = bf16r(acc[m][q][2][i]);
                    }
                }
        }
    }
}

// ---------------- host launch ----------------

extern "C" void kernel_launch(void* const* d_in, const int* in_sizes, int n_in,
                              void* d_out, int out_size, void* d_ws, size_t ws_size,
                              hipStream_t stream) {
    (void)in_sizes; (void)n_in; (void)out_size; (void)ws_size;
    const float* x_in0  = (const float*)d_in[0];
    const int*   ei     = (const int*)d_in[1];
    const float* ea_in0 = (const float*)d_in[2];
    const float* Wq = (const float*)d_in[3];
    const float* bq = (const float*)d_in[4];
    const float* Wk = (const float*)d_in[5];
    const float* Wv = (const float*)d_in[6];
    const float* We = (const float*)d_in[7];
    const float* be = (const float*)d_in[8];
    const float* Aw = (const float*)d_in[9];
    const float* VeRow = (const float*)d_in[10];
    const float* Woh = (const float*)d_in[11];
    const float* boh = (const float*)d_in[12];
    const float* Woe = (const float*)d_in[13];
    const float* boe = (const float*)d_in[14];
    const float* dc  = (const float*)d_in[15];
    const float* W1 = (const float*)d_in[16];
    const float* b1 = (const float*)d_in[17];
    const float* W2 = (const float*)d_in[18];
    const float* b2 = (const float*)d_in[19];

    char* ws = (char*)d_ws;
    size_t off = 0;
    auto alloc = [&](size_t bytes) { void* p = ws + off; off = (off + bytes + 255) & ~(size_t)255; return p; };
    int*   deg    = (int*)alloc((size_t)NN * 4);
    int*   cursor = (int*)alloc((size_t)NN * 4);
    int*   offs   = (int*)alloc((size_t)(NN + 1) * 4);
    int*   bsum   = (int*)alloc((size_t)64 * 4);
    int*   csr_src= (int*)alloc((size_t)NE * 4);
    int*   epos   = (int*)alloc((size_t)NE * 4);
    float* logdeg = (float*)alloc((size_t)NN * 4);
    unsigned short* Qh  = (unsigned short*)alloc((size_t)NN * 128 * 2);
    unsigned short* Kh  = (unsigned short*)alloc((size_t)NN * 128 * 2);
    unsigned short* Vh  = (unsigned short*)alloc((size_t)NN * 128 * 2);
    unsigned short* Qh2 = (unsigned short*)alloc((size_t)NN * 128 * 2);
    unsigned short* Kh2 = (unsigned short*)alloc((size_t)NN * 128 * 2);
    unsigned short* Vh2 = (unsigned short*)alloc((size_t)NN * 128 * 2);
    unsigned char* e8   = (unsigned char*)alloc((size_t)NE * 128);
    unsigned short* ea_bf = (unsigned short*)alloc((size_t)NE * 128 * 2);
    float* sc     = (float*)alloc((size_t)NE * 8 * 4);
    unsigned short* wVb   = (unsigned short*)alloc((size_t)NN * 128 * 2);
    unsigned short* rowVb = (unsigned short*)alloc((size_t)NN * 128 * 2);
    short* Wep    = (short*)alloc((size_t)2 * 128 * 256 * 2);
    short* Woep   = (short*)alloc((size_t)2 * 128 * 128 * 2);
    short* Wqp    = (short*)alloc((size_t)2 * 128 * 128 * 2);
    short* Wkp    = (short*)alloc((size_t)2 * 128 * 128 * 2);
    short* Wvp    = (short*)alloc((size_t)2 * 128 * 128 * 2);
    short* Wohp   = (short*)alloc((size_t)2 * 128 * 128 * 2);
    short* W1p    = (short*)alloc((size_t)2 * 128 * 256 * 2);
    short* W2p    = (short*)alloc((size_t)2 * 256 * 128 * 2);
    short* VRp    = (short*)alloc((size_t)2 * 128 * 128 * 2);

    float* out_x = (float*)d_out;
    float* out_e = out_x + (size_t)NN * 128;

    hipError_t err;
    err = hipMemsetAsync(deg, 0, (size_t)NN * 4, stream); (void)err;
    err = hipMemsetAsync(cursor, 0, (size_t)NN * 4, stream); (void)err;

    k_deg<<<(NE + 255) / 256, 256, 0, stream>>>(ei, deg);
    k_scan1<<<NBLK, 1024, 0, stream>>>(deg, offs, bsum, logdeg);
    k_scan3<<<NBLK, 1024, 0, stream>>>(offs, bsum);
    k_fill<<<(NE + 255) / 256, 256, 0, stream>>>(ei, offs, cursor, csr_src, epos);
    k_packAll<<<1536, 256, 0, stream>>>(We, Woe, Wq, Wk, Wv, Woh, W1, W2, VeRow,
                                        Wep, Woep, Wqp, Wkp, Wvp, Wohp, W1p, W2p, VRp);

    // ---- layer 0 ----
    k_qkv<<<(NN + 63) / 64, 512, 0, stream>>>(x_in0, Wqp, bq, Wkp, Wvp, Qh, Kh, Vh);
    k_edgeA<true><<<NE / 64, 512, 0, stream>>>(ea_in0, ei, epos, Wep, be, Aw, Qh, Kh,
                                               e8, sc, Woep, boe, ea_bf);
    k_nattn<<<NN, 64, 0, stream>>>(offs, csr_src, sc, e8, Vh, wVb, rowVb);
    k_nodeB<true><<<(NN + 31) / 32, 256, 0, stream>>>(
        wVb, rowVb, VRp, dc, logdeg, x_in0,
        Wohp, boh, W1p, b1, W2p, b2, out_x,
        Wqp + 128 * 128, bq + 128, Wkp + 128 * 128, Wvp + 128 * 128, Qh2, Kh2, Vh2);

    // ---- layer 1 ----
    k_edgeA<false><<<NE / 64, 512, 0, stream>>>(ea_bf, ei, epos, Wep + 128 * 256, be + 256,
                                                Aw + 128, Qh2, Kh2, e8, sc,
                                                Woep + 128 * 128, boe + 128, out_e);
    k_nattn<<<NN, 64, 0, stream>>>(offs, csr_src, sc, e8, Vh2, wVb, rowVb);
    k_nodeB<false><<<(NN + 31) / 32, 256, 0, stream>>>(
        wVb, rowVb, VRp + 128 * 128, dc + 256, logdeg, out_x,
        Wohp + 128 * 128, boh + 128, W1p + 128 * 256, b1 + 256, W2p + 256 * 128, b2 + 128, out_x,
        nullptr, nullptr, nullptr, nullptr, nullptr, nullptr, nullptr);
}

// Round 14
// 905.064 us; speedup vs baseline: 1.8374x; 1.0685x over previous
//
#include <hip/hip_runtime.h>

#define NN 50000
#define NE 800000
#define CLAMPV 5.0f
#define BNS 0.9999950000374997f
#define EPS 136    // ushort stride of fp8 Ep rows (272B, 16B-aligned)
#define NBLK 49    // ceil(NN/1024)

typedef __attribute__((ext_vector_type(8))) short s16x8;
typedef __attribute__((ext_vector_type(8))) __bf16 bf16x8;
typedef __attribute__((ext_vector_type(4))) float f32x4;

__device__ inline f32x4 mfma16(s16x8 a, s16x8 b, f32x4 c) {
    return __builtin_amdgcn_mfma_f32_16x16x32_bf16(
        __builtin_bit_cast(bf16x8, a), __builtin_bit_cast(bf16x8, b), c, 0, 0, 0);
}

__device__ inline unsigned short bf16r(float f) {
    return __builtin_bit_cast(unsigned short, (__bf16)f);
}

__device__ inline int pk2(float a, float b) {
    return (int)(unsigned)bf16r(a) | ((int)(unsigned)bf16r(b) << 16);
}

__device__ inline float b2f(unsigned short u) {
    return __builtin_bit_cast(float, (unsigned)u << 16);
}

// ---------------- degree / CSR build ----------------

__global__ __launch_bounds__(256) void k_deg(const int* __restrict__ ei, int* __restrict__ deg) {
    int e = blockIdx.x * 256 + threadIdx.x;
    if (e < NE) atomicAdd(&deg[ei[NE + e]], 1);
}

__global__ __launch_bounds__(1024) void k_scan1(const int* __restrict__ deg, int* __restrict__ offs,
                                                int* __restrict__ bsum, float* __restrict__ logdeg) {
    __shared__ int sm[1024];
    int i = blockIdx.x * 1024 + threadIdx.x;
    int v = (i < NN) ? deg[i] : 0;
    if (i < NN) logdeg[i] = logf((float)v + 1.0f);
    sm[threadIdx.x] = v;
    __syncthreads();
    for (int s = 1; s < 1024; s <<= 1) {
        int t = (threadIdx.x >= s) ? sm[threadIdx.x - s] : 0;
        __syncthreads();
        sm[threadIdx.x] += t;
        __syncthreads();
    }
    if (i < NN) offs[i + 1] = sm[threadIdx.x];
    if (threadIdx.x == 1023) bsum[blockIdx.x] = sm[1023];
    if (blockIdx.x == 0 && threadIdx.x == 0) offs[0] = 0;
}

__global__ __launch_bounds__(1024) void k_scan3(int* __restrict__ offs, const int* __restrict__ bsum) {
    __shared__ int pre;
    if (threadIdx.x == 0) {
        int acc = 0;
        for (int i = 0; i < (int)blockIdx.x; ++i) acc += bsum[i];
        pre = acc;
    }
    __syncthreads();
    int i = blockIdx.x * 1024 + threadIdx.x;
    if (i < NN) offs[i + 1] += pre;
}

__global__ __launch_bounds__(256) void k_fill(const int* __restrict__ ei, const int* __restrict__ offs,
                                              int* __restrict__ cursor, int* __restrict__ csr_src,
                                              int* __restrict__ epos) {
    int e = blockIdx.x * 256 + threadIdx.x;
    if (e < NE) {
        int d = ei[NE + e];
        int pos = offs[d] + atomicAdd(&cursor[d], 1);
        csr_src[pos] = ei[e];
        epos[e] = pos;
    }
}

// One launch packs ALL weights (both layers) into MFMA B-fragment order.
#define PL_A (128*256)
#define PL_B (128*128)
__global__ __launch_bounds__(256) void k_packAll(
    const float* __restrict__ We,  const float* __restrict__ Woe, const float* __restrict__ Wq,
    const float* __restrict__ Wk,  const float* __restrict__ Wv,  const float* __restrict__ Woh,
    const float* __restrict__ W1,  const float* __restrict__ W2,  const float* __restrict__ VR,
    short* __restrict__ Wep,  short* __restrict__ Woep, short* __restrict__ Wqp,
    short* __restrict__ Wkp,  short* __restrict__ Wvp,  short* __restrict__ Wohp,
    short* __restrict__ W1p,  short* __restrict__ W2p,  short* __restrict__ VRp) {
    int s = blockIdx.x * 256 + threadIdx.x;
    const float* W; short* out; int ncol, perL; bool vr = false;
    if (s < 2 * PL_A) { W = We; out = Wep; ncol = 256; perL = PL_A; }
    else if ((s -= 2 * PL_A) < 2 * PL_B) { W = Woe; out = Woep; ncol = 128; perL = PL_B; }
    else if ((s -= 2 * PL_B) < 2 * PL_B) { W = Wq;  out = Wqp;  ncol = 128; perL = PL_B; }
    else if ((s -= 2 * PL_B) < 2 * PL_B) { W = Wk;  out = Wkp;  ncol = 128; perL = PL_B; }
    else if ((s -= 2 * PL_B) < 2 * PL_B) { W = Wv;  out = Wvp;  ncol = 128; perL = PL_B; }
    else if ((s -= 2 * PL_B) < 2 * PL_B) { W = Woh; out = Wohp; ncol = 128; perL = PL_B; }
    else if ((s -= 2 * PL_B) < 2 * PL_A) { W = W1;  out = W1p;  ncol = 256; perL = PL_A; }
    else if ((s -= 2 * PL_A) < 2 * PL_A) { W = W2;  out = W2p;  ncol = 128; perL = PL_A; }
    else if ((s -= 2 * PL_A) < 2 * PL_B) { W = VR;  out = VRp;  ncol = 128; perL = PL_B; vr = true; }
    else return;
    int l = s / perL, q = s % perL;
    int j = q & 7; int t2 = q >> 3; int kg = t2 & 3; t2 >>= 2;
    int col = t2 % ncol; int kt = t2 / ncol;
    int k = kt * 32 + kg * 8 + j;
    float v;
    if (vr) v = ((k >> 4) == (col >> 4)) ? VR[l * 2048 + (k & 15) * 128 + col] : 0.f;
    else    v = W[(size_t)l * perL + k * ncol + col];
    out[(size_t)l * perL + q] = (short)bf16r(v);
}

// ---------------- per-layer kernels ----------------

// Q/K/V via MFMA: 64 nodes/block, 512 threads (8 waves). Layer 0 only.
__global__ __launch_bounds__(512) void k_qkv(const float* __restrict__ x,
                                             const short* __restrict__ Wqp, const float* __restrict__ bq,
                                             const short* __restrict__ Wkp, const short* __restrict__ Wvp,
                                             unsigned short* __restrict__ Qh, unsigned short* __restrict__ Kh,
                                             unsigned short* __restrict__ Vh) {
    __shared__ short xsw[64 * 128];
    int t = threadIdx.x;
    int ci = t & 15, r0 = t >> 4;
    int n0 = blockIdx.x * 64;
    for (int rr = r0; rr < 64; rr += 32) {
        int n = n0 + rr;
        int4 pkv = make_int4(0, 0, 0, 0);
        if (n < NN) {
            const float4* src = (const float4*)(x + (size_t)n * 128 + ci * 8);
            float4 v0 = src[0], v1 = src[1];
            pkv.x = pk2(v0.x, v0.y); pkv.y = pk2(v0.z, v0.w);
            pkv.z = pk2(v1.x, v1.y); pkv.w = pk2(v1.z, v1.w);
        }
        int byte = (rr * 256 + ci * 16) ^ ((rr & 7) << 4);
        *(int4*)((char*)xsw + byte) = pkv;
    }
    __syncthreads();
    int lane = t & 63, w = t >> 6;
    int l15 = lane & 15, kg = lane >> 4;
    f32x4 acc[4][3];
#pragma unroll
    for (int m = 0; m < 4; ++m)
#pragma unroll
        for (int q = 0; q < 3; ++q) { acc[m][q][0] = 0.f; acc[m][q][1] = 0.f; acc[m][q][2] = 0.f; acc[m][q][3] = 0.f; }
    int col = w * 16 + l15;
#pragma unroll
    for (int kt = 0; kt < 4; ++kt) {
        s16x8 a[4];
#pragma unroll
        for (int m = 0; m < 4; ++m) {
            int row = m * 16 + l15;
            int abyte = (row * 256 + kt * 64 + kg * 16) ^ ((l15 & 7) << 4);
            a[m] = *(const s16x8*)((const char*)xsw + abyte);
        }
        size_t bo = ((size_t)((kt * 128 + col) * 4 + kg)) * 8;
        s16x8 bqf = *(const s16x8*)(Wqp + bo);
        s16x8 bkf = *(const s16x8*)(Wkp + bo);
        s16x8 bvf = *(const s16x8*)(Wvp + bo);
#pragma unroll
        for (int m = 0; m < 4; ++m) {
            acc[m][0] = mfma16(a[m], bqf, acc[m][0]);
            acc[m][1] = mfma16(a[m], bkf, acc[m][1]);
            acc[m][2] = mfma16(a[m], bvf, acc[m][2]);
        }
    }
    float bqv = bq[col];
#pragma unroll
    for (int m = 0; m < 4; ++m)
#pragma unroll
        for (int i = 0; i < 4; ++i) {
            int n = n0 + m * 16 + kg * 4 + i;
            if (n < NN) {
                Qh[(size_t)n * 128 + col] = bf16r(acc[m][0][i] + bqv);
                Kh[(size_t)n * 128 + col] = bf16r(acc[m][1][i]);
                Vh[(size_t)n * 128 + col] = bf16r(acc[m][2][i]);
            }
        }
}

// Fused edge kernel: 64 edges/block, 512 threads (8 waves).
// Ep pairs stored fp8 in LDS (17.4 KB, shared with bf16 ets) -> total LDS ~33.4 KB.
template<bool IN_F32>
__global__ __launch_bounds__(512) void k_edgeA(const void* __restrict__ ea_, const int* __restrict__ ei,
                                               const int* __restrict__ epos,
                                               const short* __restrict__ Wep, const float* __restrict__ be,
                                               const float* __restrict__ Aw,
                                               const unsigned short* __restrict__ Qh,
                                               const unsigned short* __restrict__ Kh,
                                               unsigned char* __restrict__ e8, float* __restrict__ sc,
                                               const short* __restrict__ Woep, const float* __restrict__ boe,
                                               void* __restrict__ eout_) {
    __shared__ short eas[64 * 128];     // bf16 ea tile, XOR-swizzled (16 KB)
    __shared__ short epts[64 * EPS];    // fp8 (E_w,E_b) pairs, then bf16 ets tile (17.4 KB)
    const float* eaf = (const float*)ea_;
    const unsigned short* eab = (const unsigned short*)ea_;
    unsigned short* eout_b = (unsigned short*)eout_;
    float* eout_f = (float*)eout_;

    int e0 = blockIdx.x * 64;
    int t = threadIdx.x;
    int ci = t & 15, r0 = t >> 4;
    int eA = e0 + r0, eB = eA + 32;
    int siA = ei[eA], diA = ei[NE + eA], posA = epos[eA];
    int siB = ei[eB], diB = ei[NE + eB], posB = epos[eB];

    {   // phase 1: stage ea -> bf16 swizzled
#pragma unroll
        for (int h = 0; h < 2; ++h) {
            int rr = r0 + h * 32;
            int4 pkv;
            if (IN_F32) {
                const float4* src = (const float4*)(eaf + (size_t)(e0 + rr) * 128 + ci * 8);
                float4 v0 = src[0], v1 = src[1];
                pkv.x = pk2(v0.x, v0.y); pkv.y = pk2(v0.z, v0.w);
                pkv.z = pk2(v1.x, v1.y); pkv.w = pk2(v1.z, v1.w);
            } else {
                pkv = *(const int4*)(eab + (size_t)(e0 + rr) * 128 + ci * 8);
            }
            int byte = (rr * 256 + ci * 16) ^ ((rr & 7) << 4);
            *(int4*)((char*)eas + byte) = pkv;
        }
    }
    __syncthreads();
    union { int4 v; unsigned short us[8]; } kuA, quA, kuB, quB;
    kuA.v = *(const int4*)(Kh + (size_t)siA * 128 + ci * 8);
    quA.v = *(const int4*)(Qh + (size_t)diA * 128 + ci * 8);
    kuB.v = *(const int4*)(Kh + (size_t)siB * 128 + ci * 8);
    quB.v = *(const int4*)(Qh + (size_t)diB * 128 + ci * 8);

    int lane = t & 63, w = t >> 6;
    int l15 = lane & 15, kg = lane >> 4;
    {   // phase 2: Ep = eas @ We + be -> fp8 pairs in LDS
        f32x4 acc[4][2];
#pragma unroll
        for (int m = 0; m < 4; ++m)
#pragma unroll
            for (int q = 0; q < 2; ++q) { acc[m][q][0] = 0.f; acc[m][q][1] = 0.f; acc[m][q][2] = 0.f; acc[m][q][3] = 0.f; }
#pragma unroll
        for (int kt = 0; kt < 4; ++kt) {
            s16x8 a[4];
#pragma unroll
            for (int m = 0; m < 4; ++m) {
                int row = m * 16 + l15;
                int abyte = (row * 256 + kt * 64 + kg * 16) ^ ((l15 & 7) << 4);
                a[m] = *(const s16x8*)((const char*)eas + abyte);
            }
#pragma unroll
            for (int q = 0; q < 2; ++q) {
                int col = w * 32 + q * 16 + l15;
                s16x8 b = *(const s16x8*)(Wep + ((size_t)((kt * 256 + col) * 4 + kg)) * 8);
#pragma unroll
                for (int m = 0; m < 4; ++m) acc[m][q] = mfma16(a[m], b, acc[m][q]);
            }
        }
        float bw = be[w * 32 + l15], bb = be[w * 32 + 16 + l15];
#pragma unroll
        for (int m = 0; m < 4; ++m)
#pragma unroll
            for (int i = 0; i < 4; ++i) {
                int row = m * 16 + kg * 4 + i;
                int p8 = __builtin_amdgcn_cvt_pk_fp8_f32(acc[m][0][i] + bw, acc[m][1][i] + bb, 0, 0);
                epts[row * EPS + w * 16 + l15] = (short)p8;
            }
    }
    __syncthreads();
    int4 wA, wB;
    {
        wA = *(const int4*)(epts + (size_t)r0 * EPS + ci * 8);
        wB = *(const int4*)(epts + (size_t)(r0 + 32) * EPS + ci * 8);
    }
    __syncthreads();   // all epk reads done before ets overwrites the buffer
    {   // phase 3: elementwise
        int hh = ci >> 1, dbase = (ci & 1) * 8;
        float aw[8];
#pragma unroll
        for (int j = 0; j < 8; ++j) aw[j] = Aw[(dbase + j) * 8 + hh];
#pragma unroll
        for (int h = 0; h < 2; ++h) {
            int r = r0 + h * 32;
            int pos = h ? posB : posA;
            const unsigned short* kus = h ? kuB.us : kuA.us;
            const unsigned short* qus = h ? quB.us : quA.us;
            const int4 ww = h ? wB : wA;
            int words[4] = {ww.x, ww.y, ww.z, ww.w};
            float p = 0.f;
            float etv[8];
#pragma unroll
            for (int k = 0; k < 4; ++k) {
                float ew0 = __builtin_amdgcn_cvt_f32_fp8(words[k], 0);
                float eb0 = __builtin_amdgcn_cvt_f32_fp8(words[k], 1);
                float ew1 = __builtin_amdgcn_cvt_f32_fp8(words[k], 2);
                float eb1 = __builtin_amdgcn_cvt_f32_fp8(words[k], 3);
                float kq0 = b2f(kus[2 * k]) + b2f(qus[2 * k]);
                float kq1 = b2f(kus[2 * k + 1]) + b2f(qus[2 * k + 1]);
                float sv0 = kq0 * ew0, sv1 = kq1 * ew1;
                float et0 = fmaxf(copysignf(sqrtf(fabsf(sv0)), sv0) + eb0, 0.f);
                float et1 = fmaxf(copysignf(sqrtf(fabsf(sv1)), sv1) + eb1, 0.f);
                etv[2 * k] = et0; etv[2 * k + 1] = et1;
                p += et0 * aw[2 * k] + et1 * aw[2 * k + 1];
            }
            // fp8 pack (OCP e4m3) for the nattn/rowV path
            int lo = __builtin_amdgcn_cvt_pk_fp8_f32(etv[0], etv[1], 0, 0);
            lo = __builtin_amdgcn_cvt_pk_fp8_f32(etv[2], etv[3], lo, 1);
            int hi = __builtin_amdgcn_cvt_pk_fp8_f32(etv[4], etv[5], 0, 0);
            hi = __builtin_amdgcn_cvt_pk_fp8_f32(etv[6], etv[7], hi, 1);
            *(int2*)(e8 + (size_t)pos * 128 + ci * 8) = make_int2(lo, hi);
            // bf16 into LDS for phase-4 GEMM
            int4 pkv;
            pkv.x = pk2(etv[0], etv[1]); pkv.y = pk2(etv[2], etv[3]);
            pkv.z = pk2(etv[4], etv[5]); pkv.w = pk2(etv[6], etv[7]);
            int byte = (r * 256 + ci * 16) ^ ((r & 7) << 4);
            *(int4*)((char*)epts + byte) = pkv;
            p += __shfl_xor(p, 1);
            if ((ci & 1) == 0) {
                float s = fminf(fmaxf(p, -CLAMPV), CLAMPV);
                sc[(size_t)pos * 8 + hh] = s;
            }
        }
    }
    __syncthreads();
    {   // phase 4: e_out = (ea + ets @ Woe + boe) * BNS
        f32x4 acc[4];
#pragma unroll
        for (int m = 0; m < 4; ++m) { acc[m][0] = 0.f; acc[m][1] = 0.f; acc[m][2] = 0.f; acc[m][3] = 0.f; }
        int col = w * 16 + l15;
#pragma unroll
        for (int kt = 0; kt < 4; ++kt) {
            s16x8 a[4];
#pragma unroll
            for (int m = 0; m < 4; ++m) {
                int row = m * 16 + l15;
                int abyte = (row * 256 + kt * 64 + kg * 16) ^ ((l15 & 7) << 4);
                a[m] = *(const s16x8*)((const char*)epts + abyte);
            }
            s16x8 b = *(const s16x8*)(Woep + ((size_t)((kt * 128 + col) * 4 + kg)) * 8);
#pragma unroll
            for (int m = 0; m < 4; ++m) acc[m] = mfma16(a[m], b, acc[m]);
        }
        float bb = boe[col];
#pragma unroll
        for (int m = 0; m < 4; ++m)
#pragma unroll
            for (int i = 0; i < 4; ++i) {
                int rr = m * 16 + kg * 4 + i;
                int rbyte = (rr * 256 + col * 2) ^ ((rr & 7) << 4);
                float res = b2f(*(const unsigned short*)((const char*)eas + rbyte));
                size_t idx = (size_t)(e0 + rr) * 128 + col;
                float v = (res + acc[m][i] + bb) * BNS;
                if (IN_F32) eout_b[idx] = bf16r(v);
                else        eout_f[idx] = v;
            }
    }
}

// Node attention: one 64-lane wave per node, SINGLE pass.
// sc is clamped to [-5,5] upstream -> exp(sc) can't overflow; no max subtraction needed
// (exp(sc-m)/sum == exp(sc)/sum identically).
__global__ __launch_bounds__(64) void k_nattn(const int* __restrict__ offs, const int* __restrict__ csr_src,
                                              const float* __restrict__ sc,
                                              const unsigned char* __restrict__ e8,
                                              const unsigned short* __restrict__ Vh,
                                              unsigned short* __restrict__ wVb,
                                              unsigned short* __restrict__ rowVb) {
    int n = blockIdx.x;
    int lane = threadIdx.x;
    int beg = offs[n], end = offs[n + 1];
    int hv = lane >> 3;                   // head of cols (2*lane, 2*lane+1)
    float dsum = 0.f, av0 = 0.f, av1 = 0.f, ar0 = 0.f, ar1 = 0.f;
    auto body = [&](int i) {
        float a = __expf(sc[(size_t)i * 8 + hv]);
        dsum += a;
        int s = csr_src[i];
        int v = ((const int*)Vh)[(size_t)s * 64 + lane];
        int u8 = ((const unsigned short*)e8)[(size_t)i * 64 + lane];
        av0 += b2f((unsigned short)v) * a;
        av1 += b2f((unsigned short)((unsigned)v >> 16)) * a;
        ar0 += __builtin_amdgcn_cvt_f32_fp8(u8, 0) * a;
        ar1 += __builtin_amdgcn_cvt_f32_fp8(u8, 1) * a;
    };
    int i = beg;
    for (; i + 2 <= end; i += 2) { body(i); body(i + 1); }
    for (; i < end; ++i) body(i);
    float inv = 1.f / (dsum + 1e-16f);
    ((int*)wVb)[(size_t)n * 64 + lane]   = pk2(av0 * inv, av1 * inv);
    ((int*)rowVb)[(size_t)n * 64 + lane] = pk2(ar0 * inv, ar1 * inv);
}

// Node post via MFMA: 32 nodes/block, 256 threads (4 waves), LDS 24 KB.
template<bool EMIT>
__global__ __launch_bounds__(256) void k_nodeB(
    const unsigned short* __restrict__ wVb, const unsigned short* __restrict__ rowVb,
    const short* __restrict__ VRp, const float* __restrict__ dc,
    const float* __restrict__ logdeg, const float* __restrict__ x,
    const short* __restrict__ Wohp, const float* __restrict__ boh,
    const short* __restrict__ W1p, const float* __restrict__ b1,
    const short* __restrict__ W2p, const float* __restrict__ b2,
    float* __restrict__ xout,
    const short* __restrict__ Wqp2, const float* __restrict__ bq2,
    const short* __restrict__ Wkp2, const short* __restrict__ Wvp2,
    unsigned short* __restrict__ Qh2, unsigned short* __restrict__ Kh2,
    unsigned short* __restrict__ Vh2) {
    __shared__ short bufA[32 * 128];   // rowV staging / h1 / out (8 KB)
    __shared__ short bufU[32 * 256];   // hs / us (16 KB)
    int n0 = blockIdx.x * 32;
    int t = threadIdx.x;
    int ci = t & 15, r0 = t >> 4;      // r0 in 0..15
    {   // p0: stage rowV (bf16) -> bufA swizzled
#pragma unroll
        for (int h = 0; h < 2; ++h) {
            int rr = r0 + h * 16, n = n0 + rr;
            int4 pkv = make_int4(0, 0, 0, 0);
            if (n < NN) pkv = *(const int4*)(rowVb + (size_t)n * 128 + ci * 8);
            int byte = (rr * 256 + ci * 16) ^ ((rr & 7) << 4);
            *(int4*)((char*)bufA + byte) = pkv;
        }
    }
    __syncthreads();
    int lane = t & 63, w = t >> 6;     // w in 0..3
    int l15 = lane & 15, kg = lane >> 4;
    int cq[2] = {w * 32 + l15, w * 32 + 16 + l15};
    {   // p1: hs = (wV + rowV@VeRowBD) * degscale -> bufU
        f32x4 acc[2][2];
#pragma unroll
        for (int m = 0; m < 2; ++m)
#pragma unroll
            for (int q = 0; q < 2; ++q)
#pragma unroll
                for (int i = 0; i < 4; ++i) {
                    int n = n0 + m * 16 + kg * 4 + i;
                    acc[m][q][i] = (n < NN) ? b2f(wVb[(size_t)n * 128 + cq[q]]) : 0.f;
                }
#pragma unroll
        for (int kt = 0; kt < 4; ++kt) {
            s16x8 a[2];
#pragma unroll
            for (int m = 0; m < 2; ++m) {
                int row = m * 16 + l15;
                int abyte = (row * 256 + kt * 64 + kg * 16) ^ ((l15 & 7) << 4);
                a[m] = *(const s16x8*)((const char*)bufA + abyte);
            }
#pragma unroll
            for (int q = 0; q < 2; ++q) {
                s16x8 b = *(const s16x8*)(VRp + ((size_t)((kt * 128 + cq[q]) * 4 + kg)) * 8);
#pragma unroll
                for (int m = 0; m < 2; ++m) acc[m][q] = mfma16(a[m], b, acc[m][q]);
            }
        }
#pragma unroll
        for (int q = 0; q < 2; ++q) {
            float d0 = dc[cq[q] * 2], d1 = dc[cq[q] * 2 + 1];
#pragma unroll
            for (int m = 0; m < 2; ++m)
#pragma unroll
                for (int i = 0; i < 4; ++i) {
                    int rr = m * 16 + kg * 4 + i, n = n0 + rr;
                    float ld = (n < NN) ? logdeg[n] : 0.f;
                    float hs = acc[m][q][i] * (d0 + ld * d1);
                    int byte = (rr * 256 + cq[q] * 2) ^ ((rr & 7) << 4);
                    *(unsigned short*)((char*)bufU + byte) = bf16r(hs);
                }
        }
    }
    __syncthreads();
    float h1r[2][2][4];
    {   // p2: h1 = (x + hs@Woh + boh)*BNS -> bufA + regs
        f32x4 acc[2][2];
#pragma unroll
        for (int m = 0; m < 2; ++m)
#pragma unroll
            for (int q = 0; q < 2; ++q) { acc[m][q][0] = 0.f; acc[m][q][1] = 0.f; acc[m][q][2] = 0.f; acc[m][q][3] = 0.f; }
#pragma unroll
        for (int kt = 0; kt < 4; ++kt) {
            s16x8 a[2];
#pragma unroll
            for (int m = 0; m < 2; ++m) {
                int row = m * 16 + l15;
                int abyte = (row * 256 + kt * 64 + kg * 16) ^ ((l15 & 7) << 4);
                a[m] = *(const s16x8*)((const char*)bufU + abyte);
            }
#pragma unroll
            for (int q = 0; q < 2; ++q) {
                s16x8 b = *(const s16x8*)(Wohp + ((size_t)((kt * 128 + cq[q]) * 4 + kg)) * 8);
#pragma unroll
                for (int m = 0; m < 2; ++m) acc[m][q] = mfma16(a[m], b, acc[m][q]);
            }
        }
#pragma unroll
        for (int q = 0; q < 2; ++q) {
            float bb = boh[cq[q]];
#pragma unroll
            for (int m = 0; m < 2; ++m)
#pragma unroll
                for (int i = 0; i < 4; ++i) {
                    int rr = m * 16 + kg * 4 + i, n = n0 + rr;
                    float xv = (n < NN) ? x[(size_t)n * 128 + cq[q]] : 0.f;
                    float h1 = (xv + acc[m][q][i] + bb) * BNS;
                    h1r[m][q][i] = h1;
                    int byte = (rr * 256 + cq[q] * 2) ^ ((rr & 7) << 4);
                    *(unsigned short*)((char*)bufA + byte) = bf16r(h1);
                }
        }
    }
    __syncthreads();
    {   // p3: us = relu(h1@W1 + b1) -> bufU
        f32x4 acc[2][4];
#pragma unroll
        for (int m = 0; m < 2; ++m)
#pragma unroll
            for (int q = 0; q < 4; ++q) { acc[m][q][0] = 0.f; acc[m][q][1] = 0.f; acc[m][q][2] = 0.f; acc[m][q][3] = 0.f; }
#pragma unroll
        for (int kt = 0; kt < 4; ++kt) {
            s16x8 a[2];
#pragma unroll
            for (int m = 0; m < 2; ++m) {
                int row = m * 16 + l15;
                int abyte = (row * 256 + kt * 64 + kg * 16) ^ ((l15 & 7) << 4);
                a[m] = *(const s16x8*)((const char*)bufA + abyte);
            }
#pragma unroll
            for (int q = 0; q < 4; ++q) {
                int colq = w * 64 + q * 16 + l15;
                s16x8 b = *(const s16x8*)(W1p + ((size_t)((kt * 256 + colq) * 4 + kg)) * 8);
#pragma unroll
                for (int m = 0; m < 2; ++m) acc[m][q] = mfma16(a[m], b, acc[m][q]);
            }
        }
        __syncthreads();   // hs reads (p2) complete before us overwrites bufU
#pragma unroll
        for (int q = 0; q < 4; ++q) {
            int colq = w * 64 + q * 16 + l15;
            float bb = b1[colq];
#pragma unroll
            for (int m = 0; m < 2; ++m)
#pragma unroll
                for (int i = 0; i < 4; ++i) {
                    int rr = m * 16 + kg * 4 + i;
                    float us = fmaxf(acc[m][q][i] + bb, 0.f);
                    int byte = (rr * 512 + colq * 2) ^ ((rr & 7) << 4);
                    *(unsigned short*)((char*)bufU + byte) = bf16r(us);
                }
        }
    }
    __syncthreads();
    {   // p4: out = (h1 + us@W2 + b2)*BNS; EMIT: stage out bf16 into bufA
        f32x4 acc[2][2];
#pragma unroll
        for (int m = 0; m < 2; ++m)
#pragma unroll
            for (int q = 0; q < 2; ++q) { acc[m][q][0] = 0.f; acc[m][q][1] = 0.f; acc[m][q][2] = 0.f; acc[m][q][3] = 0.f; }
#pragma unroll
        for (int kt = 0; kt < 8; ++kt) {
            s16x8 a[2];
#pragma unroll
            for (int m = 0; m < 2; ++m) {
                int row = m * 16 + l15;
                int abyte = (row * 512 + kt * 64 + kg * 16) ^ ((l15 & 7) << 4);
                a[m] = *(const s16x8*)((const char*)bufU + abyte);
            }
#pragma unroll
            for (int q = 0; q < 2; ++q) {
                s16x8 b = *(const s16x8*)(W2p + ((size_t)((kt * 128 + cq[q]) * 4 + kg)) * 8);
#pragma unroll
                for (int m = 0; m < 2; ++m) acc[m][q] = mfma16(a[m], b, acc[m][q]);
            }
        }
#pragma unroll
        for (int q = 0; q < 2; ++q) {
            float bb = b2[cq[q]];
#pragma unroll
            for (int m = 0; m < 2; ++m)
#pragma unroll
                for (int i = 0; i < 4; ++i) {
                    int rr = m * 16 + kg * 4 + i, n = n0 + rr;
                    float outv = (h1r[m][q][i] + acc[m][q][i] + bb) * BNS;
                    if (n < NN) xout[(size_t)n * 128 + cq[q]] = outv;
                    if (EMIT) {
                        int byte = (rr * 256 + cq[q] * 2) ^ ((rr & 7) << 4);
                        *(unsigned short*)((char*)bufA + byte) = bf16r(outv);
                    }
                }
        }
    }
    if (EMIT) {   // next-layer Q/K/V from staged out
        __syncthreads();
        f32x4 acc[2][2][3];
#pragma unroll
        for (int m = 0; m < 2; ++m)
#pragma unroll
            for (int q = 0; q < 2; ++q)
#pragma unroll
                for (int o = 0; o < 3; ++o) { acc[m][q][o][0] = 0.f; acc[m][q][o][1] = 0.f; acc[m][q][o][2] = 0.f; acc[m][q][o][3] = 0.f; }
#pragma unroll
        for (int kt = 0; kt < 4; ++kt) {
            s16x8 a[2];
#pragma unroll
            for (int m = 0; m < 2; ++m) {
                int row = m * 16 + l15;
                int abyte = (row * 256 + kt * 64 + kg * 16) ^ ((l15 & 7) << 4);
                a[m] = *(const s16x8*)((const char*)bufA + abyte);
            }
#pragma unroll
            for (int q = 0; q < 2; ++q) {
                size_t bo = ((size_t)((kt * 128 + cq[q]) * 4 + kg)) * 8;
                s16x8 bqf = *(const s16x8*)(Wqp2 + bo);
                s16x8 bkf = *(const s16x8*)(Wkp2 + bo);
                s16x8 bvf = *(const s16x8*)(Wvp2 + bo);
#pragma unroll
                for (int m = 0; m < 2; ++m) {
                    acc[m][q][0] = mfma16(a[m], bqf, acc[m][q][0]);
                    acc[m][q][1] = mfma16(a[m], bkf, acc[m][q][1]);
                    acc[m][q][2] = mfma16(a[m], bvf, acc[m][q][2]);
                }
            }
        }
#pragma unroll
        for (int q = 0; q < 2; ++q) {
            float bqv = bq2[cq[q]];
#pragma unroll
            for (int m = 0; m < 2; ++m)
#pragma unroll
                for (int i = 0; i < 4; ++i) {
                    int n = n0 + m * 16 + kg * 4 + i;
                    if (n < NN) {
                        Qh2[(size_t)n * 128 + cq[q]] = bf16r(acc[m][q][0][i] + bqv);
                        Kh2[(size_t)n * 128 + cq[q]] = bf16r(acc[m][q][1][i]);
                        Vh2[(size_t)n * 128 + cq[q]] = bf16r(acc[m][q][2][i]);
                    }
                }
        }
    }
}

// ---------------- host launch ----------------

extern "C" void kernel_launch(void* const* d_in, const int* in_sizes, int n_in,
                              void* d_out, int out_size, void* d_ws, size_t ws_size,
                              hipStream_t stream) {
    (void)in_sizes; (void)n_in; (void)out_size; (void)ws_size;
    const float* x_in0  = (const float*)d_in[0];
    const int*   ei     = (const int*)d_in[1];
    const float* ea_in0 = (const float*)d_in[2];
    const float* Wq = (const float*)d_in[3];
    const float* bq = (const float*)d_in[4];
    const float* Wk = (const float*)d_in[5];
    const float* Wv = (const float*)d_in[6];
    const float* We = (const float*)d_in[7];
    const float* be = (const float*)d_in[8];
    const float* Aw = (const float*)d_in[9];
    const float* VeRow = (const float*)d_in[10];
    const float* Woh = (const float*)d_in[11];
    const float* boh = (const float*)d_in[12];
    const float* Woe = (const float*)d_in[13];
    const float* boe = (const float*)d_in[14];
    const float* dc  = (const float*)d_in[15];
    const float* W1 = (const float*)d_in[16];
    const float* b1 = (const float*)d_in[17];
    const float* W2 = (const float*)d_in[18];
    const float* b2 = (const float*)d_in[19];

    char* ws = (char*)d_ws;
    size_t off = 0;
    auto alloc = [&](size_t bytes) { void* p = ws + off; off = (off + bytes + 255) & ~(size_t)255; return p; };
    int*   deg    = (int*)alloc((size_t)NN * 4);
    int*   cursor = (int*)alloc((size_t)NN * 4);
    int*   offs   = (int*)alloc((size_t)(NN + 1) * 4);
    int*   bsum   = (int*)alloc((size_t)64 * 4);
    int*   csr_src= (int*)alloc((size_t)NE * 4);
    int*   epos   = (int*)alloc((size_t)NE * 4);
    float* logdeg = (float*)alloc((size_t)NN * 4);
    unsigned short* Qh  = (unsigned short*)alloc((size_t)NN * 128 * 2);
    unsigned short* Kh  = (unsigned short*)alloc((size_t)NN * 128 * 2);
    unsigned short* Vh  = (unsigned short*)alloc((size_t)NN * 128 * 2);
    unsigned short* Qh2 = (unsigned short*)alloc((size_t)NN * 128 * 2);
    unsigned short* Kh2 = (unsigned short*)alloc((size_t)NN * 128 * 2);
    unsigned short* Vh2 = (unsigned short*)alloc((size_t)NN * 128 * 2);
    unsigned char* e8   = (unsigned char*)alloc((size_t)NE * 128);
    unsigned short* ea_bf = (unsigned short*)alloc((size_t)NE * 128 * 2);
    float* sc     = (float*)alloc((size_t)NE * 8 * 4);
    unsigned short* wVb   = (unsigned short*)alloc((size_t)NN * 128 * 2);
    unsigned short* rowVb = (unsigned short*)alloc((size_t)NN * 128 * 2);
    short* Wep    = (short*)alloc((size_t)2 * 128 * 256 * 2);
    short* Woep   = (short*)alloc((size_t)2 * 128 * 128 * 2);
    short* Wqp    = (short*)alloc((size_t)2 * 128 * 128 * 2);
    short* Wkp    = (short*)alloc((size_t)2 * 128 * 128 * 2);
    short* Wvp    = (short*)alloc((size_t)2 * 128 * 128 * 2);
    short* Wohp   = (short*)alloc((size_t)2 * 128 * 128 * 2);
    short* W1p    = (short*)alloc((size_t)2 * 128 * 256 * 2);
    short* W2p    = (short*)alloc((size_t)2 * 256 * 128 * 2);
    short* VRp    = (short*)alloc((size_t)2 * 128 * 128 * 2);

    float* out_x = (float*)d_out;
    float* out_e = out_x + (size_t)NN * 128;

    hipError_t err;
    err = hipMemsetAsync(deg, 0, (size_t)NN * 4, stream); (void)err;
    err = hipMemsetAsync(cursor, 0, (size_t)NN * 4, stream); (void)err;

    k_deg<<<(NE + 255) / 256, 256, 0, stream>>>(ei, deg);
    k_scan1<<<NBLK, 1024, 0, stream>>>(deg, offs, bsum, logdeg);
    k_scan3<<<NBLK, 1024, 0, stream>>>(offs, bsum);
    k_fill<<<(NE + 255) / 256, 256, 0, stream>>>(ei, offs, cursor, csr_src, epos);
    k_packAll<<<1536, 256, 0, stream>>>(We, Woe, Wq, Wk, Wv, Woh, W1, W2, VeRow,
                                        Wep, Woep, Wqp, Wkp, Wvp, Wohp, W1p, W2p, VRp);

    // ---- layer 0 ----
    k_qkv<<<(NN + 63) / 64, 512, 0, stream>>>(x_in0, Wqp, bq, Wkp, Wvp, Qh, Kh, Vh);
    k_edgeA<true><<<NE / 64, 512, 0, stream>>>(ea_in0, ei, epos, Wep, be, Aw, Qh, Kh,
                                               e8, sc, Woep, boe, ea_bf);
    k_nattn<<<NN, 64, 0, stream>>>(offs, csr_src, sc, e8, Vh, wVb, rowVb);
    k_nodeB<true><<<(NN + 31) / 32, 256, 0, stream>>>(
        wVb, rowVb, VRp, dc, logdeg, x_in0,
        Wohp, boh, W1p, b1, W2p, b2, out_x,
        Wqp + 128 * 128, bq + 128, Wkp + 128 * 128, Wvp + 128 * 128, Qh2, Kh2, Vh2);

    // ---- layer 1 ----
    k_edgeA<false><<<NE / 64, 512, 0, stream>>>(ea_bf, ei, epos, Wep + 128 * 256, be + 256,
                                                Aw + 128, Qh2, Kh2, e8, sc,
                                                Woep + 128 * 128, boe + 128, out_e);
    k_nattn<<<NN, 64, 0, stream>>>(offs, csr_src, sc, e8, Vh2, wVb, rowVb);
    k_nodeB<false><<<(NN + 31) / 32, 256, 0, stream>>>(
        wVb, rowVb, VRp + 128 * 128, dc + 256, logdeg, out_x,
        Wohp + 128 * 128, boh + 128, W1p + 128 * 256, b1 + 256, W2p + 256 * 128, b2 + 128, out_x,
        nullptr, nullptr, nullptr, nullptr, nullptr, nullptr, nullptr);
}

// Round 16
// 877.690 us; speedup vs baseline: 1.8948x; 1.0312x over previous
//
#include <hip/hip_runtime.h>

#define NN 50000
#define NE 800000
#define CLAMPV 5.0f
#define BNS 0.9999950000374997f
#define EPS 136    // ushort stride of fp8 Ep rows (272B, 16B-aligned)
#define NBLK 49    // ceil(NN/1024)

typedef __attribute__((ext_vector_type(8))) short s16x8;
typedef __attribute__((ext_vector_type(8))) __bf16 bf16x8;
typedef __attribute__((ext_vector_type(4))) float f32x4;

__device__ inline f32x4 mfma16(s16x8 a, s16x8 b, f32x4 c) {
    return __builtin_amdgcn_mfma_f32_16x16x32_bf16(
        __builtin_bit_cast(bf16x8, a), __builtin_bit_cast(bf16x8, b), c, 0, 0, 0);
}

__device__ inline unsigned short bf16r(float f) {
    return __builtin_bit_cast(unsigned short, (__bf16)f);
}

__device__ inline int pk2(float a, float b) {
    return (int)(unsigned)bf16r(a) | ((int)(unsigned)bf16r(b) << 16);
}

__device__ inline float b2f(unsigned short u) {
    return __builtin_bit_cast(float, (unsigned)u << 16);
}

// ---------------- degree / CSR build ----------------

__global__ __launch_bounds__(256) void k_deg(const int* __restrict__ ei, int* __restrict__ deg) {
    int e = blockIdx.x * 256 + threadIdx.x;
    if (e < NE) atomicAdd(&deg[ei[NE + e]], 1);
}

__global__ __launch_bounds__(1024) void k_scan1(const int* __restrict__ deg, int* __restrict__ offs,
                                                int* __restrict__ bsum, float* __restrict__ logdeg) {
    __shared__ int sm[1024];
    int i = blockIdx.x * 1024 + threadIdx.x;
    int v = (i < NN) ? deg[i] : 0;
    if (i < NN) logdeg[i] = logf((float)v + 1.0f);
    sm[threadIdx.x] = v;
    __syncthreads();
    for (int s = 1; s < 1024; s <<= 1) {
        int t = (threadIdx.x >= s) ? sm[threadIdx.x - s] : 0;
        __syncthreads();
        sm[threadIdx.x] += t;
        __syncthreads();
    }
    if (i < NN) offs[i + 1] = sm[threadIdx.x];
    if (threadIdx.x == 1023) bsum[blockIdx.x] = sm[1023];
    if (blockIdx.x == 0 && threadIdx.x == 0) offs[0] = 0;
}

__global__ __launch_bounds__(1024) void k_scan3(int* __restrict__ offs, const int* __restrict__ bsum) {
    __shared__ int pre;
    if (threadIdx.x == 0) {
        int acc = 0;
        for (int i = 0; i < (int)blockIdx.x; ++i) acc += bsum[i];
        pre = acc;
    }
    __syncthreads();
    int i = blockIdx.x * 1024 + threadIdx.x;
    if (i < NN) offs[i + 1] += pre;
}

__global__ __launch_bounds__(256) void k_fill(const int* __restrict__ ei, const int* __restrict__ offs,
                                              int* __restrict__ cursor, int* __restrict__ csr_src,
                                              int* __restrict__ epos) {
    int e = blockIdx.x * 256 + threadIdx.x;
    if (e < NE) {
        int d = ei[NE + e];
        int pos = offs[d] + atomicAdd(&cursor[d], 1);
        csr_src[pos] = ei[e];
        epos[e] = pos;
    }
}

// Transpose Aw (D=16,H=8) -> AwT[h][d] for both layers (vector-loadable by head).
__global__ void k_awt(const float* __restrict__ Aw, float* __restrict__ AwT) {
    int i = threadIdx.x;   // 256 threads = 2*128
    if (i < 256) {
        int l = i >> 7, q = i & 127;
        int h = q >> 4, d = q & 15;
        AwT[l * 128 + h * 16 + d] = Aw[l * 128 + d * 8 + h];
    }
}

// One launch packs ALL weights (both layers) into MFMA B-fragment order.
#define PL_A (128*256)
#define PL_B (128*128)
__global__ __launch_bounds__(256) void k_packAll(
    const float* __restrict__ We,  const float* __restrict__ Woe, const float* __restrict__ Wq,
    const float* __restrict__ Wk,  const float* __restrict__ Wv,  const float* __restrict__ Woh,
    const float* __restrict__ W1,  const float* __restrict__ W2,  const float* __restrict__ VR,
    short* __restrict__ Wep,  short* __restrict__ Woep, short* __restrict__ Wqp,
    short* __restrict__ Wkp,  short* __restrict__ Wvp,  short* __restrict__ Wohp,
    short* __restrict__ W1p,  short* __restrict__ W2p,  short* __restrict__ VRp) {
    int s = blockIdx.x * 256 + threadIdx.x;
    const float* W; short* out; int ncol, perL; bool vr = false;
    if (s < 2 * PL_A) { W = We; out = Wep; ncol = 256; perL = PL_A; }
    else if ((s -= 2 * PL_A) < 2 * PL_B) { W = Woe; out = Woep; ncol = 128; perL = PL_B; }
    else if ((s -= 2 * PL_B) < 2 * PL_B) { W = Wq;  out = Wqp;  ncol = 128; perL = PL_B; }
    else if ((s -= 2 * PL_B) < 2 * PL_B) { W = Wk;  out = Wkp;  ncol = 128; perL = PL_B; }
    else if ((s -= 2 * PL_B) < 2 * PL_B) { W = Wv;  out = Wvp;  ncol = 128; perL = PL_B; }
    else if ((s -= 2 * PL_B) < 2 * PL_B) { W = Woh; out = Wohp; ncol = 128; perL = PL_B; }
    else if ((s -= 2 * PL_B) < 2 * PL_A) { W = W1;  out = W1p;  ncol = 256; perL = PL_A; }
    else if ((s -= 2 * PL_A) < 2 * PL_A) { W = W2;  out = W2p;  ncol = 128; perL = PL_A; }
    else if ((s -= 2 * PL_A) < 2 * PL_B) { W = VR;  out = VRp;  ncol = 128; perL = PL_B; vr = true; }
    else return;
    int l = s / perL, q = s % perL;
    int j = q & 7; int t2 = q >> 3; int kg = t2 & 3; t2 >>= 2;
    int col = t2 % ncol; int kt = t2 / ncol;
    int k = kt * 32 + kg * 8 + j;
    float v;
    if (vr) v = ((k >> 4) == (col >> 4)) ? VR[l * 2048 + (k & 15) * 128 + col] : 0.f;
    else    v = W[(size_t)l * perL + k * ncol + col];
    out[(size_t)l * perL + q] = (short)bf16r(v);
}

// ---------------- per-layer kernels ----------------

// Q/K/V via MFMA: 64 nodes/block, 512 threads (8 waves). Layer 0 only.
__global__ __launch_bounds__(512) void k_qkv(const float* __restrict__ x,
                                             const short* __restrict__ Wqp, const float* __restrict__ bq,
                                             const short* __restrict__ Wkp, const short* __restrict__ Wvp,
                                             unsigned short* __restrict__ Qh, unsigned short* __restrict__ Kh,
                                             unsigned short* __restrict__ Vh) {
    __shared__ short xsw[64 * 128];
    int t = threadIdx.x;
    int ci = t & 15, r0 = t >> 4;
    int n0 = blockIdx.x * 64;
    for (int rr = r0; rr < 64; rr += 32) {
        int n = n0 + rr;
        int4 pkv = make_int4(0, 0, 0, 0);
        if (n < NN) {
            const float4* src = (const float4*)(x + (size_t)n * 128 + ci * 8);
            float4 v0 = src[0], v1 = src[1];
            pkv.x = pk2(v0.x, v0.y); pkv.y = pk2(v0.z, v0.w);
            pkv.z = pk2(v1.x, v1.y); pkv.w = pk2(v1.z, v1.w);
        }
        int byte = (rr * 256 + ci * 16) ^ ((rr & 7) << 4);
        *(int4*)((char*)xsw + byte) = pkv;
    }
    __syncthreads();
    int lane = t & 63, w = t >> 6;
    int l15 = lane & 15, kg = lane >> 4;
    f32x4 acc[4][3];
#pragma unroll
    for (int m = 0; m < 4; ++m)
#pragma unroll
        for (int q = 0; q < 3; ++q) { acc[m][q][0] = 0.f; acc[m][q][1] = 0.f; acc[m][q][2] = 0.f; acc[m][q][3] = 0.f; }
    int col = w * 16 + l15;
#pragma unroll
    for (int kt = 0; kt < 4; ++kt) {
        s16x8 a[4];
#pragma unroll
        for (int m = 0; m < 4; ++m) {
            int row = m * 16 + l15;
            int abyte = (row * 256 + kt * 64 + kg * 16) ^ ((l15 & 7) << 4);
            a[m] = *(const s16x8*)((const char*)xsw + abyte);
        }
        size_t bo = ((size_t)((kt * 128 + col) * 4 + kg)) * 8;
        s16x8 bqf = *(const s16x8*)(Wqp + bo);
        s16x8 bkf = *(const s16x8*)(Wkp + bo);
        s16x8 bvf = *(const s16x8*)(Wvp + bo);
#pragma unroll
        for (int m = 0; m < 4; ++m) {
            acc[m][0] = mfma16(a[m], bqf, acc[m][0]);
            acc[m][1] = mfma16(a[m], bkf, acc[m][1]);
            acc[m][2] = mfma16(a[m], bvf, acc[m][2]);
        }
    }
    float bqv = bq[col];
#pragma unroll
    for (int m = 0; m < 4; ++m)
#pragma unroll
        for (int i = 0; i < 4; ++i) {
            int n = n0 + m * 16 + kg * 4 + i;
            if (n < NN) {
                Qh[(size_t)n * 128 + col] = bf16r(acc[m][0][i] + bqv);
                Kh[(size_t)n * 128 + col] = bf16r(acc[m][1][i]);
                Vh[(size_t)n * 128 + col] = bf16r(acc[m][2][i]);
            }
        }
}

// Fused edge kernel: 64 edges/block, 512 threads (8 waves).
// Ep pairs fp8 in LDS; sc computed in f32 (R14 numerics), sc stored f32.
template<bool IN_F32>
__global__ __launch_bounds__(512) void k_edgeA(const void* __restrict__ ea_, const int* __restrict__ ei,
                                               const int* __restrict__ epos,
                                               const short* __restrict__ Wep, const float* __restrict__ be,
                                               const float* __restrict__ AwT,
                                               const unsigned short* __restrict__ Qh,
                                               const unsigned short* __restrict__ Kh,
                                               unsigned char* __restrict__ e8, float* __restrict__ sc,
                                               const short* __restrict__ Woep, const float* __restrict__ boe,
                                               void* __restrict__ eout_) {
    __shared__ short eas[64 * 128];     // bf16 ea tile, XOR-swizzled (16 KB)
    __shared__ short epts[64 * EPS];    // fp8 (E_w,E_b) pairs, then bf16 ets tile (17.4 KB)
    __shared__ int eposs[64];
    const float* eaf = (const float*)ea_;
    const unsigned short* eab = (const unsigned short*)ea_;
    unsigned short* eout_b = (unsigned short*)eout_;
    float* eout_f = (float*)eout_;

    int e0 = blockIdx.x * 64;
    int t = threadIdx.x;
    int ci = t & 15, r0 = t >> 4;
    int eA = e0 + r0, eB = eA + 32;
    int siA = ei[eA], diA = ei[NE + eA];
    int siB = ei[eB], diB = ei[NE + eB];

    if (t < 64) eposs[t] = epos[e0 + t];
    {   // phase 1: stage ea -> bf16 swizzled
#pragma unroll
        for (int h = 0; h < 2; ++h) {
            int rr = r0 + h * 32;
            int4 pkv;
            if (IN_F32) {
                const float4* src = (const float4*)(eaf + (size_t)(e0 + rr) * 128 + ci * 8);
                float4 v0 = src[0], v1 = src[1];
                pkv.x = pk2(v0.x, v0.y); pkv.y = pk2(v0.z, v0.w);
                pkv.z = pk2(v1.x, v1.y); pkv.w = pk2(v1.z, v1.w);
            } else {
                pkv = *(const int4*)(eab + (size_t)(e0 + rr) * 128 + ci * 8);
            }
            int byte = (rr * 256 + ci * 16) ^ ((rr & 7) << 4);
            *(int4*)((char*)eas + byte) = pkv;
        }
    }
    __syncthreads();
    int posA = eposs[r0], posB = eposs[r0 + 32];
    union { int4 v; unsigned short us[8]; } kuA, quA, kuB, quB;
    kuA.v = *(const int4*)(Kh + (size_t)siA * 128 + ci * 8);
    quA.v = *(const int4*)(Qh + (size_t)diA * 128 + ci * 8);
    kuB.v = *(const int4*)(Kh + (size_t)siB * 128 + ci * 8);
    quB.v = *(const int4*)(Qh + (size_t)diB * 128 + ci * 8);

    int lane = t & 63, w = t >> 6;
    int l15 = lane & 15, kg = lane >> 4;
    {   // phase 2: Ep = eas @ We + be -> fp8 pairs in LDS
        f32x4 acc[4][2];
#pragma unroll
        for (int m = 0; m < 4; ++m)
#pragma unroll
            for (int q = 0; q < 2; ++q) { acc[m][q][0] = 0.f; acc[m][q][1] = 0.f; acc[m][q][2] = 0.f; acc[m][q][3] = 0.f; }
#pragma unroll
        for (int kt = 0; kt < 4; ++kt) {
            s16x8 a[4];
#pragma unroll
            for (int m = 0; m < 4; ++m) {
                int row = m * 16 + l15;
                int abyte = (row * 256 + kt * 64 + kg * 16) ^ ((l15 & 7) << 4);
                a[m] = *(const s16x8*)((const char*)eas + abyte);
            }
#pragma unroll
            for (int q = 0; q < 2; ++q) {
                int col = w * 32 + q * 16 + l15;
                s16x8 b = *(const s16x8*)(Wep + ((size_t)((kt * 256 + col) * 4 + kg)) * 8);
#pragma unroll
                for (int m = 0; m < 4; ++m) acc[m][q] = mfma16(a[m], b, acc[m][q]);
            }
        }
        float bw = be[w * 32 + l15], bb = be[w * 32 + 16 + l15];
#pragma unroll
        for (int m = 0; m < 4; ++m)
#pragma unroll
            for (int i = 0; i < 4; ++i) {
                int row = m * 16 + kg * 4 + i;
                int p8 = __builtin_amdgcn_cvt_pk_fp8_f32(acc[m][0][i] + bw, acc[m][1][i] + bb, 0, 0);
                epts[row * EPS + w * 16 + l15] = (short)p8;
            }
    }
    __syncthreads();
    int4 wA, wB;
    {
        wA = *(const int4*)(epts + (size_t)r0 * EPS + ci * 8);
        wB = *(const int4*)(epts + (size_t)(r0 + 32) * EPS + ci * 8);
    }
    __syncthreads();   // all Ep reads done before ets overwrites the buffer
    {   // phase 3: elementwise; f32 Aw dot (AwT vector loads)
        int hh = ci >> 1, dbase = (ci & 1) * 8;
        const float4* awp = (const float4*)(AwT + hh * 16 + dbase);
        float4 aw0 = awp[0], aw1 = awp[1];
        float aw[8] = {aw0.x, aw0.y, aw0.z, aw0.w, aw1.x, aw1.y, aw1.z, aw1.w};
#pragma unroll
        for (int h = 0; h < 2; ++h) {
            int r = r0 + h * 32;
            int pos = h ? posB : posA;
            const unsigned short* kus = h ? kuB.us : kuA.us;
            const unsigned short* qus = h ? quB.us : quA.us;
            const int4 ww = h ? wB : wA;
            int words[4] = {ww.x, ww.y, ww.z, ww.w};
            float p = 0.f;
            float etv[8];
#pragma unroll
            for (int k = 0; k < 4; ++k) {
                float ew0 = __builtin_amdgcn_cvt_f32_fp8(words[k], 0);
                float eb0 = __builtin_amdgcn_cvt_f32_fp8(words[k], 1);
                float ew1 = __builtin_amdgcn_cvt_f32_fp8(words[k], 2);
                float eb1 = __builtin_amdgcn_cvt_f32_fp8(words[k], 3);
                float kq0 = b2f(kus[2 * k]) + b2f(qus[2 * k]);
                float kq1 = b2f(kus[2 * k + 1]) + b2f(qus[2 * k + 1]);
                float sv0 = kq0 * ew0, sv1 = kq1 * ew1;
                float et0 = fmaxf(copysignf(sqrtf(fabsf(sv0)), sv0) + eb0, 0.f);
                float et1 = fmaxf(copysignf(sqrtf(fabsf(sv1)), sv1) + eb1, 0.f);
                etv[2 * k] = et0; etv[2 * k + 1] = et1;
                p += et0 * aw[2 * k] + et1 * aw[2 * k + 1];
            }
            int lo = __builtin_amdgcn_cvt_pk_fp8_f32(etv[0], etv[1], 0, 0);
            lo = __builtin_amdgcn_cvt_pk_fp8_f32(etv[2], etv[3], lo, 1);
            int hi = __builtin_amdgcn_cvt_pk_fp8_f32(etv[4], etv[5], 0, 0);
            hi = __builtin_amdgcn_cvt_pk_fp8_f32(etv[6], etv[7], hi, 1);
            *(int2*)(e8 + (size_t)pos * 128 + ci * 8) = make_int2(lo, hi);
            int4 pkv;
            pkv.x = pk2(etv[0], etv[1]); pkv.y = pk2(etv[2], etv[3]);
            pkv.z = pk2(etv[4], etv[5]); pkv.w = pk2(etv[6], etv[7]);
            int byte = (r * 256 + ci * 16) ^ ((r & 7) << 4);
            *(int4*)((char*)epts + byte) = pkv;
            p += __shfl_xor(p, 1);
            if ((ci & 1) == 0) {
                float s = fminf(fmaxf(p, -CLAMPV), CLAMPV);
                sc[(size_t)pos * 8 + hh] = s;
            }
        }
    }
    __syncthreads();
    {   // phase 4: e_out = (ea + ets @ Woe + boe) * BNS
        f32x4 acc[4];
#pragma unroll
        for (int m = 0; m < 4; ++m) { acc[m][0] = 0.f; acc[m][1] = 0.f; acc[m][2] = 0.f; acc[m][3] = 0.f; }
        int col = w * 16 + l15;
#pragma unroll
        for (int kt = 0; kt < 4; ++kt) {
            s16x8 a[4];
#pragma unroll
            for (int m = 0; m < 4; ++m) {
                int row = m * 16 + l15;
                int abyte = (row * 256 + kt * 64 + kg * 16) ^ ((l15 & 7) << 4);
                a[m] = *(const s16x8*)((const char*)epts + abyte);
            }
            s16x8 b = *(const s16x8*)(Woep + ((size_t)((kt * 128 + col) * 4 + kg)) * 8);
#pragma unroll
            for (int m = 0; m < 4; ++m) acc[m] = mfma16(a[m], b, acc[m]);
        }
        float bb = boe[col];
#pragma unroll
        for (int m = 0; m < 4; ++m)
#pragma unroll
            for (int i = 0; i < 4; ++i) {
                int rr = m * 16 + kg * 4 + i;
                int rbyte = (rr * 256 + col * 2) ^ ((rr & 7) << 4);
                float res = b2f(*(const unsigned short*)((const char*)eas + rbyte));
                size_t idx = (size_t)(e0 + rr) * 128 + col;
                float v = (res + acc[m][i] + bb) * BNS;
                if (IN_F32) eout_b[idx] = bf16r(v);
                else        eout_f[idx] = v;
            }
    }
}

// Node attention: one 64-lane wave per node, single pass (sc pre-clamped -> no max needed).
__global__ __launch_bounds__(64) void k_nattn(const int* __restrict__ offs, const int* __restrict__ csr_src,
                                              const float* __restrict__ sc,
                                              const unsigned char* __restrict__ e8,
                                              const unsigned short* __restrict__ Vh,
                                              unsigned short* __restrict__ wVb,
                                              unsigned short* __restrict__ rowVb) {
    int n = blockIdx.x;
    int lane = threadIdx.x;
    int beg = offs[n], end = offs[n + 1];
    int hv = lane >> 3;                   // head of cols (2*lane, 2*lane+1)
    float dsum = 0.f, av0 = 0.f, av1 = 0.f, ar0 = 0.f, ar1 = 0.f;
    auto body = [&](int i) {
        float a = __expf(sc[(size_t)i * 8 + hv]);
        dsum += a;
        int s = csr_src[i];
        int v = ((const int*)Vh)[(size_t)s * 64 + lane];
        int u8 = ((const unsigned short*)e8)[(size_t)i * 64 + lane];
        av0 += b2f((unsigned short)v) * a;
        av1 += b2f((unsigned short)((unsigned)v >> 16)) * a;
        ar0 += __builtin_amdgcn_cvt_f32_fp8(u8, 0) * a;
        ar1 += __builtin_amdgcn_cvt_f32_fp8(u8, 1) * a;
    };
    int i = beg;
    for (; i + 4 <= end; i += 4) { body(i); body(i + 1); body(i + 2); body(i + 3); }
    for (; i < end; ++i) body(i);
    float inv = 1.f / (dsum + 1e-16f);
    ((int*)wVb)[(size_t)n * 64 + lane]   = pk2(av0 * inv, av1 * inv);
    ((int*)rowVb)[(size_t)n * 64 + lane] = pk2(ar0 * inv, ar1 * inv);
}

// Node post via MFMA: 32 nodes/block, 256 threads (4 waves), LDS 24 KB.
template<bool EMIT>
__global__ __launch_bounds__(256) void k_nodeB(
    const unsigned short* __restrict__ wVb, const unsigned short* __restrict__ rowVb,
    const short* __restrict__ VRp, const float* __restrict__ dc,
    const float* __restrict__ logdeg, const float* __restrict__ x,
    const short* __restrict__ Wohp, const float* __restrict__ boh,
    const short* __restrict__ W1p, const float* __restrict__ b1,
    const short* __restrict__ W2p, const float* __restrict__ b2,
    float* __restrict__ xout,
    const short* __restrict__ Wqp2, const float* __restrict__ bq2,
    const short* __restrict__ Wkp2, const short* __restrict__ Wvp2,
    unsigned short* __restrict__ Qh2, unsigned short* __restrict__ Kh2,
    unsigned short* __restrict__ Vh2) {
    __shared__ short bufA[32 * 128];   // rowV staging / h1 / out (8 KB)
    __shared__ short bufU[32 * 256];   // hs / us (16 KB)
    int n0 = blockIdx.x * 32;
    int t = threadIdx.x;
    int ci = t & 15, r0 = t >> 4;      // r0 in 0..15
    {   // p0: stage rowV (bf16) -> bufA swizzled
#pragma unroll
        for (int h = 0; h < 2; ++h) {
            int rr = r0 + h * 16, n = n0 + rr;
            int4 pkv = make_int4(0, 0, 0, 0);
            if (n < NN) pkv = *(const int4*)(rowVb + (size_t)n * 128 + ci * 8);
            int byte = (rr * 256 + ci * 16) ^ ((rr & 7) << 4);
            *(int4*)((char*)bufA + byte) = pkv;
        }
    }
    __syncthreads();
    int lane = t & 63, w = t >> 6;     // w in 0..3
    int l15 = lane & 15, kg = lane >> 4;
    int cq[2] = {w * 32 + l15, w * 32 + 16 + l15};
    {   // p1: hs = (wV + rowV@VeRowBD) * degscale -> bufU
        f32x4 acc[2][2];
#pragma unroll
        for (int m = 0; m < 2; ++m)
#pragma unroll
            for (int q = 0; q < 2; ++q)
#pragma unroll
                for (int i = 0; i < 4; ++i) {
                    int n = n0 + m * 16 + kg * 4 + i;
                    acc[m][q][i] = (n < NN) ? b2f(wVb[(size_t)n * 128 + cq[q]]) : 0.f;
                }
#pragma unroll
        for (int kt = 0; kt < 4; ++kt) {
            s16x8 a[2];
#pragma unroll
            for (int m = 0; m < 2; ++m) {
                int row = m * 16 + l15;
                int abyte = (row * 256 + kt * 64 + kg * 16) ^ ((l15 & 7) << 4);
                a[m] = *(const s16x8*)((const char*)bufA + abyte);
            }
#pragma unroll
            for (int q = 0; q < 2; ++q) {
                s16x8 b = *(const s16x8*)(VRp + ((size_t)((kt * 128 + cq[q]) * 4 + kg)) * 8);
#pragma unroll
                for (int m = 0; m < 2; ++m) acc[m][q] = mfma16(a[m], b, acc[m][q]);
            }
        }
#pragma unroll
        for (int q = 0; q < 2; ++q) {
            float d0 = dc[cq[q] * 2], d1 = dc[cq[q] * 2 + 1];
#pragma unroll
            for (int m = 0; m < 2; ++m)
#pragma unroll
                for (int i = 0; i < 4; ++i) {
                    int rr = m * 16 + kg * 4 + i, n = n0 + rr;
                    float ld = (n < NN) ? logdeg[n] : 0.f;
                    float hs = acc[m][q][i] * (d0 + ld * d1);
                    int byte = (rr * 256 + cq[q] * 2) ^ ((rr & 7) << 4);
                    *(unsigned short*)((char*)bufU + byte) = bf16r(hs);
                }
        }
    }
    __syncthreads();
    float h1r[2][2][4];
    {   // p2: h1 = (x + hs@Woh + boh)*BNS -> bufA + regs
        f32x4 acc[2][2];
#pragma unroll
        for (int m = 0; m < 2; ++m)
#pragma unroll
            for (int q = 0; q < 2; ++q) { acc[m][q][0] = 0.f; acc[m][q][1] = 0.f; acc[m][q][2] = 0.f; acc[m][q][3] = 0.f; }
#pragma unroll
        for (int kt = 0; kt < 4; ++kt) {
            s16x8 a[2];
#pragma unroll
            for (int m = 0; m < 2; ++m) {
                int row = m * 16 + l15;
                int abyte = (row * 256 + kt * 64 + kg * 16) ^ ((l15 & 7) << 4);
                a[m] = *(const s16x8*)((const char*)bufU + abyte);
            }
#pragma unroll
            for (int q = 0; q < 2; ++q) {
                s16x8 b = *(const s16x8*)(Wohp + ((size_t)((kt * 128 + cq[q]) * 4 + kg)) * 8);
#pragma unroll
                for (int m = 0; m < 2; ++m) acc[m][q] = mfma16(a[m], b, acc[m][q]);
            }
        }
#pragma unroll
        for (int q = 0; q < 2; ++q) {
            float bb = boh[cq[q]];
#pragma unroll
            for (int m = 0; m < 2; ++m)
#pragma unroll
                for (int i = 0; i < 4; ++i) {
                    int rr = m * 16 + kg * 4 + i, n = n0 + rr;
                    float xv = (n < NN) ? x[(size_t)n * 128 + cq[q]] : 0.f;
                    float h1 = (xv + acc[m][q][i] + bb) * BNS;
                    h1r[m][q][i] = h1;
                    int byte = (rr * 256 + cq[q] * 2) ^ ((rr & 7) << 4);
                    *(unsigned short*)((char*)bufA + byte) = bf16r(h1);
                }
        }
    }
    __syncthreads();
    {   // p3: us = relu(h1@W1 + b1) -> bufU
        f32x4 acc[2][4];
#pragma unroll
        for (int m = 0; m < 2; ++m)
#pragma unroll
            for (int q = 0; q < 4; ++q) { acc[m][q][0] = 0.f; acc[m][q][1] = 0.f; acc[m][q][2] = 0.f; acc[m][q][3] = 0.f; }
#pragma unroll
        for (int kt = 0; kt < 4; ++kt) {
            s16x8 a[2];
#pragma unroll
            for (int m = 0; m < 2; ++m) {
                int row = m * 16 + l15;
                int abyte = (row * 256 + kt * 64 + kg * 16) ^ ((l15 & 7) << 4);
                a[m] = *(const s16x8*)((const char*)bufA + abyte);
            }
#pragma unroll
            for (int q = 0; q < 4; ++q) {
                int colq = w * 64 + q * 16 + l15;
                s16x8 b = *(const s16x8*)(W1p + ((size_t)((kt * 256 + colq) * 4 + kg)) * 8);
#pragma unroll
                for (int m = 0; m < 2; ++m) acc[m][q] = mfma16(a[m], b, acc[m][q]);
            }
        }
        __syncthreads();   // hs reads (p2) complete before us overwrites bufU
#pragma unroll
        for (int q = 0; q < 4; ++q) {
            int colq = w * 64 + q * 16 + l15;
            float bb = b1[colq];
#pragma unroll
            for (int m = 0; m < 2; ++m)
#pragma unroll
                for (int i = 0; i < 4; ++i) {
                    int rr = m * 16 + kg * 4 + i;
                    float us = fmaxf(acc[m][q][i] + bb, 0.f);
                    int byte = (rr * 512 + colq * 2) ^ ((rr & 7) << 4);
                    *(unsigned short*)((char*)bufU + byte) = bf16r(us);
                }
        }
    }
    __syncthreads();
    {   // p4: out = (h1 + us@W2 + b2)*BNS; EMIT: stage out bf16 into bufA
        f32x4 acc[2][2];
#pragma unroll
        for (int m = 0; m < 2; ++m)
#pragma unroll
            for (int q = 0; q < 2; ++q) { acc[m][q][0] = 0.f; acc[m][q][1] = 0.f; acc[m][q][2] = 0.f; acc[m][q][3] = 0.f; }
#pragma unroll
        for (int kt = 0; kt < 8; ++kt) {
            s16x8 a[2];
#pragma unroll
            for (int m = 0; m < 2; ++m) {
                int row = m * 16 + l15;
                int abyte = (row * 512 + kt * 64 + kg * 16) ^ ((l15 & 7) << 4);
                a[m] = *(const s16x8*)((const char*)bufU + abyte);
            }
#pragma unroll
            for (int q = 0; q < 2; ++q) {
                s16x8 b = *(const s16x8*)(W2p + ((size_t)((kt * 128 + cq[q]) * 4 + kg)) * 8);
#pragma unroll
                for (int m = 0; m < 2; ++m) acc[m][q] = mfma16(a[m], b, acc[m][q]);
            }
        }
#pragma unroll
        for (int q = 0; q < 2; ++q) {
            float bb = b2[cq[q]];
#pragma unroll
            for (int m = 0; m < 2; ++m)
#pragma unroll
                for (int i = 0; i < 4; ++i) {
                    int rr = m * 16 + kg * 4 + i, n = n0 + rr;
                    float outv = (h1r[m][q][i] + acc[m][q][i] + bb) * BNS;
                    if (n < NN) xout[(size_t)n * 128 + cq[q]] = outv;
                    if (EMIT) {
                        int byte = (rr * 256 + cq[q] * 2) ^ ((rr & 7) << 4);
                        *(unsigned short*)((char*)bufA + byte) = bf16r(outv);
                    }
                }
        }
    }
    if (EMIT) {   // next-layer Q/K/V from staged out
        __syncthreads();
        f32x4 acc[2][2][3];
#pragma unroll
        for (int m = 0; m < 2; ++m)
#pragma unroll
            for (int q = 0; q < 2; ++q)
#pragma unroll
                for (int o = 0; o < 3; ++o) { acc[m][q][o][0] = 0.f; acc[m][q][o][1] = 0.f; acc[m][q][o][2] = 0.f; acc[m][q][o][3] = 0.f; }
#pragma unroll
        for (int kt = 0; kt < 4; ++kt) {
            s16x8 a[2];
#pragma unroll
            for (int m = 0; m < 2; ++m) {
                int row = m * 16 + l15;
                int abyte = (row * 256 + kt * 64 + kg * 16) ^ ((l15 & 7) << 4);
                a[m] = *(const s16x8*)((const char*)bufA + abyte);
            }
#pragma unroll
            for (int q = 0; q < 2; ++q) {
                size_t bo = ((size_t)((kt * 128 + cq[q]) * 4 + kg)) * 8;
                s16x8 bqf = *(const s16x8*)(Wqp2 + bo);
                s16x8 bkf = *(const s16x8*)(Wkp2 + bo);
                s16x8 bvf = *(const s16x8*)(Wvp2 + bo);
#pragma unroll
                for (int m = 0; m < 2; ++m) {
                    acc[m][q][0] = mfma16(a[m], bqf, acc[m][q][0]);
                    acc[m][q][1] = mfma16(a[m], bkf, acc[m][q][1]);
                    acc[m][q][2] = mfma16(a[m], bvf, acc[m][q][2]);
                }
            }
        }
#pragma unroll
        for (int q = 0; q < 2; ++q) {
            float bqv = bq2[cq[q]];
#pragma unroll
            for (int m = 0; m < 2; ++m)
#pragma unroll
                for (int i = 0; i < 4; ++i) {
                    int n = n0 + m * 16 + kg * 4 + i;
                    if (n < NN) {
                        Qh2[(size_t)n * 128 + cq[q]] = bf16r(acc[m][q][0][i] + bqv);
                        Kh2[(size_t)n * 128 + cq[q]] = bf16r(acc[m][q][1][i]);
                        Vh2[(size_t)n * 128 + cq[q]] = bf16r(acc[m][q][2][i]);
                    }
                }
        }
    }
}

// ---------------- host launch ----------------

extern "C" void kernel_launch(void* const* d_in, const int* in_sizes, int n_in,
                              void* d_out, int out_size, void* d_ws, size_t ws_size,
                              hipStream_t stream) {
    (void)in_sizes; (void)n_in; (void)out_size; (void)ws_size;
    const float* x_in0  = (const float*)d_in[0];
    const int*   ei     = (const int*)d_in[1];
    const float* ea_in0 = (const float*)d_in[2];
    const float* Wq = (const float*)d_in[3];
    const float* bq = (const float*)d_in[4];
    const float* Wk = (const float*)d_in[5];
    const float* Wv = (const float*)d_in[6];
    const float* We = (const float*)d_in[7];
    const float* be = (const float*)d_in[8];
    const float* Aw = (const float*)d_in[9];
    const float* VeRow = (const float*)d_in[10];
    const float* Woh = (const float*)d_in[11];
    const float* boh = (const float*)d_in[12];
    const float* Woe = (const float*)d_in[13];
    const float* boe = (const float*)d_in[14];
    const float* dc  = (const float*)d_in[15];
    const float* W1 = (const float*)d_in[16];
    const float* b1 = (const float*)d_in[17];
    const float* W2 = (const float*)d_in[18];
    const float* b2 = (const float*)d_in[19];

    char* ws = (char*)d_ws;
    size_t off = 0;
    auto alloc = [&](size_t bytes) { void* p = ws + off; off = (off + bytes + 255) & ~(size_t)255; return p; };
    int*   deg    = (int*)alloc((size_t)NN * 4);
    int*   cursor = (int*)alloc((size_t)NN * 4);
    int*   offs   = (int*)alloc((size_t)(NN + 1) * 4);
    int*   bsum   = (int*)alloc((size_t)64 * 4);
    int*   csr_src= (int*)alloc((size_t)NE * 4);
    int*   epos   = (int*)alloc((size_t)NE * 4);
    float* logdeg = (float*)alloc((size_t)NN * 4);
    float* AwT    = (float*)alloc((size_t)2 * 128 * 4);
    unsigned short* Qh  = (unsigned short*)alloc((size_t)NN * 128 * 2);
    unsigned short* Kh  = (unsigned short*)alloc((size_t)NN * 128 * 2);
    unsigned short* Vh  = (unsigned short*)alloc((size_t)NN * 128 * 2);
    unsigned short* Qh2 = (unsigned short*)alloc((size_t)NN * 128 * 2);
    unsigned short* Kh2 = (unsigned short*)alloc((size_t)NN * 128 * 2);
    unsigned short* Vh2 = (unsigned short*)alloc((size_t)NN * 128 * 2);
    unsigned char* e8   = (unsigned char*)alloc((size_t)NE * 128);
    unsigned short* ea_bf = (unsigned short*)alloc((size_t)NE * 128 * 2);
    float* sc     = (float*)alloc((size_t)NE * 8 * 4);
    unsigned short* wVb   = (unsigned short*)alloc((size_t)NN * 128 * 2);
    unsigned short* rowVb = (unsigned short*)alloc((size_t)NN * 128 * 2);
    short* Wep    = (short*)alloc((size_t)2 * 128 * 256 * 2);
    short* Woep   = (short*)alloc((size_t)2 * 128 * 128 * 2);
    short* Wqp    = (short*)alloc((size_t)2 * 128 * 128 * 2);
    short* Wkp    = (short*)alloc((size_t)2 * 128 * 128 * 2);
    short* Wvp    = (short*)alloc((size_t)2 * 128 * 128 * 2);
    short* Wohp   = (short*)alloc((size_t)2 * 128 * 128 * 2);
    short* W1p    = (short*)alloc((size_t)2 * 128 * 256 * 2);
    short* W2p    = (short*)alloc((size_t)2 * 256 * 128 * 2);
    short* VRp    = (short*)alloc((size_t)2 * 128 * 128 * 2);

    float* out_x = (float*)d_out;
    float* out_e = out_x + (size_t)NN * 128;

    hipError_t err;
    err = hipMemsetAsync(deg, 0, (size_t)NN * 4, stream); (void)err;
    err = hipMemsetAsync(cursor, 0, (size_t)NN * 4, stream); (void)err;

    k_deg<<<(NE + 255) / 256, 256, 0, stream>>>(ei, deg);
    k_scan1<<<NBLK, 1024, 0, stream>>>(deg, offs, bsum, logdeg);
    k_scan3<<<NBLK, 1024, 0, stream>>>(offs, bsum);
    k_fill<<<(NE + 255) / 256, 256, 0, stream>>>(ei, offs, cursor, csr_src, epos);
    k_awt<<<1, 256, 0, stream>>>(Aw, AwT);
    k_packAll<<<1536, 256, 0, stream>>>(We, Woe, Wq, Wk, Wv, Woh, W1, W2, VeRow,
                                        Wep, Woep, Wqp, Wkp, Wvp, Wohp, W1p, W2p, VRp);

    // ---- layer 0 ----
    k_qkv<<<(NN + 63) / 64, 512, 0, stream>>>(x_in0, Wqp, bq, Wkp, Wvp, Qh, Kh, Vh);
    k_edgeA<true><<<NE / 64, 512, 0, stream>>>(ea_in0, ei, epos, Wep, be, AwT, Qh, Kh,
                                               e8, sc, Woep, boe, ea_bf);
    k_nattn<<<NN, 64, 0, stream>>>(offs, csr_src, sc, e8, Vh, wVb, rowVb);
    k_nodeB<true><<<(NN + 31) / 32, 256, 0, stream>>>(
        wVb, rowVb, VRp, dc, logdeg, x_in0,
        Wohp, boh, W1p, b1, W2p, b2, out_x,
        Wqp + 128 * 128, bq + 128, Wkp + 128 * 128, Wvp + 128 * 128, Qh2, Kh2, Vh2);

    // ---- layer 1 ----
    k_edgeA<false><<<NE / 64, 512, 0, stream>>>(ea_bf, ei, epos, Wep + 128 * 256, be + 256,
                                                AwT + 128, Qh2, Kh2, e8, sc,
                                                Woep + 128 * 128, boe + 128, out_e);
    k_nattn<<<NN, 64, 0, stream>>>(offs, csr_src, sc, e8, Vh2, wVb, rowVb);
    k_nodeB<false><<<(NN + 31) / 32, 256, 0, stream>>>(
        wVb, rowVb, VRp + 128 * 128, dc + 256, logdeg, out_x,
        Wohp + 128 * 128, boh + 128, W1p + 128 * 256, b1 + 256, W2p + 256 * 128, b2 + 128, out_x,
        nullptr, nullptr, nullptr, nullptr, nullptr, nullptr, nullptr);
}

// Round 17
// 873.598 us; speedup vs baseline: 1.9036x; 1.0047x over previous
//
#include <hip/hip_runtime.h>

#define NN 50000
#define NE 800000
#define CLAMPV 5.0f
#define BNS 0.9999950000374997f
#define EPS 136    // ushort stride of fp8 Ep rows (272B, 16B-aligned)
#define NBLK 49    // ceil(NN/1024)

typedef __attribute__((ext_vector_type(8))) short s16x8;
typedef __attribute__((ext_vector_type(8))) __bf16 bf16x8;
typedef __attribute__((ext_vector_type(4))) float f32x4;

__device__ inline f32x4 mfma16(s16x8 a, s16x8 b, f32x4 c) {
    return __builtin_amdgcn_mfma_f32_16x16x32_bf16(
        __builtin_bit_cast(bf16x8, a), __builtin_bit_cast(bf16x8, b), c, 0, 0, 0);
}

__device__ inline unsigned short bf16r(float f) {
    return __builtin_bit_cast(unsigned short, (__bf16)f);
}

__device__ inline int pk2(float a, float b) {
    return (int)(unsigned)bf16r(a) | ((int)(unsigned)bf16r(b) << 16);
}

__device__ inline float b2f(unsigned short u) {
    return __builtin_bit_cast(float, (unsigned)u << 16);
}

// ---------------- degree / CSR build ----------------

__global__ __launch_bounds__(256) void k_deg(const int* __restrict__ ei, int* __restrict__ deg) {
    int e = blockIdx.x * 256 + threadIdx.x;
    if (e < NE) atomicAdd(&deg[ei[NE + e]], 1);
}

__global__ __launch_bounds__(1024) void k_scan1(const int* __restrict__ deg, int* __restrict__ offs,
                                                int* __restrict__ bsum, float* __restrict__ logdeg) {
    __shared__ int sm[1024];
    int i = blockIdx.x * 1024 + threadIdx.x;
    int v = (i < NN) ? deg[i] : 0;
    if (i < NN) logdeg[i] = logf((float)v + 1.0f);
    sm[threadIdx.x] = v;
    __syncthreads();
    for (int s = 1; s < 1024; s <<= 1) {
        int t = (threadIdx.x >= s) ? sm[threadIdx.x - s] : 0;
        __syncthreads();
        sm[threadIdx.x] += t;
        __syncthreads();
    }
    if (i < NN) offs[i + 1] = sm[threadIdx.x];
    if (threadIdx.x == 1023) bsum[blockIdx.x] = sm[1023];
    if (blockIdx.x == 0 && threadIdx.x == 0) offs[0] = 0;
}

__global__ __launch_bounds__(1024) void k_scan3(int* __restrict__ offs, const int* __restrict__ bsum) {
    __shared__ int pre;
    if (threadIdx.x == 0) {
        int acc = 0;
        for (int i = 0; i < (int)blockIdx.x; ++i) acc += bsum[i];
        pre = acc;
    }
    __syncthreads();
    int i = blockIdx.x * 1024 + threadIdx.x;
    if (i < NN) offs[i + 1] += pre;
}

__global__ __launch_bounds__(256) void k_fill(const int* __restrict__ ei, const int* __restrict__ offs,
                                              int* __restrict__ cursor, int* __restrict__ csr_src,
                                              int* __restrict__ epos) {
    int e = blockIdx.x * 256 + threadIdx.x;
    if (e < NE) {
        int d = ei[NE + e];
        int pos = offs[d] + atomicAdd(&cursor[d], 1);
        csr_src[pos] = ei[e];
        epos[e] = pos;
    }
}

// Transpose Aw (D=16,H=8) -> AwT[h][d] for both layers (vector-loadable by head).
__global__ void k_awt(const float* __restrict__ Aw, float* __restrict__ AwT) {
    int i = threadIdx.x;   // 256 threads = 2*128
    if (i < 256) {
        int l = i >> 7, q = i & 127;
        int h = q >> 4, d = q & 15;
        AwT[l * 128 + h * 16 + d] = Aw[l * 128 + d * 8 + h];
    }
}

// One launch packs ALL weights (both layers) into MFMA B-fragment order.
#define PL_A (128*256)
#define PL_B (128*128)
__global__ __launch_bounds__(256) void k_packAll(
    const float* __restrict__ We,  const float* __restrict__ Woe, const float* __restrict__ Wq,
    const float* __restrict__ Wk,  const float* __restrict__ Wv,  const float* __restrict__ Woh,
    const float* __restrict__ W1,  const float* __restrict__ W2,  const float* __restrict__ VR,
    short* __restrict__ Wep,  short* __restrict__ Woep, short* __restrict__ Wqp,
    short* __restrict__ Wkp,  short* __restrict__ Wvp,  short* __restrict__ Wohp,
    short* __restrict__ W1p,  short* __restrict__ W2p,  short* __restrict__ VRp) {
    int s = blockIdx.x * 256 + threadIdx.x;
    const float* W; short* out; int ncol, perL; bool vr = false;
    if (s < 2 * PL_A) { W = We; out = Wep; ncol = 256; perL = PL_A; }
    else if ((s -= 2 * PL_A) < 2 * PL_B) { W = Woe; out = Woep; ncol = 128; perL = PL_B; }
    else if ((s -= 2 * PL_B) < 2 * PL_B) { W = Wq;  out = Wqp;  ncol = 128; perL = PL_B; }
    else if ((s -= 2 * PL_B) < 2 * PL_B) { W = Wk;  out = Wkp;  ncol = 128; perL = PL_B; }
    else if ((s -= 2 * PL_B) < 2 * PL_B) { W = Wv;  out = Wvp;  ncol = 128; perL = PL_B; }
    else if ((s -= 2 * PL_B) < 2 * PL_B) { W = Woh; out = Wohp; ncol = 128; perL = PL_B; }
    else if ((s -= 2 * PL_B) < 2 * PL_A) { W = W1;  out = W1p;  ncol = 256; perL = PL_A; }
    else if ((s -= 2 * PL_A) < 2 * PL_A) { W = W2;  out = W2p;  ncol = 128; perL = PL_A; }
    else if ((s -= 2 * PL_A) < 2 * PL_B) { W = VR;  out = VRp;  ncol = 128; perL = PL_B; vr = true; }
    else return;
    int l = s / perL, q = s % perL;
    int j = q & 7; int t2 = q >> 3; int kg = t2 & 3; t2 >>= 2;
    int col = t2 % ncol; int kt = t2 / ncol;
    int k = kt * 32 + kg * 8 + j;
    float v;
    if (vr) v = ((k >> 4) == (col >> 4)) ? VR[l * 2048 + (k & 15) * 128 + col] : 0.f;
    else    v = W[(size_t)l * perL + k * ncol + col];
    out[(size_t)l * perL + q] = (short)bf16r(v);
}

// ---------------- per-layer kernels ----------------

// Q/K/V via MFMA: 64 nodes/block, 512 threads (8 waves). Layer 0 only.
__global__ __launch_bounds__(512) void k_qkv(const float* __restrict__ x,
                                             const short* __restrict__ Wqp, const float* __restrict__ bq,
                                             const short* __restrict__ Wkp, const short* __restrict__ Wvp,
                                             unsigned short* __restrict__ Qh, unsigned short* __restrict__ Kh,
                                             unsigned short* __restrict__ Vh) {
    __shared__ short xsw[64 * 128];
    int t = threadIdx.x;
    int ci = t & 15, r0 = t >> 4;
    int n0 = blockIdx.x * 64;
    for (int rr = r0; rr < 64; rr += 32) {
        int n = n0 + rr;
        int4 pkv = make_int4(0, 0, 0, 0);
        if (n < NN) {
            const float4* src = (const float4*)(x + (size_t)n * 128 + ci * 8);
            float4 v0 = src[0], v1 = src[1];
            pkv.x = pk2(v0.x, v0.y); pkv.y = pk2(v0.z, v0.w);
            pkv.z = pk2(v1.x, v1.y); pkv.w = pk2(v1.z, v1.w);
        }
        int byte = (rr * 256 + ci * 16) ^ ((rr & 7) << 4);
        *(int4*)((char*)xsw + byte) = pkv;
    }
    __syncthreads();
    int lane = t & 63, w = t >> 6;
    int l15 = lane & 15, kg = lane >> 4;
    f32x4 acc[4][3];
#pragma unroll
    for (int m = 0; m < 4; ++m)
#pragma unroll
        for (int q = 0; q < 3; ++q) { acc[m][q][0] = 0.f; acc[m][q][1] = 0.f; acc[m][q][2] = 0.f; acc[m][q][3] = 0.f; }
    int col = w * 16 + l15;
#pragma unroll
    for (int kt = 0; kt < 4; ++kt) {
        s16x8 a[4];
#pragma unroll
        for (int m = 0; m < 4; ++m) {
            int row = m * 16 + l15;
            int abyte = (row * 256 + kt * 64 + kg * 16) ^ ((l15 & 7) << 4);
            a[m] = *(const s16x8*)((const char*)xsw + abyte);
        }
        size_t bo = ((size_t)((kt * 128 + col) * 4 + kg)) * 8;
        s16x8 bqf = *(const s16x8*)(Wqp + bo);
        s16x8 bkf = *(const s16x8*)(Wkp + bo);
        s16x8 bvf = *(const s16x8*)(Wvp + bo);
#pragma unroll
        for (int m = 0; m < 4; ++m) {
            acc[m][0] = mfma16(a[m], bqf, acc[m][0]);
            acc[m][1] = mfma16(a[m], bkf, acc[m][1]);
            acc[m][2] = mfma16(a[m], bvf, acc[m][2]);
        }
    }
    float bqv = bq[col];
#pragma unroll
    for (int m = 0; m < 4; ++m)
#pragma unroll
        for (int i = 0; i < 4; ++i) {
            int n = n0 + m * 16 + kg * 4 + i;
            if (n < NN) {
                Qh[(size_t)n * 128 + col] = bf16r(acc[m][0][i] + bqv);
                Kh[(size_t)n * 128 + col] = bf16r(acc[m][1][i]);
                Vh[(size_t)n * 128 + col] = bf16r(acc[m][2][i]);
            }
        }
}

// Fused edge kernel: 64 edges/block, 512 threads (8 waves).
// K/Q gathers issued at kernel top (T14): fly under phase-1 staging + barrier + phase 2.
template<bool IN_F32>
__global__ __launch_bounds__(512) void k_edgeA(const void* __restrict__ ea_, const int* __restrict__ ei,
                                               const int* __restrict__ epos,
                                               const short* __restrict__ Wep, const float* __restrict__ be,
                                               const float* __restrict__ AwT,
                                               const unsigned short* __restrict__ Qh,
                                               const unsigned short* __restrict__ Kh,
                                               unsigned char* __restrict__ e8, float* __restrict__ sc,
                                               const short* __restrict__ Woep, const float* __restrict__ boe,
                                               void* __restrict__ eout_) {
    __shared__ short eas[64 * 128];     // bf16 ea tile, XOR-swizzled (16 KB)
    __shared__ short epts[64 * EPS];    // fp8 (E_w,E_b) pairs, then bf16 ets tile (17.4 KB)
    __shared__ int eposs[64];
    const float* eaf = (const float*)ea_;
    const unsigned short* eab = (const unsigned short*)ea_;
    unsigned short* eout_b = (unsigned short*)eout_;
    float* eout_f = (float*)eout_;

    int e0 = blockIdx.x * 64;
    int t = threadIdx.x;
    int ci = t & 15, r0 = t >> 4;
    int eA = e0 + r0, eB = eA + 32;
    int siA = ei[eA], diA = ei[NE + eA];
    int siB = ei[eB], diB = ei[NE + eB];

    // K/Q gathers issued FIRST — consumed in phase 3
    union { int4 v; unsigned short us[8]; } kuA, quA, kuB, quB;
    kuA.v = *(const int4*)(Kh + (size_t)siA * 128 + ci * 8);
    quA.v = *(const int4*)(Qh + (size_t)diA * 128 + ci * 8);
    kuB.v = *(const int4*)(Kh + (size_t)siB * 128 + ci * 8);
    quB.v = *(const int4*)(Qh + (size_t)diB * 128 + ci * 8);

    if (t < 64) eposs[t] = epos[e0 + t];
    {   // phase 1: stage ea -> bf16 swizzled
#pragma unroll
        for (int h = 0; h < 2; ++h) {
            int rr = r0 + h * 32;
            int4 pkv;
            if (IN_F32) {
                const float4* src = (const float4*)(eaf + (size_t)(e0 + rr) * 128 + ci * 8);
                float4 v0 = src[0], v1 = src[1];
                pkv.x = pk2(v0.x, v0.y); pkv.y = pk2(v0.z, v0.w);
                pkv.z = pk2(v1.x, v1.y); pkv.w = pk2(v1.z, v1.w);
            } else {
                pkv = *(const int4*)(eab + (size_t)(e0 + rr) * 128 + ci * 8);
            }
            int byte = (rr * 256 + ci * 16) ^ ((rr & 7) << 4);
            *(int4*)((char*)eas + byte) = pkv;
        }
    }
    __syncthreads();
    int posA = eposs[r0], posB = eposs[r0 + 32];

    int lane = t & 63, w = t >> 6;
    int l15 = lane & 15, kg = lane >> 4;
    {   // phase 2: Ep = eas @ We + be -> fp8 pairs in LDS
        f32x4 acc[4][2];
#pragma unroll
        for (int m = 0; m < 4; ++m)
#pragma unroll
            for (int q = 0; q < 2; ++q) { acc[m][q][0] = 0.f; acc[m][q][1] = 0.f; acc[m][q][2] = 0.f; acc[m][q][3] = 0.f; }
#pragma unroll
        for (int kt = 0; kt < 4; ++kt) {
            s16x8 a[4];
#pragma unroll
            for (int m = 0; m < 4; ++m) {
                int row = m * 16 + l15;
                int abyte = (row * 256 + kt * 64 + kg * 16) ^ ((l15 & 7) << 4);
                a[m] = *(const s16x8*)((const char*)eas + abyte);
            }
#pragma unroll
            for (int q = 0; q < 2; ++q) {
                int col = w * 32 + q * 16 + l15;
                s16x8 b = *(const s16x8*)(Wep + ((size_t)((kt * 256 + col) * 4 + kg)) * 8);
#pragma unroll
                for (int m = 0; m < 4; ++m) acc[m][q] = mfma16(a[m], b, acc[m][q]);
            }
        }
        float bw = be[w * 32 + l15], bb = be[w * 32 + 16 + l15];
#pragma unroll
        for (int m = 0; m < 4; ++m)
#pragma unroll
            for (int i = 0; i < 4; ++i) {
                int row = m * 16 + kg * 4 + i;
                int p8 = __builtin_amdgcn_cvt_pk_fp8_f32(acc[m][0][i] + bw, acc[m][1][i] + bb, 0, 0);
                epts[row * EPS + w * 16 + l15] = (short)p8;
            }
    }
    __syncthreads();
    int4 wA, wB;
    {
        wA = *(const int4*)(epts + (size_t)r0 * EPS + ci * 8);
        wB = *(const int4*)(epts + (size_t)(r0 + 32) * EPS + ci * 8);
    }
    __syncthreads();   // all Ep reads done before ets overwrites the buffer
    {   // phase 3: elementwise; f32 Aw dot (AwT vector loads)
        int hh = ci >> 1, dbase = (ci & 1) * 8;
        const float4* awp = (const float4*)(AwT + hh * 16 + dbase);
        float4 aw0 = awp[0], aw1 = awp[1];
        float aw[8] = {aw0.x, aw0.y, aw0.z, aw0.w, aw1.x, aw1.y, aw1.z, aw1.w};
#pragma unroll
        for (int h = 0; h < 2; ++h) {
            int r = r0 + h * 32;
            int pos = h ? posB : posA;
            const unsigned short* kus = h ? kuB.us : kuA.us;
            const unsigned short* qus = h ? quB.us : quA.us;
            const int4 ww = h ? wB : wA;
            int words[4] = {ww.x, ww.y, ww.z, ww.w};
            float p = 0.f;
            float etv[8];
#pragma unroll
            for (int k = 0; k < 4; ++k) {
                float ew0 = __builtin_amdgcn_cvt_f32_fp8(words[k], 0);
                float eb0 = __builtin_amdgcn_cvt_f32_fp8(words[k], 1);
                float ew1 = __builtin_amdgcn_cvt_f32_fp8(words[k], 2);
                float eb1 = __builtin_amdgcn_cvt_f32_fp8(words[k], 3);
                float kq0 = b2f(kus[2 * k]) + b2f(qus[2 * k]);
                float kq1 = b2f(kus[2 * k + 1]) + b2f(qus[2 * k + 1]);
                float sv0 = kq0 * ew0, sv1 = kq1 * ew1;
                float et0 = fmaxf(copysignf(sqrtf(fabsf(sv0)), sv0) + eb0, 0.f);
                float et1 = fmaxf(copysignf(sqrtf(fabsf(sv1)), sv1) + eb1, 0.f);
                etv[2 * k] = et0; etv[2 * k + 1] = et1;
                p += et0 * aw[2 * k] + et1 * aw[2 * k + 1];
            }
            int lo = __builtin_amdgcn_cvt_pk_fp8_f32(etv[0], etv[1], 0, 0);
            lo = __builtin_amdgcn_cvt_pk_fp8_f32(etv[2], etv[3], lo, 1);
            int hi = __builtin_amdgcn_cvt_pk_fp8_f32(etv[4], etv[5], 0, 0);
            hi = __builtin_amdgcn_cvt_pk_fp8_f32(etv[6], etv[7], hi, 1);
            *(int2*)(e8 + (size_t)pos * 128 + ci * 8) = make_int2(lo, hi);
            int4 pkv;
            pkv.x = pk2(etv[0], etv[1]); pkv.y = pk2(etv[2], etv[3]);
            pkv.z = pk2(etv[4], etv[5]); pkv.w = pk2(etv[6], etv[7]);
            int byte = (r * 256 + ci * 16) ^ ((r & 7) << 4);
            *(int4*)((char*)epts + byte) = pkv;
            p += __shfl_xor(p, 1);
            if ((ci & 1) == 0) {
                float s = fminf(fmaxf(p, -CLAMPV), CLAMPV);
                sc[(size_t)pos * 8 + hh] = s;
            }
        }
    }
    __syncthreads();
    {   // phase 4: e_out = (ea + ets @ Woe + boe) * BNS
        f32x4 acc[4];
#pragma unroll
        for (int m = 0; m < 4; ++m) { acc[m][0] = 0.f; acc[m][1] = 0.f; acc[m][2] = 0.f; acc[m][3] = 0.f; }
        int col = w * 16 + l15;
#pragma unroll
        for (int kt = 0; kt < 4; ++kt) {
            s16x8 a[4];
#pragma unroll
            for (int m = 0; m < 4; ++m) {
                int row = m * 16 + l15;
                int abyte = (row * 256 + kt * 64 + kg * 16) ^ ((l15 & 7) << 4);
                a[m] = *(const s16x8*)((const char*)epts + abyte);
            }
            s16x8 b = *(const s16x8*)(Woep + ((size_t)((kt * 128 + col) * 4 + kg)) * 8);
#pragma unroll
            for (int m = 0; m < 4; ++m) acc[m] = mfma16(a[m], b, acc[m]);
        }
        float bb = boe[col];
#pragma unroll
        for (int m = 0; m < 4; ++m)
#pragma unroll
            for (int i = 0; i < 4; ++i) {
                int rr = m * 16 + kg * 4 + i;
                int rbyte = (rr * 256 + col * 2) ^ ((rr & 7) << 4);
                float res = b2f(*(const unsigned short*)((const char*)eas + rbyte));
                size_t idx = (size_t)(e0 + rr) * 128 + col;
                float v = (res + acc[m][i] + bb) * BNS;
                if (IN_F32) eout_b[idx] = bf16r(v);
                else        eout_f[idx] = v;
            }
    }
}

// Node attention: one 64-lane wave per node, single pass (sc pre-clamped -> no max needed).
__global__ __launch_bounds__(64) void k_nattn(const int* __restrict__ offs, const int* __restrict__ csr_src,
                                              const float* __restrict__ sc,
                                              const unsigned char* __restrict__ e8,
                                              const unsigned short* __restrict__ Vh,
                                              unsigned short* __restrict__ wVb,
                                              unsigned short* __restrict__ rowVb) {
    int n = blockIdx.x;
    int lane = threadIdx.x;
    int beg = offs[n], end = offs[n + 1];
    int hv = lane >> 3;                   // head of cols (2*lane, 2*lane+1)
    float dsum = 0.f, av0 = 0.f, av1 = 0.f, ar0 = 0.f, ar1 = 0.f;
    auto body = [&](int i) {
        float a = __expf(sc[(size_t)i * 8 + hv]);
        dsum += a;
        int s = csr_src[i];
        int v = ((const int*)Vh)[(size_t)s * 64 + lane];
        int u8 = ((const unsigned short*)e8)[(size_t)i * 64 + lane];
        av0 += b2f((unsigned short)v) * a;
        av1 += b2f((unsigned short)((unsigned)v >> 16)) * a;
        ar0 += __builtin_amdgcn_cvt_f32_fp8(u8, 0) * a;
        ar1 += __builtin_amdgcn_cvt_f32_fp8(u8, 1) * a;
    };
    int i = beg;
    for (; i + 4 <= end; i += 4) { body(i); body(i + 1); body(i + 2); body(i + 3); }
    for (; i < end; ++i) body(i);
    float inv = 1.f / (dsum + 1e-16f);
    ((int*)wVb)[(size_t)n * 64 + lane]   = pk2(av0 * inv, av1 * inv);
    ((int*)rowVb)[(size_t)n * 64 + lane] = pk2(ar0 * inv, ar1 * inv);
}

// Node post via MFMA: 32 nodes/block, 256 threads (4 waves), LDS 24 KB.
// p0 stages BOTH rowV (swz bufA) and wV (linear bufU) with int4 loads; p1 reads wV from LDS.
template<bool EMIT>
__global__ __launch_bounds__(256) void k_nodeB(
    const unsigned short* __restrict__ wVb, const unsigned short* __restrict__ rowVb,
    const short* __restrict__ VRp, const float* __restrict__ dc,
    const float* __restrict__ logdeg, const float* __restrict__ x,
    const short* __restrict__ Wohp, const float* __restrict__ boh,
    const short* __restrict__ W1p, const float* __restrict__ b1,
    const short* __restrict__ W2p, const float* __restrict__ b2,
    float* __restrict__ xout,
    const short* __restrict__ Wqp2, const float* __restrict__ bq2,
    const short* __restrict__ Wkp2, const short* __restrict__ Wvp2,
    unsigned short* __restrict__ Qh2, unsigned short* __restrict__ Kh2,
    unsigned short* __restrict__ Vh2) {
    __shared__ short bufA[32 * 128];   // rowV staging / h1 / out (8 KB)
    __shared__ short bufU[32 * 256];   // wV linear / hs / us (16 KB)
    int n0 = blockIdx.x * 32;
    int t = threadIdx.x;
    int ci = t & 15, r0 = t >> 4;      // r0 in 0..15
    {   // p0: stage rowV (swz) + wV (linear) via int4 loads
#pragma unroll
        for (int h = 0; h < 2; ++h) {
            int rr = r0 + h * 16, n = n0 + rr;
            int4 pr = make_int4(0, 0, 0, 0), pw = make_int4(0, 0, 0, 0);
            if (n < NN) {
                pr = *(const int4*)(rowVb + (size_t)n * 128 + ci * 8);
                pw = *(const int4*)(wVb + (size_t)n * 128 + ci * 8);
            }
            int byte = (rr * 256 + ci * 16) ^ ((rr & 7) << 4);
            *(int4*)((char*)bufA + byte) = pr;
            *(int4*)(bufU + rr * 128 + ci * 8) = pw;
        }
    }
    __syncthreads();
    int lane = t & 63, w = t >> 6;     // w in 0..3
    int l15 = lane & 15, kg = lane >> 4;
    int cq[2] = {w * 32 + l15, w * 32 + 16 + l15};
    {   // p1: hs = (wV + rowV@VeRowBD) * degscale -> bufU (after internal barrier)
        float ldv[2][4];
#pragma unroll
        for (int m = 0; m < 2; ++m)
#pragma unroll
            for (int i = 0; i < 4; ++i) {
                int n = n0 + m * 16 + kg * 4 + i;
                ldv[m][i] = (n < NN) ? logdeg[n] : 0.f;
            }
        f32x4 acc[2][2];
#pragma unroll
        for (int m = 0; m < 2; ++m)
#pragma unroll
            for (int q = 0; q < 2; ++q)
#pragma unroll
                for (int i = 0; i < 4; ++i) {
                    int rr = m * 16 + kg * 4 + i;
                    acc[m][q][i] = b2f(*(const unsigned short*)(bufU + rr * 128 + cq[q]));
                }
#pragma unroll
        for (int kt = 0; kt < 4; ++kt) {
            s16x8 a[2];
#pragma unroll
            for (int m = 0; m < 2; ++m) {
                int row = m * 16 + l15;
                int abyte = (row * 256 + kt * 64 + kg * 16) ^ ((l15 & 7) << 4);
                a[m] = *(const s16x8*)((const char*)bufA + abyte);
            }
#pragma unroll
            for (int q = 0; q < 2; ++q) {
                s16x8 b = *(const s16x8*)(VRp + ((size_t)((kt * 128 + cq[q]) * 4 + kg)) * 8);
#pragma unroll
                for (int m = 0; m < 2; ++m) acc[m][q] = mfma16(a[m], b, acc[m][q]);
            }
        }
        __syncthreads();   // all wV LDS reads complete before hs overwrites bufU
#pragma unroll
        for (int q = 0; q < 2; ++q) {
            float d0 = dc[cq[q] * 2], d1 = dc[cq[q] * 2 + 1];
#pragma unroll
            for (int m = 0; m < 2; ++m)
#pragma unroll
                for (int i = 0; i < 4; ++i) {
                    int rr = m * 16 + kg * 4 + i;
                    float hs = acc[m][q][i] * (d0 + ldv[m][i] * d1);
                    int byte = (rr * 256 + cq[q] * 2) ^ ((rr & 7) << 4);
                    *(unsigned short*)((char*)bufU + byte) = bf16r(hs);
                }
        }
    }
    __syncthreads();
    float h1r[2][2][4];
    {   // p2: h1 = (x + hs@Woh + boh)*BNS -> bufA + regs; x loads hoisted to phase start
        float xv[2][2][4];
#pragma unroll
        for (int m = 0; m < 2; ++m)
#pragma unroll
            for (int q = 0; q < 2; ++q)
#pragma unroll
                for (int i = 0; i < 4; ++i) {
                    int n = n0 + m * 16 + kg * 4 + i;
                    xv[m][q][i] = (n < NN) ? x[(size_t)n * 128 + cq[q]] : 0.f;
                }
        f32x4 acc[2][2];
#pragma unroll
        for (int m = 0; m < 2; ++m)
#pragma unroll
            for (int q = 0; q < 2; ++q) { acc[m][q][0] = 0.f; acc[m][q][1] = 0.f; acc[m][q][2] = 0.f; acc[m][q][3] = 0.f; }
#pragma unroll
        for (int kt = 0; kt < 4; ++kt) {
            s16x8 a[2];
#pragma unroll
            for (int m = 0; m < 2; ++m) {
                int row = m * 16 + l15;
                int abyte = (row * 256 + kt * 64 + kg * 16) ^ ((l15 & 7) << 4);
                a[m] = *(const s16x8*)((const char*)bufU + abyte);
            }
#pragma unroll
            for (int q = 0; q < 2; ++q) {
                s16x8 b = *(const s16x8*)(Wohp + ((size_t)((kt * 128 + cq[q]) * 4 + kg)) * 8);
#pragma unroll
                for (int m = 0; m < 2; ++m) acc[m][q] = mfma16(a[m], b, acc[m][q]);
            }
        }
#pragma unroll
        for (int q = 0; q < 2; ++q) {
            float bb = boh[cq[q]];
#pragma unroll
            for (int m = 0; m < 2; ++m)
#pragma unroll
                for (int i = 0; i < 4; ++i) {
                    int rr = m * 16 + kg * 4 + i;
                    float h1 = (xv[m][q][i] + acc[m][q][i] + bb) * BNS;
                    h1r[m][q][i] = h1;
                    int byte = (rr * 256 + cq[q] * 2) ^ ((rr & 7) << 4);
                    *(unsigned short*)((char*)bufA + byte) = bf16r(h1);
                }
        }
    }
    __syncthreads();
    {   // p3: us = relu(h1@W1 + b1) -> bufU
        f32x4 acc[2][4];
#pragma unroll
        for (int m = 0; m < 2; ++m)
#pragma unroll
            for (int q = 0; q < 4; ++q) { acc[m][q][0] = 0.f; acc[m][q][1] = 0.f; acc[m][q][2] = 0.f; acc[m][q][3] = 0.f; }
#pragma unroll
        for (int kt = 0; kt < 4; ++kt) {
            s16x8 a[2];
#pragma unroll
            for (int m = 0; m < 2; ++m) {
                int row = m * 16 + l15;
                int abyte = (row * 256 + kt * 64 + kg * 16) ^ ((l15 & 7) << 4);
                a[m] = *(const s16x8*)((const char*)bufA + abyte);
            }
#pragma unroll
            for (int q = 0; q < 4; ++q) {
                int colq = w * 64 + q * 16 + l15;
                s16x8 b = *(const s16x8*)(W1p + ((size_t)((kt * 256 + colq) * 4 + kg)) * 8);
#pragma unroll
                for (int m = 0; m < 2; ++m) acc[m][q] = mfma16(a[m], b, acc[m][q]);
            }
        }
        __syncthreads();   // hs reads (p2) complete before us overwrites bufU
#pragma unroll
        for (int q = 0; q < 4; ++q) {
            int colq = w * 64 + q * 16 + l15;
            float bb = b1[colq];
#pragma unroll
            for (int m = 0; m < 2; ++m)
#pragma unroll
                for (int i = 0; i < 4; ++i) {
                    int rr = m * 16 + kg * 4 + i;
                    float us = fmaxf(acc[m][q][i] + bb, 0.f);
                    int byte = (rr * 512 + colq * 2) ^ ((rr & 7) << 4);
                    *(unsigned short*)((char*)bufU + byte) = bf16r(us);
                }
        }
    }
    __syncthreads();
    {   // p4: out = (h1 + us@W2 + b2)*BNS; EMIT: stage out bf16 into bufA
        f32x4 acc[2][2];
#pragma unroll
        for (int m = 0; m < 2; ++m)
#pragma unroll
            for (int q = 0; q < 2; ++q) { acc[m][q][0] = 0.f; acc[m][q][1] = 0.f; acc[m][q][2] = 0.f; acc[m][q][3] = 0.f; }
#pragma unroll
        for (int kt = 0; kt < 8; ++kt) {
            s16x8 a[2];
#pragma unroll
            for (int m = 0; m < 2; ++m) {
                int row = m * 16 + l15;
                int abyte = (row * 512 + kt * 64 + kg * 16) ^ ((l15 & 7) << 4);
                a[m] = *(const s16x8*)((const char*)bufU + abyte);
            }
#pragma unroll
            for (int q = 0; q < 2; ++q) {
                s16x8 b = *(const s16x8*)(W2p + ((size_t)((kt * 128 + cq[q]) * 4 + kg)) * 8);
#pragma unroll
                for (int m = 0; m < 2; ++m) acc[m][q] = mfma16(a[m], b, acc[m][q]);
            }
        }
#pragma unroll
        for (int q = 0; q < 2; ++q) {
            float bb = b2[cq[q]];
#pragma unroll
            for (int m = 0; m < 2; ++m)
#pragma unroll
                for (int i = 0; i < 4; ++i) {
                    int rr = m * 16 + kg * 4 + i, n = n0 + rr;
                    float outv = (h1r[m][q][i] + acc[m][q][i] + bb) * BNS;
                    if (n < NN) xout[(size_t)n * 128 + cq[q]] = outv;
                    if (EMIT) {
                        int byte = (rr * 256 + cq[q] * 2) ^ ((rr & 7) << 4);
                        *(unsigned short*)((char*)bufA + byte) = bf16r(outv);
                    }
                }
        }
    }
    if (EMIT) {   // next-layer Q/K/V from staged out
        __syncthreads();
        f32x4 acc[2][2][3];
#pragma unroll
        for (int m = 0; m < 2; ++m)
#pragma unroll
            for (int q = 0; q < 2; ++q)
#pragma unroll
                for (int o = 0; o < 3; ++o) { acc[m][q][o][0] = 0.f; acc[m][q][o][1] = 0.f; acc[m][q][o][2] = 0.f; acc[m][q][o][3] = 0.f; }
#pragma unroll
        for (int kt = 0; kt < 4; ++kt) {
            s16x8 a[2];
#pragma unroll
            for (int m = 0; m < 2; ++m) {
                int row = m * 16 + l15;
                int abyte = (row * 256 + kt * 64 + kg * 16) ^ ((l15 & 7) << 4);
                a[m] = *(const s16x8*)((const char*)bufA + abyte);
            }
#pragma unroll
            for (int q = 0; q < 2; ++q) {
                size_t bo = ((size_t)((kt * 128 + cq[q]) * 4 + kg)) * 8;
                s16x8 bqf = *(const s16x8*)(Wqp2 + bo);
                s16x8 bkf = *(const s16x8*)(Wkp2 + bo);
                s16x8 bvf = *(const s16x8*)(Wvp2 + bo);
#pragma unroll
                for (int m = 0; m < 2; ++m) {
                    acc[m][q][0] = mfma16(a[m], bqf, acc[m][q][0]);
                    acc[m][q][1] = mfma16(a[m], bkf, acc[m][q][1]);
                    acc[m][q][2] = mfma16(a[m], bvf, acc[m][q][2]);
                }
            }
        }
#pragma unroll
        for (int q = 0; q < 2; ++q) {
            float bqv = bq2[cq[q]];
#pragma unroll
            for (int m = 0; m < 2; ++m)
#pragma unroll
                for (int i = 0; i < 4; ++i) {
                    int n = n0 + m * 16 + kg * 4 + i;
                    if (n < NN) {
                        Qh2[(size_t)n * 128 + cq[q]] = bf16r(acc[m][q][0][i] + bqv);
                        Kh2[(size_t)n * 128 + cq[q]] = bf16r(acc[m][q][1][i]);
                        Vh2[(size_t)n * 128 + cq[q]] = bf16r(acc[m][q][2][i]);
                    }
                }
        }
    }
}

// ---------------- host launch ----------------

extern "C" void kernel_launch(void* const* d_in, const int* in_sizes, int n_in,
                              void* d_out, int out_size, void* d_ws, size_t ws_size,
                              hipStream_t stream) {
    (void)in_sizes; (void)n_in; (void)out_size; (void)ws_size;
    const float* x_in0  = (const float*)d_in[0];
    const int*   ei     = (const int*)d_in[1];
    const float* ea_in0 = (const float*)d_in[2];
    const float* Wq = (const float*)d_in[3];
    const float* bq = (const float*)d_in[4];
    const float* Wk = (const float*)d_in[5];
    const float* Wv = (const float*)d_in[6];
    const float* We = (const float*)d_in[7];
    const float* be = (const float*)d_in[8];
    const float* Aw = (const float*)d_in[9];
    const float* VeRow = (const float*)d_in[10];
    const float* Woh = (const float*)d_in[11];
    const float* boh = (const float*)d_in[12];
    const float* Woe = (const float*)d_in[13];
    const float* boe = (const float*)d_in[14];
    const float* dc  = (const float*)d_in[15];
    const float* W1 = (const float*)d_in[16];
    const float* b1 = (const float*)d_in[17];
    const float* W2 = (const float*)d_in[18];
    const float* b2 = (const float*)d_in[19];

    char* ws = (char*)d_ws;
    size_t off = 0;
    auto alloc = [&](size_t bytes) { void* p = ws + off; off = (off + bytes + 255) & ~(size_t)255; return p; };
    int*   deg    = (int*)alloc((size_t)NN * 4);
    int*   cursor = (int*)alloc((size_t)NN * 4);
    int*   offs   = (int*)alloc((size_t)(NN + 1) * 4);
    int*   bsum   = (int*)alloc((size_t)64 * 4);
    int*   csr_src= (int*)alloc((size_t)NE * 4);
    int*   epos   = (int*)alloc((size_t)NE * 4);
    float* logdeg = (float*)alloc((size_t)NN * 4);
    float* AwT    = (float*)alloc((size_t)2 * 128 * 4);
    unsigned short* Qh  = (unsigned short*)alloc((size_t)NN * 128 * 2);
    unsigned short* Kh  = (unsigned short*)alloc((size_t)NN * 128 * 2);
    unsigned short* Vh  = (unsigned short*)alloc((size_t)NN * 128 * 2);
    unsigned short* Qh2 = (unsigned short*)alloc((size_t)NN * 128 * 2);
    unsigned short* Kh2 = (unsigned short*)alloc((size_t)NN * 128 * 2);
    unsigned short* Vh2 = (unsigned short*)alloc((size_t)NN * 128 * 2);
    unsigned char* e8   = (unsigned char*)alloc((size_t)NE * 128);
    unsigned short* ea_bf = (unsigned short*)alloc((size_t)NE * 128 * 2);
    float* sc     = (float*)alloc((size_t)NE * 8 * 4);
    unsigned short* wVb   = (unsigned short*)alloc((size_t)NN * 128 * 2);
    unsigned short* rowVb = (unsigned short*)alloc((size_t)NN * 128 * 2);
    short* Wep    = (short*)alloc((size_t)2 * 128 * 256 * 2);
    short* Woep   = (short*)alloc((size_t)2 * 128 * 128 * 2);
    short* Wqp    = (short*)alloc((size_t)2 * 128 * 128 * 2);
    short* Wkp    = (short*)alloc((size_t)2 * 128 * 128 * 2);
    short* Wvp    = (short*)alloc((size_t)2 * 128 * 128 * 2);
    short* Wohp   = (short*)alloc((size_t)2 * 128 * 128 * 2);
    short* W1p    = (short*)alloc((size_t)2 * 128 * 256 * 2);
    short* W2p    = (short*)alloc((size_t)2 * 256 * 128 * 2);
    short* VRp    = (short*)alloc((size_t)2 * 128 * 128 * 2);

    float* out_x = (float*)d_out;
    float* out_e = out_x + (size_t)NN * 128;

    hipError_t err;
    err = hipMemsetAsync(deg, 0, (size_t)NN * 4, stream); (void)err;
    err = hipMemsetAsync(cursor, 0, (size_t)NN * 4, stream); (void)err;

    k_deg<<<(NE + 255) / 256, 256, 0, stream>>>(ei, deg);
    k_scan1<<<NBLK, 1024, 0, stream>>>(deg, offs, bsum, logdeg);
    k_scan3<<<NBLK, 1024, 0, stream>>>(offs, bsum);
    k_fill<<<(NE + 255) / 256, 256, 0, stream>>>(ei, offs, cursor, csr_src, epos);
    k_awt<<<1, 256, 0, stream>>>(Aw, AwT);
    k_packAll<<<1536, 256, 0, stream>>>(We, Woe, Wq, Wk, Wv, Woh, W1, W2, VeRow,
                                        Wep, Woep, Wqp, Wkp, Wvp, Wohp, W1p, W2p, VRp);

    // ---- layer 0 ----
    k_qkv<<<(NN + 63) / 64, 512, 0, stream>>>(x_in0, Wqp, bq, Wkp, Wvp, Qh, Kh, Vh);
    k_edgeA<true><<<NE / 64, 512, 0, stream>>>(ea_in0, ei, epos, Wep, be, AwT, Qh, Kh,
                                               e8, sc, Woep, boe, ea_bf);
    k_nattn<<<NN, 64, 0, stream>>>(offs, csr_src, sc, e8, Vh, wVb, rowVb);
    k_nodeB<true><<<(NN + 31) / 32, 256, 0, stream>>>(
        wVb, rowVb, VRp, dc, logdeg, x_in0,
        Wohp, boh, W1p, b1, W2p, b2, out_x,
        Wqp + 128 * 128, bq + 128, Wkp + 128 * 128, Wvp + 128 * 128, Qh2, Kh2, Vh2);

    // ---- layer 1 ----
    k_edgeA<false><<<NE / 64, 512, 0, stream>>>(ea_bf, ei, epos, Wep + 128 * 256, be + 256,
                                                AwT + 128, Qh2, Kh2, e8, sc,
                                                Woep + 128 * 128, boe + 128, out_e);
    k_nattn<<<NN, 64, 0, stream>>>(offs, csr_src, sc, e8, Vh2, wVb, rowVb);
    k_nodeB<false><<<(NN + 31) / 32, 256, 0, stream>>>(
        wVb, rowVb, VRp + 128 * 128, dc + 256, logdeg, out_x,
        Wohp + 128 * 128, boh + 128, W1p + 128 * 256, b1 + 256, W2p + 256 * 128, b2 + 128, out_x,
        nullptr, nullptr, nullptr, nullptr, nullptr, nullptr, nullptr);
}

// Round 18
// 841.590 us; speedup vs baseline: 1.9760x; 1.0380x over previous
//
#include <hip/hip_runtime.h>

#define NN 50000
#define NE 800000
#define CLAMPV 5.0f
#define BNS 0.9999950000374997f
#define EPS 136    // ushort stride of fp8 Ep rows (272B, 16B-aligned)
#define NBLK 49    // ceil(NN/1024)

typedef __attribute__((ext_vector_type(8))) short s16x8;
typedef __attribute__((ext_vector_type(8))) __bf16 bf16x8;
typedef __attribute__((ext_vector_type(4))) float f32x4;

__device__ inline f32x4 mfma16(s16x8 a, s16x8 b, f32x4 c) {
    return __builtin_amdgcn_mfma_f32_16x16x32_bf16(
        __builtin_bit_cast(bf16x8, a), __builtin_bit_cast(bf16x8, b), c, 0, 0, 0);
}

__device__ inline unsigned short bf16r(float f) {
    return __builtin_bit_cast(unsigned short, (__bf16)f);
}

__device__ inline int pk2(float a, float b) {
    return (int)(unsigned)bf16r(a) | ((int)(unsigned)bf16r(b) << 16);
}

__device__ inline float b2f(unsigned short u) {
    return __builtin_bit_cast(float, (unsigned)u << 16);
}

// ---------------- degree / CSR build ----------------

__global__ __launch_bounds__(256) void k_deg(const int* __restrict__ ei, int* __restrict__ deg) {
    int e = blockIdx.x * 256 + threadIdx.x;
    if (e < NE) atomicAdd(&deg[ei[NE + e]], 1);
}

__global__ __launch_bounds__(1024) void k_scan1(const int* __restrict__ deg, int* __restrict__ offs,
                                                int* __restrict__ bsum, float* __restrict__ logdeg) {
    __shared__ int sm[1024];
    int i = blockIdx.x * 1024 + threadIdx.x;
    int v = (i < NN) ? deg[i] : 0;
    if (i < NN) logdeg[i] = logf((float)v + 1.0f);
    sm[threadIdx.x] = v;
    __syncthreads();
    for (int s = 1; s < 1024; s <<= 1) {
        int t = (threadIdx.x >= s) ? sm[threadIdx.x - s] : 0;
        __syncthreads();
        sm[threadIdx.x] += t;
        __syncthreads();
    }
    if (i < NN) offs[i + 1] = sm[threadIdx.x];
    if (threadIdx.x == 1023) bsum[blockIdx.x] = sm[1023];
    if (blockIdx.x == 0 && threadIdx.x == 0) offs[0] = 0;
}

__global__ __launch_bounds__(1024) void k_scan3(int* __restrict__ offs, const int* __restrict__ bsum) {
    __shared__ int pre;
    if (threadIdx.x == 0) {
        int acc = 0;
        for (int i = 0; i < (int)blockIdx.x; ++i) acc += bsum[i];
        pre = acc;
    }
    __syncthreads();
    int i = blockIdx.x * 1024 + threadIdx.x;
    if (i < NN) offs[i + 1] += pre;
}

__global__ __launch_bounds__(256) void k_fill(const int* __restrict__ ei, const int* __restrict__ offs,
                                              int* __restrict__ cursor, int* __restrict__ csr_src,
                                              int* __restrict__ epos) {
    int e = blockIdx.x * 256 + threadIdx.x;
    if (e < NE) {
        int d = ei[NE + e];
        int pos = offs[d] + atomicAdd(&cursor[d], 1);
        csr_src[pos] = ei[e];
        epos[e] = pos;
    }
}

// Transpose Aw (D=16,H=8) -> AwT[h][d] for both layers (vector-loadable by head).
__global__ void k_awt(const float* __restrict__ Aw, float* __restrict__ AwT) {
    int i = threadIdx.x;   // 256 threads = 2*128
    if (i < 256) {
        int l = i >> 7, q = i & 127;
        int h = q >> 4, d = q & 15;
        AwT[l * 128 + h * 16 + d] = Aw[l * 128 + d * 8 + h];
    }
}

// One launch packs ALL weights (both layers) into MFMA B-fragment order.
#define PL_A (128*256)
#define PL_B (128*128)
__global__ __launch_bounds__(256) void k_packAll(
    const float* __restrict__ We,  const float* __restrict__ Woe, const float* __restrict__ Wq,
    const float* __restrict__ Wk,  const float* __restrict__ Wv,  const float* __restrict__ Woh,
    const float* __restrict__ W1,  const float* __restrict__ W2,  const float* __restrict__ VR,
    short* __restrict__ Wep,  short* __restrict__ Woep, short* __restrict__ Wqp,
    short* __restrict__ Wkp,  short* __restrict__ Wvp,  short* __restrict__ Wohp,
    short* __restrict__ W1p,  short* __restrict__ W2p,  short* __restrict__ VRp) {
    int s = blockIdx.x * 256 + threadIdx.x;
    const float* W; short* out; int ncol, perL; bool vr = false;
    if (s < 2 * PL_A) { W = We; out = Wep; ncol = 256; perL = PL_A; }
    else if ((s -= 2 * PL_A) < 2 * PL_B) { W = Woe; out = Woep; ncol = 128; perL = PL_B; }
    else if ((s -= 2 * PL_B) < 2 * PL_B) { W = Wq;  out = Wqp;  ncol = 128; perL = PL_B; }
    else if ((s -= 2 * PL_B) < 2 * PL_B) { W = Wk;  out = Wkp;  ncol = 128; perL = PL_B; }
    else if ((s -= 2 * PL_B) < 2 * PL_B) { W = Wv;  out = Wvp;  ncol = 128; perL = PL_B; }
    else if ((s -= 2 * PL_B) < 2 * PL_B) { W = Woh; out = Wohp; ncol = 128; perL = PL_B; }
    else if ((s -= 2 * PL_B) < 2 * PL_A) { W = W1;  out = W1p;  ncol = 256; perL = PL_A; }
    else if ((s -= 2 * PL_A) < 2 * PL_A) { W = W2;  out = W2p;  ncol = 128; perL = PL_A; }
    else if ((s -= 2 * PL_A) < 2 * PL_B) { W = VR;  out = VRp;  ncol = 128; perL = PL_B; vr = true; }
    else return;
    int l = s / perL, q = s % perL;
    int j = q & 7; int t2 = q >> 3; int kg = t2 & 3; t2 >>= 2;
    int col = t2 % ncol; int kt = t2 / ncol;
    int k = kt * 32 + kg * 8 + j;
    float v;
    if (vr) v = ((k >> 4) == (col >> 4)) ? VR[l * 2048 + (k & 15) * 128 + col] : 0.f;
    else    v = W[(size_t)l * perL + k * ncol + col];
    out[(size_t)l * perL + q] = (short)bf16r(v);
}

// ---------------- per-layer kernels ----------------

// Q/K/V via MFMA: 64 nodes/block, 512 threads (8 waves). Layer 0 only.
__global__ __launch_bounds__(512) void k_qkv(const float* __restrict__ x,
                                             const short* __restrict__ Wqp, const float* __restrict__ bq,
                                             const short* __restrict__ Wkp, const short* __restrict__ Wvp,
                                             unsigned short* __restrict__ Qh, unsigned short* __restrict__ Kh,
                                             unsigned short* __restrict__ Vh) {
    __shared__ short xsw[64 * 128];
    int t = threadIdx.x;
    int ci = t & 15, r0 = t >> 4;
    int n0 = blockIdx.x * 64;
    for (int rr = r0; rr < 64; rr += 32) {
        int n = n0 + rr;
        int4 pkv = make_int4(0, 0, 0, 0);
        if (n < NN) {
            const float4* src = (const float4*)(x + (size_t)n * 128 + ci * 8);
            float4 v0 = src[0], v1 = src[1];
            pkv.x = pk2(v0.x, v0.y); pkv.y = pk2(v0.z, v0.w);
            pkv.z = pk2(v1.x, v1.y); pkv.w = pk2(v1.z, v1.w);
        }
        int byte = (rr * 256 + ci * 16) ^ ((rr & 7) << 4);
        *(int4*)((char*)xsw + byte) = pkv;
    }
    __syncthreads();
    int lane = t & 63, w = t >> 6;
    int l15 = lane & 15, kg = lane >> 4;
    f32x4 acc[4][3];
#pragma unroll
    for (int m = 0; m < 4; ++m)
#pragma unroll
        for (int q = 0; q < 3; ++q) { acc[m][q][0] = 0.f; acc[m][q][1] = 0.f; acc[m][q][2] = 0.f; acc[m][q][3] = 0.f; }
    int col = w * 16 + l15;
#pragma unroll
    for (int kt = 0; kt < 4; ++kt) {
        s16x8 a[4];
#pragma unroll
        for (int m = 0; m < 4; ++m) {
            int row = m * 16 + l15;
            int abyte = (row * 256 + kt * 64 + kg * 16) ^ ((l15 & 7) << 4);
            a[m] = *(const s16x8*)((const char*)xsw + abyte);
        }
        size_t bo = ((size_t)((kt * 128 + col) * 4 + kg)) * 8;
        s16x8 bqf = *(const s16x8*)(Wqp + bo);
        s16x8 bkf = *(const s16x8*)(Wkp + bo);
        s16x8 bvf = *(const s16x8*)(Wvp + bo);
#pragma unroll
        for (int m = 0; m < 4; ++m) {
            acc[m][0] = mfma16(a[m], bqf, acc[m][0]);
            acc[m][1] = mfma16(a[m], bkf, acc[m][1]);
            acc[m][2] = mfma16(a[m], bvf, acc[m][2]);
        }
    }
    float bqv = bq[col];
#pragma unroll
    for (int m = 0; m < 4; ++m)
#pragma unroll
        for (int i = 0; i < 4; ++i) {
            int n = n0 + m * 16 + kg * 4 + i;
            if (n < NN) {
                Qh[(size_t)n * 128 + col] = bf16r(acc[m][0][i] + bqv);
                Kh[(size_t)n * 128 + col] = bf16r(acc[m][1][i]);
                Vh[(size_t)n * 128 + col] = bf16r(acc[m][2][i]);
            }
        }
}

// Fused edge kernel: 64 edges/block, 512 threads (8 waves).
// K/Q gathers issued right AFTER the phase-1 barrier (R16 placement — vmcnt in-order
// semantics make an earlier hoist serialize the phase-1 waits).
template<bool IN_F32>
__global__ __launch_bounds__(512) void k_edgeA(const void* __restrict__ ea_, const int* __restrict__ ei,
                                               const int* __restrict__ epos,
                                               const short* __restrict__ Wep, const float* __restrict__ be,
                                               const float* __restrict__ AwT,
                                               const unsigned short* __restrict__ Qh,
                                               const unsigned short* __restrict__ Kh,
                                               unsigned char* __restrict__ e8, float* __restrict__ sc,
                                               const short* __restrict__ Woep, const float* __restrict__ boe,
                                               void* __restrict__ eout_) {
    __shared__ short eas[64 * 128];     // bf16 ea tile, XOR-swizzled (16 KB)
    __shared__ short epts[64 * EPS];    // fp8 (E_w,E_b) pairs, then bf16 ets tile (17.4 KB)
    __shared__ int eposs[64];
    const float* eaf = (const float*)ea_;
    const unsigned short* eab = (const unsigned short*)ea_;
    unsigned short* eout_b = (unsigned short*)eout_;
    float* eout_f = (float*)eout_;

    int e0 = blockIdx.x * 64;
    int t = threadIdx.x;
    int ci = t & 15, r0 = t >> 4;
    int eA = e0 + r0, eB = eA + 32;
    int siA = ei[eA], diA = ei[NE + eA];
    int siB = ei[eB], diB = ei[NE + eB];

    if (t < 64) eposs[t] = epos[e0 + t];
    {   // phase 1: stage ea -> bf16 swizzled
#pragma unroll
        for (int h = 0; h < 2; ++h) {
            int rr = r0 + h * 32;
            int4 pkv;
            if (IN_F32) {
                const float4* src = (const float4*)(eaf + (size_t)(e0 + rr) * 128 + ci * 8);
                float4 v0 = src[0], v1 = src[1];
                pkv.x = pk2(v0.x, v0.y); pkv.y = pk2(v0.z, v0.w);
                pkv.z = pk2(v1.x, v1.y); pkv.w = pk2(v1.z, v1.w);
            } else {
                pkv = *(const int4*)(eab + (size_t)(e0 + rr) * 128 + ci * 8);
            }
            int byte = (rr * 256 + ci * 16) ^ ((rr & 7) << 4);
            *(int4*)((char*)eas + byte) = pkv;
        }
    }
    __syncthreads();
    // K/Q gathers issued now — fly under phase-2 MFMAs, consumed in phase 3
    union { int4 v; unsigned short us[8]; } kuA, quA, kuB, quB;
    kuA.v = *(const int4*)(Kh + (size_t)siA * 128 + ci * 8);
    quA.v = *(const int4*)(Qh + (size_t)diA * 128 + ci * 8);
    kuB.v = *(const int4*)(Kh + (size_t)siB * 128 + ci * 8);
    quB.v = *(const int4*)(Qh + (size_t)diB * 128 + ci * 8);
    int posA = eposs[r0], posB = eposs[r0 + 32];

    int lane = t & 63, w = t >> 6;
    int l15 = lane & 15, kg = lane >> 4;
    {   // phase 2: Ep = eas @ We + be -> fp8 pairs in LDS
        f32x4 acc[4][2];
#pragma unroll
        for (int m = 0; m < 4; ++m)
#pragma unroll
            for (int q = 0; q < 2; ++q) { acc[m][q][0] = 0.f; acc[m][q][1] = 0.f; acc[m][q][2] = 0.f; acc[m][q][3] = 0.f; }
#pragma unroll
        for (int kt = 0; kt < 4; ++kt) {
            s16x8 a[4];
#pragma unroll
            for (int m = 0; m < 4; ++m) {
                int row = m * 16 + l15;
                int abyte = (row * 256 + kt * 64 + kg * 16) ^ ((l15 & 7) << 4);
                a[m] = *(const s16x8*)((const char*)eas + abyte);
            }
#pragma unroll
            for (int q = 0; q < 2; ++q) {
                int col = w * 32 + q * 16 + l15;
                s16x8 b = *(const s16x8*)(Wep + ((size_t)((kt * 256 + col) * 4 + kg)) * 8);
#pragma unroll
                for (int m = 0; m < 4; ++m) acc[m][q] = mfma16(a[m], b, acc[m][q]);
            }
        }
        float bw = be[w * 32 + l15], bb = be[w * 32 + 16 + l15];
#pragma unroll
        for (int m = 0; m < 4; ++m)
#pragma unroll
            for (int i = 0; i < 4; ++i) {
                int row = m * 16 + kg * 4 + i;
                int p8 = __builtin_amdgcn_cvt_pk_fp8_f32(acc[m][0][i] + bw, acc[m][1][i] + bb, 0, 0);
                epts[row * EPS + w * 16 + l15] = (short)p8;
            }
    }
    __syncthreads();
    int4 wA, wB;
    {
        wA = *(const int4*)(epts + (size_t)r0 * EPS + ci * 8);
        wB = *(const int4*)(epts + (size_t)(r0 + 32) * EPS + ci * 8);
    }
    __syncthreads();   // all Ep reads done before ets overwrites the buffer
    {   // phase 3: elementwise; f32 Aw dot (AwT vector loads)
        int hh = ci >> 1, dbase = (ci & 1) * 8;
        const float4* awp = (const float4*)(AwT + hh * 16 + dbase);
        float4 aw0 = awp[0], aw1 = awp[1];
        float aw[8] = {aw0.x, aw0.y, aw0.z, aw0.w, aw1.x, aw1.y, aw1.z, aw1.w};
#pragma unroll
        for (int h = 0; h < 2; ++h) {
            int r = r0 + h * 32;
            int pos = h ? posB : posA;
            const unsigned short* kus = h ? kuB.us : kuA.us;
            const unsigned short* qus = h ? quB.us : quA.us;
            const int4 ww = h ? wB : wA;
            int words[4] = {ww.x, ww.y, ww.z, ww.w};
            float p = 0.f;
            float etv[8];
#pragma unroll
            for (int k = 0; k < 4; ++k) {
                float ew0 = __builtin_amdgcn_cvt_f32_fp8(words[k], 0);
                float eb0 = __builtin_amdgcn_cvt_f32_fp8(words[k], 1);
                float ew1 = __builtin_amdgcn_cvt_f32_fp8(words[k], 2);
                float eb1 = __builtin_amdgcn_cvt_f32_fp8(words[k], 3);
                float kq0 = b2f(kus[2 * k]) + b2f(qus[2 * k]);
                float kq1 = b2f(kus[2 * k + 1]) + b2f(qus[2 * k + 1]);
                float sv0 = kq0 * ew0, sv1 = kq1 * ew1;
                float et0 = fmaxf(copysignf(sqrtf(fabsf(sv0)), sv0) + eb0, 0.f);
                float et1 = fmaxf(copysignf(sqrtf(fabsf(sv1)), sv1) + eb1, 0.f);
                etv[2 * k] = et0; etv[2 * k + 1] = et1;
                p += et0 * aw[2 * k] + et1 * aw[2 * k + 1];
            }
            int lo = __builtin_amdgcn_cvt_pk_fp8_f32(etv[0], etv[1], 0, 0);
            lo = __builtin_amdgcn_cvt_pk_fp8_f32(etv[2], etv[3], lo, 1);
            int hi = __builtin_amdgcn_cvt_pk_fp8_f32(etv[4], etv[5], 0, 0);
            hi = __builtin_amdgcn_cvt_pk_fp8_f32(etv[6], etv[7], hi, 1);
            *(int2*)(e8 + (size_t)pos * 128 + ci * 8) = make_int2(lo, hi);
            int4 pkv;
            pkv.x = pk2(etv[0], etv[1]); pkv.y = pk2(etv[2], etv[3]);
            pkv.z = pk2(etv[4], etv[5]); pkv.w = pk2(etv[6], etv[7]);
            int byte = (r * 256 + ci * 16) ^ ((r & 7) << 4);
            *(int4*)((char*)epts + byte) = pkv;
            p += __shfl_xor(p, 1);
            if ((ci & 1) == 0) {
                float s = fminf(fmaxf(p, -CLAMPV), CLAMPV);
                sc[(size_t)pos * 8 + hh] = s;
            }
        }
    }
    __syncthreads();
    {   // phase 4: e_out = (ea + ets @ Woe + boe) * BNS
        f32x4 acc[4];
#pragma unroll
        for (int m = 0; m < 4; ++m) { acc[m][0] = 0.f; acc[m][1] = 0.f; acc[m][2] = 0.f; acc[m][3] = 0.f; }
        int col = w * 16 + l15;
#pragma unroll
        for (int kt = 0; kt < 4; ++kt) {
            s16x8 a[4];
#pragma unroll
            for (int m = 0; m < 4; ++m) {
                int row = m * 16 + l15;
                int abyte = (row * 256 + kt * 64 + kg * 16) ^ ((l15 & 7) << 4);
                a[m] = *(const s16x8*)((const char*)epts + abyte);
            }
            s16x8 b = *(const s16x8*)(Woep + ((size_t)((kt * 128 + col) * 4 + kg)) * 8);
#pragma unroll
            for (int m = 0; m < 4; ++m) acc[m] = mfma16(a[m], b, acc[m]);
        }
        float bb = boe[col];
#pragma unroll
        for (int m = 0; m < 4; ++m)
#pragma unroll
            for (int i = 0; i < 4; ++i) {
                int rr = m * 16 + kg * 4 + i;
                int rbyte = (rr * 256 + col * 2) ^ ((rr & 7) << 4);
                float res = b2f(*(const unsigned short*)((const char*)eas + rbyte));
                size_t idx = (size_t)(e0 + rr) * 128 + col;
                float v = (res + acc[m][i] + bb) * BNS;
                if (IN_F32) eout_b[idx] = bf16r(v);
                else        eout_f[idx] = v;
            }
    }
}

// Node attention: one 64-lane wave per node, single pass (sc pre-clamped -> no max needed).
__global__ __launch_bounds__(64) void k_nattn(const int* __restrict__ offs, const int* __restrict__ csr_src,
                                              const float* __restrict__ sc,
                                              const unsigned char* __restrict__ e8,
                                              const unsigned short* __restrict__ Vh,
                                              unsigned short* __restrict__ wVb,
                                              unsigned short* __restrict__ rowVb) {
    int n = blockIdx.x;
    int lane = threadIdx.x;
    int beg = offs[n], end = offs[n + 1];
    int hv = lane >> 3;                   // head of cols (2*lane, 2*lane+1)
    float dsum = 0.f, av0 = 0.f, av1 = 0.f, ar0 = 0.f, ar1 = 0.f;
    auto body = [&](int i) {
        float a = __expf(sc[(size_t)i * 8 + hv]);
        dsum += a;
        int s = csr_src[i];
        int v = ((const int*)Vh)[(size_t)s * 64 + lane];
        int u8 = ((const unsigned short*)e8)[(size_t)i * 64 + lane];
        av0 += b2f((unsigned short)v) * a;
        av1 += b2f((unsigned short)((unsigned)v >> 16)) * a;
        ar0 += __builtin_amdgcn_cvt_f32_fp8(u8, 0) * a;
        ar1 += __builtin_amdgcn_cvt_f32_fp8(u8, 1) * a;
    };
    int i = beg;
    for (; i + 4 <= end; i += 4) { body(i); body(i + 1); body(i + 2); body(i + 3); }
    for (; i < end; ++i) body(i);
    float inv = 1.f / (dsum + 1e-16f);
    ((int*)wVb)[(size_t)n * 64 + lane]   = pk2(av0 * inv, av1 * inv);
    ((int*)rowVb)[(size_t)n * 64 + lane] = pk2(ar0 * inv, ar1 * inv);
}

// Node post via MFMA: 32 nodes/block, 256 threads (4 waves), LDS 24 KB.
// p0 stages BOTH rowV (swz bufA) and wV (linear bufU) with int4 loads; p1 reads wV from LDS.
template<bool EMIT>
__global__ __launch_bounds__(256) void k_nodeB(
    const unsigned short* __restrict__ wVb, const unsigned short* __restrict__ rowVb,
    const short* __restrict__ VRp, const float* __restrict__ dc,
    const float* __restrict__ logdeg, const float* __restrict__ x,
    const short* __restrict__ Wohp, const float* __restrict__ boh,
    const short* __restrict__ W1p, const float* __restrict__ b1,
    const short* __restrict__ W2p, const float* __restrict__ b2,
    float* __restrict__ xout,
    const short* __restrict__ Wqp2, const float* __restrict__ bq2,
    const short* __restrict__ Wkp2, const short* __restrict__ Wvp2,
    unsigned short* __restrict__ Qh2, unsigned short* __restrict__ Kh2,
    unsigned short* __restrict__ Vh2) {
    __shared__ short bufA[32 * 128];   // rowV staging / h1 / out (8 KB)
    __shared__ short bufU[32 * 256];   // wV linear / hs / us (16 KB)
    int n0 = blockIdx.x * 32;
    int t = threadIdx.x;
    int ci = t & 15, r0 = t >> 4;      // r0 in 0..15
    {   // p0: stage rowV (swz) + wV (linear) via int4 loads
#pragma unroll
        for (int h = 0; h < 2; ++h) {
            int rr = r0 + h * 16, n = n0 + rr;
            int4 pr = make_int4(0, 0, 0, 0), pw = make_int4(0, 0, 0, 0);
            if (n < NN) {
                pr = *(const int4*)(rowVb + (size_t)n * 128 + ci * 8);
                pw = *(const int4*)(wVb + (size_t)n * 128 + ci * 8);
            }
            int byte = (rr * 256 + ci * 16) ^ ((rr & 7) << 4);
            *(int4*)((char*)bufA + byte) = pr;
            *(int4*)(bufU + rr * 128 + ci * 8) = pw;
        }
    }
    __syncthreads();
    int lane = t & 63, w = t >> 6;     // w in 0..3
    int l15 = lane & 15, kg = lane >> 4;
    int cq[2] = {w * 32 + l15, w * 32 + 16 + l15};
    {   // p1: hs = (wV + rowV@VeRowBD) * degscale -> bufU (after internal barrier)
        float ldv[2][4];
#pragma unroll
        for (int m = 0; m < 2; ++m)
#pragma unroll
            for (int i = 0; i < 4; ++i) {
                int n = n0 + m * 16 + kg * 4 + i;
                ldv[m][i] = (n < NN) ? logdeg[n] : 0.f;
            }
        f32x4 acc[2][2];
#pragma unroll
        for (int m = 0; m < 2; ++m)
#pragma unroll
            for (int q = 0; q < 2; ++q)
#pragma unroll
                for (int i = 0; i < 4; ++i) {
                    int rr = m * 16 + kg * 4 + i;
                    acc[m][q][i] = b2f(*(const unsigned short*)(bufU + rr * 128 + cq[q]));
                }
#pragma unroll
        for (int kt = 0; kt < 4; ++kt) {
            s16x8 a[2];
#pragma unroll
            for (int m = 0; m < 2; ++m) {
                int row = m * 16 + l15;
                int abyte = (row * 256 + kt * 64 + kg * 16) ^ ((l15 & 7) << 4);
                a[m] = *(const s16x8*)((const char*)bufA + abyte);
            }
#pragma unroll
            for (int q = 0; q < 2; ++q) {
                s16x8 b = *(const s16x8*)(VRp + ((size_t)((kt * 128 + cq[q]) * 4 + kg)) * 8);
#pragma unroll
                for (int m = 0; m < 2; ++m) acc[m][q] = mfma16(a[m], b, acc[m][q]);
            }
        }
        __syncthreads();   // all wV LDS reads complete before hs overwrites bufU
#pragma unroll
        for (int q = 0; q < 2; ++q) {
            float d0 = dc[cq[q] * 2], d1 = dc[cq[q] * 2 + 1];
#pragma unroll
            for (int m = 0; m < 2; ++m)
#pragma unroll
                for (int i = 0; i < 4; ++i) {
                    int rr = m * 16 + kg * 4 + i;
                    float hs = acc[m][q][i] * (d0 + ldv[m][i] * d1);
                    int byte = (rr * 256 + cq[q] * 2) ^ ((rr & 7) << 4);
                    *(unsigned short*)((char*)bufU + byte) = bf16r(hs);
                }
        }
    }
    __syncthreads();
    float h1r[2][2][4];
    {   // p2: h1 = (x + hs@Woh + boh)*BNS -> bufA + regs; x loads hoisted to phase start
        float xv[2][2][4];
#pragma unroll
        for (int m = 0; m < 2; ++m)
#pragma unroll
            for (int q = 0; q < 2; ++q)
#pragma unroll
                for (int i = 0; i < 4; ++i) {
                    int n = n0 + m * 16 + kg * 4 + i;
                    xv[m][q][i] = (n < NN) ? x[(size_t)n * 128 + cq[q]] : 0.f;
                }
        f32x4 acc[2][2];
#pragma unroll
        for (int m = 0; m < 2; ++m)
#pragma unroll
            for (int q = 0; q < 2; ++q) { acc[m][q][0] = 0.f; acc[m][q][1] = 0.f; acc[m][q][2] = 0.f; acc[m][q][3] = 0.f; }
#pragma unroll
        for (int kt = 0; kt < 4; ++kt) {
            s16x8 a[2];
#pragma unroll
            for (int m = 0; m < 2; ++m) {
                int row = m * 16 + l15;
                int abyte = (row * 256 + kt * 64 + kg * 16) ^ ((l15 & 7) << 4);
                a[m] = *(const s16x8*)((const char*)bufU + abyte);
            }
#pragma unroll
            for (int q = 0; q < 2; ++q) {
                s16x8 b = *(const s16x8*)(Wohp + ((size_t)((kt * 128 + cq[q]) * 4 + kg)) * 8);
#pragma unroll
                for (int m = 0; m < 2; ++m) acc[m][q] = mfma16(a[m], b, acc[m][q]);
            }
        }
#pragma unroll
        for (int q = 0; q < 2; ++q) {
            float bb = boh[cq[q]];
#pragma unroll
            for (int m = 0; m < 2; ++m)
#pragma unroll
                for (int i = 0; i < 4; ++i) {
                    int rr = m * 16 + kg * 4 + i;
                    float h1 = (xv[m][q][i] + acc[m][q][i] + bb) * BNS;
                    h1r[m][q][i] = h1;
                    int byte = (rr * 256 + cq[q] * 2) ^ ((rr & 7) << 4);
                    *(unsigned short*)((char*)bufA + byte) = bf16r(h1);
                }
        }
    }
    __syncthreads();
    {   // p3: us = relu(h1@W1 + b1) -> bufU
        f32x4 acc[2][4];
#pragma unroll
        for (int m = 0; m < 2; ++m)
#pragma unroll
            for (int q = 0; q < 4; ++q) { acc[m][q][0] = 0.f; acc[m][q][1] = 0.f; acc[m][q][2] = 0.f; acc[m][q][3] = 0.f; }
#pragma unroll
        for (int kt = 0; kt < 4; ++kt) {
            s16x8 a[2];
#pragma unroll
            for (int m = 0; m < 2; ++m) {
                int row = m * 16 + l15;
                int abyte = (row * 256 + kt * 64 + kg * 16) ^ ((l15 & 7) << 4);
                a[m] = *(const s16x8*)((const char*)bufA + abyte);
            }
#pragma unroll
            for (int q = 0; q < 4; ++q) {
                int colq = w * 64 + q * 16 + l15;
                s16x8 b = *(const s16x8*)(W1p + ((size_t)((kt * 256 + colq) * 4 + kg)) * 8);
#pragma unroll
                for (int m = 0; m < 2; ++m) acc[m][q] = mfma16(a[m], b, acc[m][q]);
            }
        }
        __syncthreads();   // hs reads (p2) complete before us overwrites bufU
#pragma unroll
        for (int q = 0; q < 4; ++q) {
            int colq = w * 64 + q * 16 + l15;
            float bb = b1[colq];
#pragma unroll
            for (int m = 0; m < 2; ++m)
#pragma unroll
                for (int i = 0; i < 4; ++i) {
                    int rr = m * 16 + kg * 4 + i;
                    float us = fmaxf(acc[m][q][i] + bb, 0.f);
                    int byte = (rr * 512 + colq * 2) ^ ((rr & 7) << 4);
                    *(unsigned short*)((char*)bufU + byte) = bf16r(us);
                }
        }
    }
    __syncthreads();
    {   // p4: out = (h1 + us@W2 + b2)*BNS; EMIT: stage out bf16 into bufA
        f32x4 acc[2][2];
#pragma unroll
        for (int m = 0; m < 2; ++m)
#pragma unroll
            for (int q = 0; q < 2; ++q) { acc[m][q][0] = 0.f; acc[m][q][1] = 0.f; acc[m][q][2] = 0.f; acc[m][q][3] = 0.f; }
#pragma unroll
        for (int kt = 0; kt < 8; ++kt) {
            s16x8 a[2];
#pragma unroll
            for (int m = 0; m < 2; ++m) {
                int row = m * 16 + l15;
                int abyte = (row * 512 + kt * 64 + kg * 16) ^ ((l15 & 7) << 4);
                a[m] = *(const s16x8*)((const char*)bufU + abyte);
            }
#pragma unroll
            for (int q = 0; q < 2; ++q) {
                s16x8 b = *(const s16x8*)(W2p + ((size_t)((kt * 128 + cq[q]) * 4 + kg)) * 8);
#pragma unroll
                for (int m = 0; m < 2; ++m) acc[m][q] = mfma16(a[m], b, acc[m][q]);
            }
        }
#pragma unroll
        for (int q = 0; q < 2; ++q) {
            float bb = b2[cq[q]];
#pragma unroll
            for (int m = 0; m < 2; ++m)
#pragma unroll
                for (int i = 0; i < 4; ++i) {
                    int rr = m * 16 + kg * 4 + i, n = n0 + rr;
                    float outv = (h1r[m][q][i] + acc[m][q][i] + bb) * BNS;
                    if (n < NN) xout[(size_t)n * 128 + cq[q]] = outv;
                    if (EMIT) {
                        int byte = (rr * 256 + cq[q] * 2) ^ ((rr & 7) << 4);
                        *(unsigned short*)((char*)bufA + byte) = bf16r(outv);
                    }
                }
        }
    }
    if (EMIT) {   // next-layer Q/K/V from staged out
        __syncthreads();
        f32x4 acc[2][2][3];
#pragma unroll
        for (int m = 0; m < 2; ++m)
#pragma unroll
            for (int q = 0; q < 2; ++q)
#pragma unroll
                for (int o = 0; o < 3; ++o) { acc[m][q][o][0] = 0.f; acc[m][q][o][1] = 0.f; acc[m][q][o][2] = 0.f; acc[m][q][o][3] = 0.f; }
#pragma unroll
        for (int kt = 0; kt < 4; ++kt) {
            s16x8 a[2];
#pragma unroll
            for (int m = 0; m < 2; ++m) {
                int row = m * 16 + l15;
                int abyte = (row * 256 + kt * 64 + kg * 16) ^ ((l15 & 7) << 4);
                a[m] = *(const s16x8*)((const char*)bufA + abyte);
            }
#pragma unroll
            for (int q = 0; q < 2; ++q) {
                size_t bo = ((size_t)((kt * 128 + cq[q]) * 4 + kg)) * 8;
                s16x8 bqf = *(const s16x8*)(Wqp2 + bo);
                s16x8 bkf = *(const s16x8*)(Wkp2 + bo);
                s16x8 bvf = *(const s16x8*)(Wvp2 + bo);
#pragma unroll
                for (int m = 0; m < 2; ++m) {
                    acc[m][q][0] = mfma16(a[m], bqf, acc[m][q][0]);
                    acc[m][q][1] = mfma16(a[m], bkf, acc[m][q][1]);
                    acc[m][q][2] = mfma16(a[m], bvf, acc[m][q][2]);
                }
            }
        }
#pragma unroll
        for (int q = 0; q < 2; ++q) {
            float bqv = bq2[cq[q]];
#pragma unroll
            for (int m = 0; m < 2; ++m)
#pragma unroll
                for (int i = 0; i < 4; ++i) {
                    int n = n0 + m * 16 + kg * 4 + i;
                    if (n < NN) {
                        Qh2[(size_t)n * 128 + cq[q]] = bf16r(acc[m][q][0][i] + bqv);
                        Kh2[(size_t)n * 128 + cq[q]] = bf16r(acc[m][q][1][i]);
                        Vh2[(size_t)n * 128 + cq[q]] = bf16r(acc[m][q][2][i]);
                    }
                }
        }
    }
}

// ---------------- host launch ----------------

extern "C" void kernel_launch(void* const* d_in, const int* in_sizes, int n_in,
                              void* d_out, int out_size, void* d_ws, size_t ws_size,
                              hipStream_t stream) {
    (void)in_sizes; (void)n_in; (void)out_size; (void)ws_size;
    const float* x_in0  = (const float*)d_in[0];
    const int*   ei     = (const int*)d_in[1];
    const float* ea_in0 = (const float*)d_in[2];
    const float* Wq = (const float*)d_in[3];
    const float* bq = (const float*)d_in[4];
    const float* Wk = (const float*)d_in[5];
    const float* Wv = (const float*)d_in[6];
    const float* We = (const float*)d_in[7];
    const float* be = (const float*)d_in[8];
    const float* Aw = (const float*)d_in[9];
    const float* VeRow = (const float*)d_in[10];
    const float* Woh = (const float*)d_in[11];
    const float* boh = (const float*)d_in[12];
    const float* Woe = (const float*)d_in[13];
    const float* boe = (const float*)d_in[14];
    const float* dc  = (const float*)d_in[15];
    const float* W1 = (const float*)d_in[16];
    const float* b1 = (const float*)d_in[17];
    const float* W2 = (const float*)d_in[18];
    const float* b2 = (const float*)d_in[19];

    char* ws = (char*)d_ws;
    size_t off = 0;
    auto alloc = [&](size_t bytes) { void* p = ws + off; off = (off + bytes + 255) & ~(size_t)255; return p; };
    int*   deg    = (int*)alloc((size_t)NN * 4);
    int*   cursor = (int*)alloc((size_t)NN * 4);
    int*   offs   = (int*)alloc((size_t)(NN + 1) * 4);
    int*   bsum   = (int*)alloc((size_t)64 * 4);
    int*   csr_src= (int*)alloc((size_t)NE * 4);
    int*   epos   = (int*)alloc((size_t)NE * 4);
    float* logdeg = (float*)alloc((size_t)NN * 4);
    float* AwT    = (float*)alloc((size_t)2 * 128 * 4);
    unsigned short* Qh  = (unsigned short*)alloc((size_t)NN * 128 * 2);
    unsigned short* Kh  = (unsigned short*)alloc((size_t)NN * 128 * 2);
    unsigned short* Vh  = (unsigned short*)alloc((size_t)NN * 128 * 2);
    unsigned short* Qh2 = (unsigned short*)alloc((size_t)NN * 128 * 2);
    unsigned short* Kh2 = (unsigned short*)alloc((size_t)NN * 128 * 2);
    unsigned short* Vh2 = (unsigned short*)alloc((size_t)NN * 128 * 2);
    unsigned char* e8   = (unsigned char*)alloc((size_t)NE * 128);
    unsigned short* ea_bf = (unsigned short*)alloc((size_t)NE * 128 * 2);
    float* sc     = (float*)alloc((size_t)NE * 8 * 4);
    unsigned short* wVb   = (unsigned short*)alloc((size_t)NN * 128 * 2);
    unsigned short* rowVb = (unsigned short*)alloc((size_t)NN * 128 * 2);
    short* Wep    = (short*)alloc((size_t)2 * 128 * 256 * 2);
    short* Woep   = (short*)alloc((size_t)2 * 128 * 128 * 2);
    short* Wqp    = (short*)alloc((size_t)2 * 128 * 128 * 2);
    short* Wkp    = (short*)alloc((size_t)2 * 128 * 128 * 2);
    short* Wvp    = (short*)alloc((size_t)2 * 128 * 128 * 2);
    short* Wohp   = (short*)alloc((size_t)2 * 128 * 128 * 2);
    short* W1p    = (short*)alloc((size_t)2 * 128 * 256 * 2);
    short* W2p    = (short*)alloc((size_t)2 * 256 * 128 * 2);
    short* VRp    = (short*)alloc((size_t)2 * 128 * 128 * 2);

    float* out_x = (float*)d_out;
    float* out_e = out_x + (size_t)NN * 128;

    hipError_t err;
    err = hipMemsetAsync(deg, 0, (size_t)NN * 4, stream); (void)err;
    err = hipMemsetAsync(cursor, 0, (size_t)NN * 4, stream); (void)err;

    k_deg<<<(NE + 255) / 256, 256, 0, stream>>>(ei, deg);
    k_scan1<<<NBLK, 1024, 0, stream>>>(deg, offs, bsum, logdeg);
    k_scan3<<<NBLK, 1024, 0, stream>>>(offs, bsum);
    k_fill<<<(NE + 255) / 256, 256, 0, stream>>>(ei, offs, cursor, csr_src, epos);
    k_awt<<<1, 256, 0, stream>>>(Aw, AwT);
    k_packAll<<<1536, 256, 0, stream>>>(We, Woe, Wq, Wk, Wv, Woh, W1, W2, VeRow,
                                        Wep, Woep, Wqp, Wkp, Wvp, Wohp, W1p, W2p, VRp);

    // ---- layer 0 ----
    k_qkv<<<(NN + 63) / 64, 512, 0, stream>>>(x_in0, Wqp, bq, Wkp, Wvp, Qh, Kh, Vh);
    k_edgeA<true><<<NE / 64, 512, 0, stream>>>(ea_in0, ei, epos, Wep, be, AwT, Qh, Kh,
                                               e8, sc, Woep, boe, ea_bf);
    k_nattn<<<NN, 64, 0, stream>>>(offs, csr_src, sc, e8, Vh, wVb, rowVb);
    k_nodeB<true><<<(NN + 31) / 32, 256, 0, stream>>>(
        wVb, rowVb, VRp, dc, logdeg, x_in0,
        Wohp, boh, W1p, b1, W2p, b2, out_x,
        Wqp + 128 * 128, bq + 128, Wkp + 128 * 128, Wvp + 128 * 128, Qh2, Kh2, Vh2);

    // ---- layer 1 ----
    k_edgeA<false><<<NE / 64, 512, 0, stream>>>(ea_bf, ei, epos, Wep + 128 * 256, be + 256,
                                                AwT + 128, Qh2, Kh2, e8, sc,
                                                Woep + 128 * 128, boe + 128, out_e);
    k_nattn<<<NN, 64, 0, stream>>>(offs, csr_src, sc, e8, Vh2, wVb, rowVb);
    k_nodeB<false><<<(NN + 31) / 32, 256, 0, stream>>>(
        wVb, rowVb, VRp + 128 * 128, dc + 256, logdeg, out_x,
        Wohp + 128 * 128, boh + 128, W1p + 128 * 256, b1 + 256, W2p + 256 * 128, b2 + 128, out_x,
        nullptr, nullptr, nullptr, nullptr, nullptr, nullptr, nullptr);
}

// Round 20
// 839.708 us; speedup vs baseline: 1.9805x; 1.0022x over previous
//
#include <hip/hip_runtime.h>

#define NN 50000
#define NE 800000
#define CLAMPV 5.0f
#define BNS 0.9999950000374997f
#define EPS 136    // ushort stride of fp8 Ep rows (272B, 16B-aligned)
#define NBLK 49    // ceil(NN/1024)

typedef __attribute__((ext_vector_type(8))) short s16x8;
typedef __attribute__((ext_vector_type(8))) __bf16 bf16x8;
typedef __attribute__((ext_vector_type(4))) float f32x4;

__device__ inline f32x4 mfma16(s16x8 a, s16x8 b, f32x4 c) {
    return __builtin_amdgcn_mfma_f32_16x16x32_bf16(
        __builtin_bit_cast(bf16x8, a), __builtin_bit_cast(bf16x8, b), c, 0, 0, 0);
}

__device__ inline unsigned short bf16r(float f) {
    return __builtin_bit_cast(unsigned short, (__bf16)f);
}

__device__ inline int pk2(float a, float b) {
    return (int)(unsigned)bf16r(a) | ((int)(unsigned)bf16r(b) << 16);
}

__device__ inline float b2f(unsigned short u) {
    return __builtin_bit_cast(float, (unsigned)u << 16);
}

// ---------------- degree / CSR build ----------------

__global__ __launch_bounds__(256) void k_deg(const int* __restrict__ ei, int* __restrict__ deg) {
    int e = blockIdx.x * 256 + threadIdx.x;
    if (e < NE) atomicAdd(&deg[ei[NE + e]], 1);
}

__global__ __launch_bounds__(1024) void k_scan1(const int* __restrict__ deg, int* __restrict__ offs,
                                                int* __restrict__ bsum, float* __restrict__ logdeg) {
    __shared__ int sm[1024];
    int i = blockIdx.x * 1024 + threadIdx.x;
    int v = (i < NN) ? deg[i] : 0;
    if (i < NN) logdeg[i] = logf((float)v + 1.0f);
    sm[threadIdx.x] = v;
    __syncthreads();
    for (int s = 1; s < 1024; s <<= 1) {
        int t = (threadIdx.x >= s) ? sm[threadIdx.x - s] : 0;
        __syncthreads();
        sm[threadIdx.x] += t;
        __syncthreads();
    }
    if (i < NN) offs[i + 1] = sm[threadIdx.x];
    if (threadIdx.x == 1023) bsum[blockIdx.x] = sm[1023];
    if (blockIdx.x == 0 && threadIdx.x == 0) offs[0] = 0;
}

__global__ __launch_bounds__(1024) void k_scan3(int* __restrict__ offs, const int* __restrict__ bsum) {
    __shared__ int pre;
    if (threadIdx.x == 0) {
        int acc = 0;
        for (int i = 0; i < (int)blockIdx.x; ++i) acc += bsum[i];
        pre = acc;
    }
    __syncthreads();
    int i = blockIdx.x * 1024 + threadIdx.x;
    if (i < NN) offs[i + 1] += pre;
}

__global__ __launch_bounds__(256) void k_fill(const int* __restrict__ ei, const int* __restrict__ offs,
                                              int* __restrict__ cursor, int* __restrict__ csr_src,
                                              int* __restrict__ epos) {
    int e = blockIdx.x * 256 + threadIdx.x;
    if (e < NE) {
        int d = ei[NE + e];
        int pos = offs[d] + atomicAdd(&cursor[d], 1);
        csr_src[pos] = ei[e];
        epos[e] = pos;
    }
}

// Transpose Aw (D=16,H=8) -> AwT[h][d] for both layers (vector-loadable by head).
__global__ void k_awt(const float* __restrict__ Aw, float* __restrict__ AwT) {
    int i = threadIdx.x;   // 256 threads = 2*128
    if (i < 256) {
        int l = i >> 7, q = i & 127;
        int h = q >> 4, d = q & 15;
        AwT[l * 128 + h * 16 + d] = Aw[l * 128 + d * 8 + h];
    }
}

// One launch packs ALL weights (both layers) into MFMA B-fragment order.
#define PL_A (128*256)
#define PL_B (128*128)
__global__ __launch_bounds__(256) void k_packAll(
    const float* __restrict__ We,  const float* __restrict__ Woe, const float* __restrict__ Wq,
    const float* __restrict__ Wk,  const float* __restrict__ Wv,  const float* __restrict__ Woh,
    const float* __restrict__ W1,  const float* __restrict__ W2,  const float* __restrict__ VR,
    short* __restrict__ Wep,  short* __restrict__ Woep, short* __restrict__ Wqp,
    short* __restrict__ Wkp,  short* __restrict__ Wvp,  short* __restrict__ Wohp,
    short* __restrict__ W1p,  short* __restrict__ W2p,  short* __restrict__ VRp) {
    int s = blockIdx.x * 256 + threadIdx.x;
    const float* W; short* out; int ncol, perL; bool vr = false;
    if (s < 2 * PL_A) { W = We; out = Wep; ncol = 256; perL = PL_A; }
    else if ((s -= 2 * PL_A) < 2 * PL_B) { W = Woe; out = Woep; ncol = 128; perL = PL_B; }
    else if ((s -= 2 * PL_B) < 2 * PL_B) { W = Wq;  out = Wqp;  ncol = 128; perL = PL_B; }
    else if ((s -= 2 * PL_B) < 2 * PL_B) { W = Wk;  out = Wkp;  ncol = 128; perL = PL_B; }
    else if ((s -= 2 * PL_B) < 2 * PL_B) { W = Wv;  out = Wvp;  ncol = 128; perL = PL_B; }
    else if ((s -= 2 * PL_B) < 2 * PL_B) { W = Woh; out = Wohp; ncol = 128; perL = PL_B; }
    else if ((s -= 2 * PL_B) < 2 * PL_A) { W = W1;  out = W1p;  ncol = 256; perL = PL_A; }
    else if ((s -= 2 * PL_A) < 2 * PL_A) { W = W2;  out = W2p;  ncol = 128; perL = PL_A; }
    else if ((s -= 2 * PL_A) < 2 * PL_B) { W = VR;  out = VRp;  ncol = 128; perL = PL_B; vr = true; }
    else return;
    int l = s / perL, q = s % perL;
    int j = q & 7; int t2 = q >> 3; int kg = t2 & 3; t2 >>= 2;
    int col = t2 % ncol; int kt = t2 / ncol;
    int k = kt * 32 + kg * 8 + j;
    float v;
    if (vr) v = ((k >> 4) == (col >> 4)) ? VR[l * 2048 + (k & 15) * 128 + col] : 0.f;
    else    v = W[(size_t)l * perL + k * ncol + col];
    out[(size_t)l * perL + q] = (short)bf16r(v);
}

// ---------------- per-layer kernels ----------------

// Q/K/V via MFMA: 64 nodes/block, 512 threads (8 waves). Layer 0 only.
__global__ __launch_bounds__(512) void k_qkv(const float* __restrict__ x,
                                             const short* __restrict__ Wqp, const float* __restrict__ bq,
                                             const short* __restrict__ Wkp, const short* __restrict__ Wvp,
                                             unsigned short* __restrict__ Qh, unsigned short* __restrict__ Kh,
                                             unsigned short* __restrict__ Vh) {
    __shared__ short xsw[64 * 128];
    int t = threadIdx.x;
    int ci = t & 15, r0 = t >> 4;
    int n0 = blockIdx.x * 64;
    for (int rr = r0; rr < 64; rr += 32) {
        int n = n0 + rr;
        int4 pkv = make_int4(0, 0, 0, 0);
        if (n < NN) {
            const float4* src = (const float4*)(x + (size_t)n * 128 + ci * 8);
            float4 v0 = src[0], v1 = src[1];
            pkv.x = pk2(v0.x, v0.y); pkv.y = pk2(v0.z, v0.w);
            pkv.z = pk2(v1.x, v1.y); pkv.w = pk2(v1.z, v1.w);
        }
        int byte = (rr * 256 + ci * 16) ^ ((rr & 7) << 4);
        *(int4*)((char*)xsw + byte) = pkv;
    }
    __syncthreads();
    int lane = t & 63, w = t >> 6;
    int l15 = lane & 15, kg = lane >> 4;
    f32x4 acc[4][3];
#pragma unroll
    for (int m = 0; m < 4; ++m)
#pragma unroll
        for (int q = 0; q < 3; ++q) { acc[m][q][0] = 0.f; acc[m][q][1] = 0.f; acc[m][q][2] = 0.f; acc[m][q][3] = 0.f; }
    int col = w * 16 + l15;
#pragma unroll
    for (int kt = 0; kt < 4; ++kt) {
        s16x8 a[4];
#pragma unroll
        for (int m = 0; m < 4; ++m) {
            int row = m * 16 + l15;
            int abyte = (row * 256 + kt * 64 + kg * 16) ^ ((l15 & 7) << 4);
            a[m] = *(const s16x8*)((const char*)xsw + abyte);
        }
        size_t bo = ((size_t)((kt * 128 + col) * 4 + kg)) * 8;
        s16x8 bqf = *(const s16x8*)(Wqp + bo);
        s16x8 bkf = *(const s16x8*)(Wkp + bo);
        s16x8 bvf = *(const s16x8*)(Wvp + bo);
#pragma unroll
        for (int m = 0; m < 4; ++m) {
            acc[m][0] = mfma16(a[m], bqf, acc[m][0]);
            acc[m][1] = mfma16(a[m], bkf, acc[m][1]);
            acc[m][2] = mfma16(a[m], bvf, acc[m][2]);
        }
    }
    float bqv = bq[col];
#pragma unroll
    for (int m = 0; m < 4; ++m)
#pragma unroll
        for (int i = 0; i < 4; ++i) {
            int n = n0 + m * 16 + kg * 4 + i;
            if (n < NN) {
                Qh[(size_t)n * 128 + col] = bf16r(acc[m][0][i] + bqv);
                Kh[(size_t)n * 128 + col] = bf16r(acc[m][1][i]);
                Vh[(size_t)n * 128 + col] = bf16r(acc[m][2][i]);
            }
        }
}

// Fused edge kernel: 64 edges/block, 512 threads (8 waves).
// K/Q gathers issued right AFTER the phase-1 barrier (vmcnt in-order semantics).
template<bool IN_F32>
__global__ __launch_bounds__(512) void k_edgeA(const void* __restrict__ ea_, const int* __restrict__ ei,
                                               const int* __restrict__ epos,
                                               const short* __restrict__ Wep, const float* __restrict__ be,
                                               const float* __restrict__ AwT,
                                               const unsigned short* __restrict__ Qh,
                                               const unsigned short* __restrict__ Kh,
                                               unsigned char* __restrict__ e8, float* __restrict__ sc,
                                               const short* __restrict__ Woep, const float* __restrict__ boe,
                                               void* __restrict__ eout_) {
    __shared__ short eas[64 * 128];     // bf16 ea tile, XOR-swizzled (16 KB)
    __shared__ short epts[64 * EPS];    // fp8 (E_w,E_b) pairs, then bf16 ets tile (17.4 KB)
    __shared__ int eposs[64];
    const float* eaf = (const float*)ea_;
    const unsigned short* eab = (const unsigned short*)ea_;
    unsigned short* eout_b = (unsigned short*)eout_;
    float* eout_f = (float*)eout_;

    int e0 = blockIdx.x * 64;
    int t = threadIdx.x;
    int ci = t & 15, r0 = t >> 4;
    int eA = e0 + r0, eB = eA + 32;
    int siA = ei[eA], diA = ei[NE + eA];
    int siB = ei[eB], diB = ei[NE + eB];

    if (t < 64) eposs[t] = epos[e0 + t];
    {   // phase 1: stage ea -> bf16 swizzled
#pragma unroll
        for (int h = 0; h < 2; ++h) {
            int rr = r0 + h * 32;
            int4 pkv;
            if (IN_F32) {
                const float4* src = (const float4*)(eaf + (size_t)(e0 + rr) * 128 + ci * 8);
                float4 v0 = src[0], v1 = src[1];
                pkv.x = pk2(v0.x, v0.y); pkv.y = pk2(v0.z, v0.w);
                pkv.z = pk2(v1.x, v1.y); pkv.w = pk2(v1.z, v1.w);
            } else {
                pkv = *(const int4*)(eab + (size_t)(e0 + rr) * 128 + ci * 8);
            }
            int byte = (rr * 256 + ci * 16) ^ ((rr & 7) << 4);
            *(int4*)((char*)eas + byte) = pkv;
        }
    }
    __syncthreads();
    // K/Q gathers issued now — fly under phase-2 MFMAs, consumed in phase 3
    union { int4 v; unsigned short us[8]; } kuA, quA, kuB, quB;
    kuA.v = *(const int4*)(Kh + (size_t)siA * 128 + ci * 8);
    quA.v = *(const int4*)(Qh + (size_t)diA * 128 + ci * 8);
    kuB.v = *(const int4*)(Kh + (size_t)siB * 128 + ci * 8);
    quB.v = *(const int4*)(Qh + (size_t)diB * 128 + ci * 8);
    int posA = eposs[r0], posB = eposs[r0 + 32];

    int lane = t & 63, w = t >> 6;
    int l15 = lane & 15, kg = lane >> 4;
    {   // phase 2: Ep = eas @ We + be -> fp8 pairs in LDS
        f32x4 acc[4][2];
#pragma unroll
        for (int m = 0; m < 4; ++m)
#pragma unroll
            for (int q = 0; q < 2; ++q) { acc[m][q][0] = 0.f; acc[m][q][1] = 0.f; acc[m][q][2] = 0.f; acc[m][q][3] = 0.f; }
#pragma unroll
        for (int kt = 0; kt < 4; ++kt) {
            s16x8 a[4];
#pragma unroll
            for (int m = 0; m < 4; ++m) {
                int row = m * 16 + l15;
                int abyte = (row * 256 + kt * 64 + kg * 16) ^ ((l15 & 7) << 4);
                a[m] = *(const s16x8*)((const char*)eas + abyte);
            }
#pragma unroll
            for (int q = 0; q < 2; ++q) {
                int col = w * 32 + q * 16 + l15;
                s16x8 b = *(const s16x8*)(Wep + ((size_t)((kt * 256 + col) * 4 + kg)) * 8);
#pragma unroll
                for (int m = 0; m < 4; ++m) acc[m][q] = mfma16(a[m], b, acc[m][q]);
            }
        }
        float bw = be[w * 32 + l15], bb = be[w * 32 + 16 + l15];
#pragma unroll
        for (int m = 0; m < 4; ++m)
#pragma unroll
            for (int i = 0; i < 4; ++i) {
                int row = m * 16 + kg * 4 + i;
                int p8 = __builtin_amdgcn_cvt_pk_fp8_f32(acc[m][0][i] + bw, acc[m][1][i] + bb, 0, 0);
                epts[row * EPS + w * 16 + l15] = (short)p8;
            }
    }
    __syncthreads();
    int4 wA, wB;
    {
        wA = *(const int4*)(epts + (size_t)r0 * EPS + ci * 8);
        wB = *(const int4*)(epts + (size_t)(r0 + 32) * EPS + ci * 8);
    }
    __syncthreads();   // all Ep reads done before ets overwrites the buffer
    {   // phase 3: elementwise; f32 Aw dot (AwT vector loads)
        int hh = ci >> 1, dbase = (ci & 1) * 8;
        const float4* awp = (const float4*)(AwT + hh * 16 + dbase);
        float4 aw0 = awp[0], aw1 = awp[1];
        float aw[8] = {aw0.x, aw0.y, aw0.z, aw0.w, aw1.x, aw1.y, aw1.z, aw1.w};
#pragma unroll
        for (int h = 0; h < 2; ++h) {
            int r = r0 + h * 32;
            int pos = h ? posB : posA;
            const unsigned short* kus = h ? kuB.us : kuA.us;
            const unsigned short* qus = h ? quB.us : quA.us;
            const int4 ww = h ? wB : wA;
            int words[4] = {ww.x, ww.y, ww.z, ww.w};
            float p = 0.f;
            float etv[8];
#pragma unroll
            for (int k = 0; k < 4; ++k) {
                float ew0 = __builtin_amdgcn_cvt_f32_fp8(words[k], 0);
                float eb0 = __builtin_amdgcn_cvt_f32_fp8(words[k], 1);
                float ew1 = __builtin_amdgcn_cvt_f32_fp8(words[k], 2);
                float eb1 = __builtin_amdgcn_cvt_f32_fp8(words[k], 3);
                float kq0 = b2f(kus[2 * k]) + b2f(qus[2 * k]);
                float kq1 = b2f(kus[2 * k + 1]) + b2f(qus[2 * k + 1]);
                float sv0 = kq0 * ew0, sv1 = kq1 * ew1;
                float et0 = fmaxf(copysignf(sqrtf(fabsf(sv0)), sv0) + eb0, 0.f);
                float et1 = fmaxf(copysignf(sqrtf(fabsf(sv1)), sv1) + eb1, 0.f);
                etv[2 * k] = et0; etv[2 * k + 1] = et1;
                p += et0 * aw[2 * k] + et1 * aw[2 * k + 1];
            }
            int lo = __builtin_amdgcn_cvt_pk_fp8_f32(etv[0], etv[1], 0, 0);
            lo = __builtin_amdgcn_cvt_pk_fp8_f32(etv[2], etv[3], lo, 1);
            int hi = __builtin_amdgcn_cvt_pk_fp8_f32(etv[4], etv[5], 0, 0);
            hi = __builtin_amdgcn_cvt_pk_fp8_f32(etv[6], etv[7], hi, 1);
            *(int2*)(e8 + (size_t)pos * 128 + ci * 8) = make_int2(lo, hi);
            int4 pkv;
            pkv.x = pk2(etv[0], etv[1]); pkv.y = pk2(etv[2], etv[3]);
            pkv.z = pk2(etv[4], etv[5]); pkv.w = pk2(etv[6], etv[7]);
            int byte = (r * 256 + ci * 16) ^ ((r & 7) << 4);
            *(int4*)((char*)epts + byte) = pkv;
            p += __shfl_xor(p, 1);
            if ((ci & 1) == 0) {
                float s = fminf(fmaxf(p, -CLAMPV), CLAMPV);
                sc[(size_t)pos * 8 + hh] = s;
            }
        }
    }
    __syncthreads();
    {   // phase 4: e_out = (ea + ets @ Woe + boe) * BNS  (bf16 MFMA)
        f32x4 acc[4];
#pragma unroll
        for (int m = 0; m < 4; ++m) { acc[m][0] = 0.f; acc[m][1] = 0.f; acc[m][2] = 0.f; acc[m][3] = 0.f; }
        int col = w * 16 + l15;
#pragma unroll
        for (int kt = 0; kt < 4; ++kt) {
            s16x8 a[4];
#pragma unroll
            for (int m = 0; m < 4; ++m) {
                int row = m * 16 + l15;
                int abyte = (row * 256 + kt * 64 + kg * 16) ^ ((l15 & 7) << 4);
                a[m] = *(const s16x8*)((const char*)epts + abyte);
            }
            s16x8 b = *(const s16x8*)(Woep + ((size_t)((kt * 128 + col) * 4 + kg)) * 8);
#pragma unroll
            for (int m = 0; m < 4; ++m) acc[m] = mfma16(a[m], b, acc[m]);
        }
        float bb = boe[col];
#pragma unroll
        for (int m = 0; m < 4; ++m)
#pragma unroll
            for (int i = 0; i < 4; ++i) {
                int rr = m * 16 + kg * 4 + i;
                int rbyte = (rr * 256 + col * 2) ^ ((rr & 7) << 4);
                float res = b2f(*(const unsigned short*)((const char*)eas + rbyte));
                size_t idx = (size_t)(e0 + rr) * 128 + col;
                float v = (res + acc[m][i] + bb) * BNS;
                if (IN_F32) eout_b[idx] = bf16r(v);
                else        eout_f[idx] = v;
            }
    }
}

// Node attention: one 64-lane wave per node, single pass (sc pre-clamped -> no max needed).
__global__ __launch_bounds__(64) void k_nattn(const int* __restrict__ offs, const int* __restrict__ csr_src,
                                              const float* __restrict__ sc,
                                              const unsigned char* __restrict__ e8,
                                              const unsigned short* __restrict__ Vh,
                                              unsigned short* __restrict__ wVb,
                                              unsigned short* __restrict__ rowVb) {
    int n = blockIdx.x;
    int lane = threadIdx.x;
    int beg = offs[n], end = offs[n + 1];
    int hv = lane >> 3;
    float dsum = 0.f, av0 = 0.f, av1 = 0.f, ar0 = 0.f, ar1 = 0.f;
    auto body = [&](int i) {
        float a = __expf(sc[(size_t)i * 8 + hv]);
        dsum += a;
        int s = csr_src[i];
        int v = ((const int*)Vh)[(size_t)s * 64 + lane];
        int u8 = ((const unsigned short*)e8)[(size_t)i * 64 + lane];
        av0 += b2f((unsigned short)v) * a;
        av1 += b2f((unsigned short)((unsigned)v >> 16)) * a;
        ar0 += __builtin_amdgcn_cvt_f32_fp8(u8, 0) * a;
        ar1 += __builtin_amdgcn_cvt_f32_fp8(u8, 1) * a;
    };
    int i = beg;
    for (; i + 4 <= end; i += 4) { body(i); body(i + 1); body(i + 2); body(i + 3); }
    for (; i < end; ++i) body(i);
    float inv = 1.f / (dsum + 1e-16f);
    ((int*)wVb)[(size_t)n * 64 + lane]   = pk2(av0 * inv, av1 * inv);
    ((int*)rowVb)[(size_t)n * 64 + lane] = pk2(ar0 * inv, ar1 * inv);
}

// Node post via MFMA: 32 nodes/block, 256 threads (4 waves), LDS 24 KB.
template<bool EMIT>
__global__ __launch_bounds__(256) void k_nodeB(
    const unsigned short* __restrict__ wVb, const unsigned short* __restrict__ rowVb,
    const short* __restrict__ VRp, const float* __restrict__ dc,
    const float* __restrict__ logdeg, const float* __restrict__ x,
    const short* __restrict__ Wohp, const float* __restrict__ boh,
    const short* __restrict__ W1p, const float* __restrict__ b1,
    const short* __restrict__ W2p, const float* __restrict__ b2,
    float* __restrict__ xout,
    const short* __restrict__ Wqp2, const float* __restrict__ bq2,
    const short* __restrict__ Wkp2, const short* __restrict__ Wvp2,
    unsigned short* __restrict__ Qh2, unsigned short* __restrict__ Kh2,
    unsigned short* __restrict__ Vh2) {
    __shared__ short bufA[32 * 128];   // rowV staging / h1 / out (8 KB)
    __shared__ short bufU[32 * 256];   // wV linear / hs / us (16 KB)
    int n0 = blockIdx.x * 32;
    int t = threadIdx.x;
    int ci = t & 15, r0 = t >> 4;
    {   // p0: stage rowV (swz) + wV (linear) via int4 loads
#pragma unroll
        for (int h = 0; h < 2; ++h) {
            int rr = r0 + h * 16, n = n0 + rr;
            int4 pr = make_int4(0, 0, 0, 0), pw = make_int4(0, 0, 0, 0);
            if (n < NN) {
                pr = *(const int4*)(rowVb + (size_t)n * 128 + ci * 8);
                pw = *(const int4*)(wVb + (size_t)n * 128 + ci * 8);
            }
            int byte = (rr * 256 + ci * 16) ^ ((rr & 7) << 4);
            *(int4*)((char*)bufA + byte) = pr;
            *(int4*)(bufU + rr * 128 + ci * 8) = pw;
        }
    }
    __syncthreads();
    int lane = t & 63, w = t >> 6;
    int l15 = lane & 15, kg = lane >> 4;
    int cq[2] = {w * 32 + l15, w * 32 + 16 + l15};
    {   // p1: hs = (wV + rowV@VeRowBD) * degscale -> bufU
        float ldv[2][4];
#pragma unroll
        for (int m = 0; m < 2; ++m)
#pragma unroll
            for (int i = 0; i < 4; ++i) {
                int n = n0 + m * 16 + kg * 4 + i;
                ldv[m][i] = (n < NN) ? logdeg[n] : 0.f;
            }
        f32x4 acc[2][2];
#pragma unroll
        for (int m = 0; m < 2; ++m)
#pragma unroll
            for (int q = 0; q < 2; ++q)
#pragma unroll
                for (int i = 0; i < 4; ++i) {
                    int rr = m * 16 + kg * 4 + i;
                    acc[m][q][i] = b2f(*(const unsigned short*)(bufU + rr * 128 + cq[q]));
                }
#pragma unroll
        for (int kt = 0; kt < 4; ++kt) {
            s16x8 a[2];
#pragma unroll
            for (int m = 0; m < 2; ++m) {
                int row = m * 16 + l15;
                int abyte = (row * 256 + kt * 64 + kg * 16) ^ ((l15 & 7) << 4);
                a[m] = *(const s16x8*)((const char*)bufA + abyte);
            }
#pragma unroll
            for (int q = 0; q < 2; ++q) {
                s16x8 b = *(const s16x8*)(VRp + ((size_t)((kt * 128 + cq[q]) * 4 + kg)) * 8);
#pragma unroll
                for (int m = 0; m < 2; ++m) acc[m][q] = mfma16(a[m], b, acc[m][q]);
            }
        }
        __syncthreads();   // all wV LDS reads complete before hs overwrites bufU
#pragma unroll
        for (int q = 0; q < 2; ++q) {
            float d0 = dc[cq[q] * 2], d1 = dc[cq[q] * 2 + 1];
#pragma unroll
            for (int m = 0; m < 2; ++m)
#pragma unroll
                for (int i = 0; i < 4; ++i) {
                    int rr = m * 16 + kg * 4 + i;
                    float hs = acc[m][q][i] * (d0 + ldv[m][i] * d1);
                    int byte = (rr * 256 + cq[q] * 2) ^ ((rr & 7) << 4);
                    *(unsigned short*)((char*)bufU + byte) = bf16r(hs);
                }
        }
    }
    __syncthreads();
    float h1r[2][2][4];
    {   // p2: h1 = (x + hs@Woh + boh)*BNS -> bufA + regs
        float xv[2][2][4];
#pragma unroll
        for (int m = 0; m < 2; ++m)
#pragma unroll
            for (int q = 0; q < 2; ++q)
#pragma unroll
                for (int i = 0; i < 4; ++i) {
                    int n = n0 + m * 16 + kg * 4 + i;
                    xv[m][q][i] = (n < NN) ? x[(size_t)n * 128 + cq[q]] : 0.f;
                }
        f32x4 acc[2][2];
#pragma unroll
        for (int m = 0; m < 2; ++m)
#pragma unroll
            for (int q = 0; q < 2; ++q) { acc[m][q][0] = 0.f; acc[m][q][1] = 0.f; acc[m][q][2] = 0.f; acc[m][q][3] = 0.f; }
#pragma unroll
        for (int kt = 0; kt < 4; ++kt) {
            s16x8 a[2];
#pragma unroll
            for (int m = 0; m < 2; ++m) {
                int row = m * 16 + l15;
                int abyte = (row * 256 + kt * 64 + kg * 16) ^ ((l15 & 7) << 4);
                a[m] = *(const s16x8*)((const char*)bufU + abyte);
            }
#pragma unroll
            for (int q = 0; q < 2; ++q) {
                s16x8 b = *(const s16x8*)(Wohp + ((size_t)((kt * 128 + cq[q]) * 4 + kg)) * 8);
#pragma unroll
                for (int m = 0; m < 2; ++m) acc[m][q] = mfma16(a[m], b, acc[m][q]);
            }
        }
#pragma unroll
        for (int q = 0; q < 2; ++q) {
            float bb = boh[cq[q]];
#pragma unroll
            for (int m = 0; m < 2; ++m)
#pragma unroll
                for (int i = 0; i < 4; ++i) {
                    int rr = m * 16 + kg * 4 + i;
                    float h1 = (xv[m][q][i] + acc[m][q][i] + bb) * BNS;
                    h1r[m][q][i] = h1;
                    int byte = (rr * 256 + cq[q] * 2) ^ ((rr & 7) << 4);
                    *(unsigned short*)((char*)bufA + byte) = bf16r(h1);
                }
        }
    }
    __syncthreads();
    {   // p3: us = relu(h1@W1 + b1) -> bufU
        f32x4 acc[2][4];
#pragma unroll
        for (int m = 0; m < 2; ++m)
#pragma unroll
            for (int q = 0; q < 4; ++q) { acc[m][q][0] = 0.f; acc[m][q][1] = 0.f; acc[m][q][2] = 0.f; acc[m][q][3] = 0.f; }
#pragma unroll
        for (int kt = 0; kt < 4; ++kt) {
            s16x8 a[2];
#pragma unroll
            for (int m = 0; m < 2; ++m) {
                int row = m * 16 + l15;
                int abyte = (row * 256 + kt * 64 + kg * 16) ^ ((l15 & 7) << 4);
                a[m] = *(const s16x8*)((const char*)bufA + abyte);
            }
#pragma unroll
            for (int q = 0; q < 4; ++q) {
                int colq = w * 64 + q * 16 + l15;
                s16x8 b = *(const s16x8*)(W1p + ((size_t)((kt * 256 + colq) * 4 + kg)) * 8);
#pragma unroll
                for (int m = 0; m < 2; ++m) acc[m][q] = mfma16(a[m], b, acc[m][q]);
            }
        }
        __syncthreads();   // hs reads (p2) complete before us overwrites bufU
#pragma unroll
        for (int q = 0; q < 4; ++q) {
            int colq = w * 64 + q * 16 + l15;
            float bb = b1[colq];
#pragma unroll
            for (int m = 0; m < 2; ++m)
#pragma unroll
                for (int i = 0; i < 4; ++i) {
                    int rr = m * 16 + kg * 4 + i;
                    float us = fmaxf(acc[m][q][i] + bb, 0.f);
                    int byte = (rr * 512 + colq * 2) ^ ((rr & 7) << 4);
                    *(unsigned short*)((char*)bufU + byte) = bf16r(us);
                }
        }
    }
    __syncthreads();
    {   // p4: out = (h1 + us@W2 + b2)*BNS; EMIT: stage out bf16 into bufA
        f32x4 acc[2][2];
#pragma unroll
        for (int m = 0; m < 2; ++m)
#pragma unroll
            for (int q = 0; q < 2; ++q) { acc[m][q][0] = 0.f; acc[m][q][1] = 0.f; acc[m][q][2] = 0.f; acc[m][q][3] = 0.f; }
#pragma unroll
        for (int kt = 0; kt < 8; ++kt) {
            s16x8 a[2];
#pragma unroll
            for (int m = 0; m < 2; ++m) {
                int row = m * 16 + l15;
                int abyte = (row * 512 + kt * 64 + kg * 16) ^ ((l15 & 7) << 4);
                a[m] = *(const s16x8*)((const char*)bufU + abyte);
            }
#pragma unroll
            for (int q = 0; q < 2; ++q) {
                s16x8 b = *(const s16x8*)(W2p + ((size_t)((kt * 128 + cq[q]) * 4 + kg)) * 8);
#pragma unroll
                for (int m = 0; m < 2; ++m) acc[m][q] = mfma16(a[m], b, acc[m][q]);
            }
        }
#pragma unroll
        for (int q = 0; q < 2; ++q) {
            float bb = b2[cq[q]];
#pragma unroll
            for (int m = 0; m < 2; ++m)
#pragma unroll
                for (int i = 0; i < 4; ++i) {
                    int rr = m * 16 + kg * 4 + i, n = n0 + rr;
                    float outv = (h1r[m][q][i] + acc[m][q][i] + bb) * BNS;
                    if (n < NN) xout[(size_t)n * 128 + cq[q]] = outv;
                    if (EMIT) {
                        int byte = (rr * 256 + cq[q] * 2) ^ ((rr & 7) << 4);
                        *(unsigned short*)((char*)bufA + byte) = bf16r(outv);
                    }
                }
        }
    }
    if (EMIT) {   // next-layer Q/K/V from staged out
        __syncthreads();
        f32x4 acc[2][2][3];
#pragma unroll
        for (int m = 0; m < 2; ++m)
#pragma unroll
            for (int q = 0; q < 2; ++q)
#pragma unroll
                for (int o = 0; o < 3; ++o) { acc[m][q][o][0] = 0.f; acc[m][q][o][1] = 0.f; acc[m][q][o][2] = 0.f; acc[m][q][o][3] = 0.f; }
#pragma unroll
        for (int kt = 0; kt < 4; ++kt) {
            s16x8 a[2];
#pragma unroll
            for (int m = 0; m < 2; ++m) {
                int row = m * 16 + l15;
                int abyte = (row * 256 + kt * 64 + kg * 16) ^ ((l15 & 7) << 4);
                a[m] = *(const s16x8*)((const char*)bufA + abyte);
            }
#pragma unroll
            for (int q = 0; q < 2; ++q) {
                size_t bo = ((size_t)((kt * 128 + cq[q]) * 4 + kg)) * 8;
                s16x8 bqf = *(const s16x8*)(Wqp2 + bo);
                s16x8 bkf = *(const s16x8*)(Wkp2 + bo);
                s16x8 bvf = *(const s16x8*)(Wvp2 + bo);
#pragma unroll
                for (int m = 0; m < 2; ++m) {
                    acc[m][q][0] = mfma16(a[m], bqf, acc[m][q][0]);
                    acc[m][q][1] = mfma16(a[m], bkf, acc[m][q][1]);
                    acc[m][q][2] = mfma16(a[m], bvf, acc[m][q][2]);
                }
            }
        }
#pragma unroll
        for (int q = 0; q < 2; ++q) {
            float bqv = bq2[cq[q]];
#pragma unroll
            for (int m = 0; m < 2; ++m)
#pragma unroll
                for (int i = 0; i < 4; ++i) {
                    int n = n0 + m * 16 + kg * 4 + i;
                    if (n < NN) {
                        Qh2[(size_t)n * 128 + cq[q]] = bf16r(acc[m][q][0][i] + bqv);
                        Kh2[(size_t)n * 128 + cq[q]] = bf16r(acc[m][q][1][i]);
                        Vh2[(size_t)n * 128 + cq[q]] = bf16r(acc[m][q][2][i]);
                    }
                }
        }
    }
}

// ---------------- host launch ----------------

extern "C" void kernel_launch(void* const* d_in, const int* in_sizes, int n_in,
                              void* d_out, int out_size, void* d_ws, size_t ws_size,
                              hipStream_t stream) {
    (void)in_sizes; (void)n_in; (void)out_size; (void)ws_size;
    const float* x_in0  = (const float*)d_in[0];
    const int*   ei     = (const int*)d_in[1];
    const float* ea_in0 = (const float*)d_in[2];
    const float* Wq = (const float*)d_in[3];
    const float* bq = (const float*)d_in[4];
    const float* Wk = (const float*)d_in[5];
    const float* Wv = (const float*)d_in[6];
    const float* We = (const float*)d_in[7];
    const float* be = (const float*)d_in[8];
    const float* Aw = (const float*)d_in[9];
    const float* VeRow = (const float*)d_in[10];
    const float* Woh = (const float*)d_in[11];
    const float* boh = (const float*)d_in[12];
    const float* Woe = (const float*)d_in[13];
    const float* boe = (const float*)d_in[14];
    const float* dc  = (const float*)d_in[15];
    const float* W1 = (const float*)d_in[16];
    const float* b1 = (const float*)d_in[17];
    const float* W2 = (const float*)d_in[18];
    const float* b2 = (const float*)d_in[19];

    char* ws = (char*)d_ws;
    size_t off = 0;
    auto alloc = [&](size_t bytes) { void* p = ws + off; off = (off + bytes + 255) & ~(size_t)255; return p; };
    int*   deg    = (int*)alloc((size_t)NN * 4);
    int*   cursor = (int*)alloc((size_t)NN * 4);
    int*   offs   = (int*)alloc((size_t)(NN + 1) * 4);
    int*   bsum   = (int*)alloc((size_t)64 * 4);
    int*   csr_src= (int*)alloc((size_t)NE * 4);
    int*   epos   = (int*)alloc((size_t)NE * 4);
    float* logdeg = (float*)alloc((size_t)NN * 4);
    float* AwT    = (float*)alloc((size_t)2 * 128 * 4);
    unsigned short* Qh  = (unsigned short*)alloc((size_t)NN * 128 * 2);
    unsigned short* Kh  = (unsigned short*)alloc((size_t)NN * 128 * 2);
    unsigned short* Vh  = (unsigned short*)alloc((size_t)NN * 128 * 2);
    unsigned short* Qh2 = (unsigned short*)alloc((size_t)NN * 128 * 2);
    unsigned short* Kh2 = (unsigned short*)alloc((size_t)NN * 128 * 2);
    unsigned short* Vh2 = (unsigned short*)alloc((size_t)NN * 128 * 2);
    unsigned char* e8   = (unsigned char*)alloc((size_t)NE * 128);
    unsigned short* ea_bf = (unsigned short*)alloc((size_t)NE * 128 * 2);
    float* sc     = (float*)alloc((size_t)NE * 8 * 4);
    unsigned short* wVb   = (unsigned short*)alloc((size_t)NN * 128 * 2);
    unsigned short* rowVb = (unsigned short*)alloc((size_t)NN * 128 * 2);
    short* Wep    = (short*)alloc((size_t)2 * 128 * 256 * 2);
    short* Woep   = (short*)alloc((size_t)2 * 128 * 128 * 2);
    short* Wqp    = (short*)alloc((size_t)2 * 128 * 128 * 2);
    short* Wkp    = (short*)alloc((size_t)2 * 128 * 128 * 2);
    short* Wvp    = (short*)alloc((size_t)2 * 128 * 128 * 2);
    short* Wohp   = (short*)alloc((size_t)2 * 128 * 128 * 2);
    short* W1p    = (short*)alloc((size_t)2 * 128 * 256 * 2);
    short* W2p    = (short*)alloc((size_t)2 * 256 * 128 * 2);
    short* VRp    = (short*)alloc((size_t)2 * 128 * 128 * 2);

    float* out_x = (float*)d_out;
    float* out_e = out_x + (size_t)NN * 128;

    hipError_t err;
    err = hipMemsetAsync(deg, 0, (size_t)NN * 4, stream); (void)err;
    err = hipMemsetAsync(cursor, 0, (size_t)NN * 4, stream); (void)err;

    k_deg<<<(NE + 255) / 256, 256, 0, stream>>>(ei, deg);
    k_scan1<<<NBLK, 1024, 0, stream>>>(deg, offs, bsum, logdeg);
    k_scan3<<<NBLK, 1024, 0, stream>>>(offs, bsum);
    k_fill<<<(NE + 255) / 256, 256, 0, stream>>>(ei, offs, cursor, csr_src, epos);
    k_awt<<<1, 256, 0, stream>>>(Aw, AwT);
    k_packAll<<<1536, 256, 0, stream>>>(We, Woe, Wq, Wk, Wv, Woh, W1, W2, VeRow,
                                        Wep, Woep, Wqp, Wkp, Wvp, Wohp, W1p, W2p, VRp);

    // ---- layer 0 ----
    k_qkv<<<(NN + 63) / 64, 512, 0, stream>>>(x_in0, Wqp, bq, Wkp, Wvp, Qh, Kh, Vh);
    k_edgeA<true><<<NE / 64, 512, 0, stream>>>(ea_in0, ei, epos, Wep, be, AwT, Qh, Kh,
                                               e8, sc, Woep, boe, ea_bf);
    k_nattn<<<NN, 64, 0, stream>>>(offs, csr_src, sc, e8, Vh, wVb, rowVb);
    k_nodeB<true><<<(NN + 31) / 32, 256, 0, stream>>>(
        wVb, rowVb, VRp, dc, logdeg, x_in0,
        Wohp, boh, W1p, b1, W2p, b2, out_x,
        Wqp + 128 * 128, bq + 128, Wkp + 128 * 128, Wvp + 128 * 128, Qh2, Kh2, Vh2);

    // ---- layer 1 ----
    k_edgeA<false><<<NE / 64, 512, 0, stream>>>(ea_bf, ei, epos, Wep + 128 * 256, be + 256,
                                                AwT + 128, Qh2, Kh2, e8, sc,
                                                Woep + 128 * 128, boe + 128, out_e);
    k_nattn<<<NN, 64, 0, stream>>>(offs, csr_src, sc, e8, Vh2, wVb, rowVb);
    k_nodeB<false><<<(NN + 31) / 32, 256, 0, stream>>>(
        wVb, rowVb, VRp + 128 * 128, dc + 256, logdeg, out_x,
        Wohp + 128 * 128, boh + 128, W1p + 128 * 256, b1 + 256, W2p + 256 * 128, b2 + 128, out_x,
        nullptr, nullptr, nullptr, nullptr, nullptr, nullptr, nullptr);
}